// Round 1
// baseline (1568.948 us; speedup 1.0000x reference)
//
#include <hip/hip_runtime.h>
#include <hip/hip_bf16.h>
#include <math.h>

// Problem constants (B,S,D,H,WIN) = (2,2048,1024,16,128), DH=64
#define BB    2
#define SS    2048
#define DD    1024
#define HH    16
#define DHH   64
#define WINW  128
#define MROWS (BB * SS)          // 4096

// ---------------------------------------------------------------------------
// GEMM (NT): C[M,N] = A[M,K] * B[N,K]^T + bias[N]
// A row-major [M,K], B row-major [N,K].  64x64 tile, k-tile 16, 256 threads,
// 4x4 outputs per thread. M,N multiples of 64; K multiple of 16.
// ---------------------------------------------------------------------------
__global__ __launch_bounds__(256) void gemm_nt_bias(
    const float* __restrict__ A, const float* __restrict__ B,
    const float* __restrict__ bias, float* __restrict__ C,
    int M, int N, int K) {
  __shared__ float As[64][17];
  __shared__ float Bs[64][17];
  const int tid = threadIdx.x;
  const int tx = tid & 15;        // 0..15 col group
  const int ty = tid >> 4;        // 0..15 row group
  const int row0 = blockIdx.y * 64;
  const int col0 = blockIdx.x * 64;
  const int lrow = tid >> 2;          // 0..63
  const int lk4  = (tid & 3) << 2;    // 0,4,8,12

  float acc[4][4];
#pragma unroll
  for (int i = 0; i < 4; ++i)
#pragma unroll
    for (int j = 0; j < 4; ++j) acc[i][j] = 0.f;

  for (int k0 = 0; k0 < K; k0 += 16) {
    const float4 a4 = *(const float4*)(A + (size_t)(row0 + lrow) * K + k0 + lk4);
    const float4 b4 = *(const float4*)(B + (size_t)(col0 + lrow) * K + k0 + lk4);
    __syncthreads();   // previous iteration's LDS reads complete
    As[lrow][lk4 + 0] = a4.x; As[lrow][lk4 + 1] = a4.y;
    As[lrow][lk4 + 2] = a4.z; As[lrow][lk4 + 3] = a4.w;
    Bs[lrow][lk4 + 0] = b4.x; Bs[lrow][lk4 + 1] = b4.y;
    Bs[lrow][lk4 + 2] = b4.z; Bs[lrow][lk4 + 3] = b4.w;
    __syncthreads();
#pragma unroll
    for (int kk = 0; kk < 16; ++kk) {
      float av[4], bv[4];
#pragma unroll
      for (int i = 0; i < 4; ++i) av[i] = As[ty * 4 + i][kk];
#pragma unroll
      for (int j = 0; j < 4; ++j) bv[j] = Bs[tx * 4 + j][kk];
#pragma unroll
      for (int i = 0; i < 4; ++i)
#pragma unroll
        for (int j = 0; j < 4; ++j) acc[i][j] += av[i] * bv[j];
    }
  }
#pragma unroll
  for (int i = 0; i < 4; ++i) {
    const size_t r = (size_t)(row0 + ty * 4 + i) * N + col0 + tx * 4;
#pragma unroll
    for (int j = 0; j < 4; ++j)
      C[r + j] = acc[i][j] + bias[col0 + tx * 4 + j];
  }
}

// ---------------------------------------------------------------------------
// Sliding-window attention. qkv layout [B,S,3D]; one wave per (b,h,q).
// Band: keys in [q-128, q+128] clamped -> <=257 scores in LDS.
// ---------------------------------------------------------------------------
__global__ __launch_bounds__(256) void sw_attn(const float* __restrict__ qkv,
                                               float* __restrict__ attn) {
  const int wave = threadIdx.x >> 6;
  const int lane = threadIdx.x & 63;
  const int q = blockIdx.x * 4 + wave;
  const int h = blockIdx.y;
  const int b = blockIdx.z;

  __shared__ float sc[4][257];
  __shared__ float qs[4][DHH];

  const size_t rowq = ((size_t)b * SS + q) * (3 * DD);
  qs[wave][lane] = qkv[rowq + h * DHH + lane];
  __syncthreads();

  const int k0 = (q - WINW) > 0 ? (q - WINW) : 0;
  const int k1 = (q + WINW) < (SS - 1) ? (q + WINW) : (SS - 1);
  const int nk = k1 - k0 + 1;

  float lmax = -1e30f;
  for (int j = lane; j < nk; j += 64) {
    const float* kp = qkv + ((size_t)b * SS + (k0 + j)) * (3 * DD) + DD + h * DHH;
    float dot = 0.f;
#pragma unroll
    for (int dd = 0; dd < DHH; dd += 4) {
      const float4 kv = *(const float4*)(kp + dd);
      dot += qs[wave][dd + 0] * kv.x + qs[wave][dd + 1] * kv.y +
             qs[wave][dd + 2] * kv.z + qs[wave][dd + 3] * kv.w;
    }
    dot *= 0.125f;          // DH^-0.5
    sc[wave][j] = dot;
    lmax = fmaxf(lmax, dot);
  }
#pragma unroll
  for (int off = 32; off; off >>= 1) lmax = fmaxf(lmax, __shfl_xor(lmax, off, 64));

  float lsum = 0.f;
  for (int j = lane; j < nk; j += 64) {       // same-lane re-read: no barrier needed
    const float p = __expf(sc[wave][j] - lmax);
    sc[wave][j] = p;
    lsum += p;
  }
#pragma unroll
  for (int off = 32; off; off >>= 1) lsum += __shfl_xor(lsum, off, 64);
  __syncthreads();    // make all sc[] writes visible to all lanes

  const float inv = 1.f / lsum;
  float acc = 0.f;
  for (int j = 0; j < nk; ++j) {
    const float* vp = qkv + ((size_t)b * SS + (k0 + j)) * (3 * DD) + 2 * DD + h * DHH;
    acc += sc[wave][j] * vp[lane];            // sc broadcast, vp coalesced
  }
  attn[((size_t)b * SS + q) * DD + h * DHH + lane] = acc * inv;
}

// ---------------------------------------------------------------------------
// out = LayerNorm(a + b) * g + beta, row length D=1024, one block per row.
// ---------------------------------------------------------------------------
__global__ __launch_bounds__(256) void add_ln(
    const float* __restrict__ a, const float* __restrict__ b,
    const float* __restrict__ g, const float* __restrict__ be,
    float* __restrict__ out) {
  const int row = blockIdx.x;
  const int tid = threadIdx.x;
  const int lane = tid & 63;
  const int wave = tid >> 6;

  const float4 av = *(const float4*)(a + (size_t)row * DD + tid * 4);
  const float4 bv = *(const float4*)(b + (size_t)row * DD + tid * 4);
  float v[4] = {av.x + bv.x, av.y + bv.y, av.z + bv.z, av.w + bv.w};

  float s = v[0] + v[1] + v[2] + v[3];
  float s2 = v[0] * v[0] + v[1] * v[1] + v[2] * v[2] + v[3] * v[3];
#pragma unroll
  for (int off = 32; off; off >>= 1) {
    s += __shfl_xor(s, off, 64);
    s2 += __shfl_xor(s2, off, 64);
  }
  __shared__ float red[8];
  if (lane == 0) { red[wave] = s; red[4 + wave] = s2; }
  __syncthreads();
  s = red[0] + red[1] + red[2] + red[3];
  s2 = red[4] + red[5] + red[6] + red[7];

  const float mu = s * (1.f / DD);
  const float var = s2 * (1.f / DD) - mu * mu;
  const float r = rsqrtf(var + 1e-5f);

  const float4 gv = *(const float4*)(g + tid * 4);
  const float4 bev = *(const float4*)(be + tid * 4);
  float4 o;
  o.x = (v[0] - mu) * r * gv.x + bev.x;
  o.y = (v[1] - mu) * r * gv.y + bev.y;
  o.z = (v[2] - mu) * r * gv.z + bev.z;
  o.w = (v[3] - mu) * r * gv.w + bev.w;
  *(float4*)(out + (size_t)row * DD + tid * 4) = o;
}

// ---------------------------------------------------------------------------
// Spectral filter: per (b,d) signal of length 2048.
// Forward DIF FFT (natural in -> bit-reversed out), pointwise complex filter
// applied in bit-reversed order with Hermitian extension, inverse DIT FFT
// (bit-reversed in -> natural out, conjugate twiddles), scale 1/N.
// ---------------------------------------------------------------------------
__global__ __launch_bounds__(256) void spec_filter(
    const float* __restrict__ x, const float* __restrict__ wr,
    const float* __restrict__ wi, float* __restrict__ y) {
  __shared__ float re[SS];
  __shared__ float im[SS];
  const int d = blockIdx.x;
  const int b = blockIdx.y;
  const int tid = threadIdx.x;

  const float* xp = x + (size_t)b * SS * DD + d;
  for (int s = tid; s < SS; s += 256) {
    re[s] = xp[(size_t)s * DD];
    im[s] = 0.f;
  }

  // forward DIF
  for (int stage = 11; stage >= 1; --stage) {
    __syncthreads();
    const int half = 1 << (stage - 1);
    const float ang0 = -6.283185307179586f / (float)(1 << stage);
    for (int t = tid; t < SS / 2; t += 256) {
      const int gI = t >> (stage - 1);
      const int p = t & (half - 1);
      const int i = (gI << stage) + p;
      const int j = i + half;
      float sn, c;
      __sincosf(ang0 * (float)p, &sn, &c);
      const float ar = re[i], ai = im[i], br = re[j], bi = im[j];
      re[i] = ar + br; im[i] = ai + bi;
      const float dr = ar - br, di = ai - bi;
      re[j] = dr * c - di * sn;
      im[j] = dr * sn + di * c;
    }
  }
  __syncthreads();

  // pointwise multiply (bit-reversed positions hold freq k = bitrev11(p))
  for (int p = tid; p < SS; p += 256) {
    const int k = __brev((unsigned)p) >> 21;
    float wre, wim;
    if (k <= SS / 2) {
      wre = wr[(size_t)k * DD + d];
      wim = wi[(size_t)k * DD + d];
    } else {
      wre = wr[(size_t)(SS - k) * DD + d];
      wim = -wi[(size_t)(SS - k) * DD + d];
    }
    const float ar = re[p], ai = im[p];
    re[p] = ar * wre - ai * wim;
    im[p] = ar * wim + ai * wre;
  }

  // inverse DIT (conjugate twiddles)
  for (int stage = 1; stage <= 11; ++stage) {
    __syncthreads();
    const int half = 1 << (stage - 1);
    const float ang0 = 6.283185307179586f / (float)(1 << stage);
    for (int t = tid; t < SS / 2; t += 256) {
      const int gI = t >> (stage - 1);
      const int p = t & (half - 1);
      const int i = (gI << stage) + p;
      const int j = i + half;
      float sn, c;
      __sincosf(ang0 * (float)p, &sn, &c);
      const float br = re[j], bi = im[j];
      const float tr = br * c - bi * sn;
      const float ti = br * sn + bi * c;
      const float ar = re[i], ai = im[i];
      re[i] = ar + tr; im[i] = ai + ti;
      re[j] = ar - tr; im[j] = ai - ti;
    }
  }
  __syncthreads();

  float* yp = y + (size_t)b * SS * DD + d;
  const float scale = 1.f / (float)SS;
  for (int s = tid; s < SS; s += 256) yp[(size_t)s * DD] = re[s] * scale;
}

// ---------------------------------------------------------------------------
extern "C" void kernel_launch(void* const* d_in, const int* in_sizes, int n_in,
                              void* d_out, int out_size, void* d_ws, size_t ws_size,
                              hipStream_t stream) {
  const float* x     = (const float*)d_in[0];
  const float* in_w  = (const float*)d_in[1];
  const float* in_b  = (const float*)d_in[2];
  const float* out_w = (const float*)d_in[3];
  const float* out_b = (const float*)d_in[4];
  const float* ln1_g = (const float*)d_in[5];
  const float* ln1_b = (const float*)d_in[6];
  const float* wr    = (const float*)d_in[7];
  const float* wi    = (const float*)d_in[8];
  const float* ln2_g = (const float*)d_in[9];
  const float* ln2_b = (const float*)d_in[10];
  float* out = (float*)d_out;

  float* ws = (float*)d_ws;
  // Workspace layout (floats). Peak 16,777,216 floats = 64 MB.
  float* qkv      = ws;                  // [0 .. 12.58M)  B*S*3D
  float* attn     = ws + 12582912;       // [12.58M .. 16.78M)
  float* attn_out = ws;                  // reuse qkv region after attention
  float* x_attn   = ws + 4194304;
  float* x_wave   = ws + 8388608;

  // 1. qkv = x @ in_w^T + in_b    [4096, 3072]
  gemm_nt_bias<<<dim3(3072 / 64, MROWS / 64), 256, 0, stream>>>(
      x, in_w, in_b, qkv, MROWS, 3 * DD, DD);

  // 2. sliding-window attention   [4096, 1024]
  sw_attn<<<dim3(SS / 4, HH, BB), 256, 0, stream>>>(qkv, attn);

  // 3. attn_out = attn @ out_w^T + out_b
  gemm_nt_bias<<<dim3(DD / 64, MROWS / 64), 256, 0, stream>>>(
      attn, out_w, out_b, attn_out, MROWS, DD, DD);

  // 4. x_attn = LN1(x + attn_out)
  add_ln<<<MROWS, 256, 0, stream>>>(x, attn_out, ln1_g, ln1_b, x_attn);

  // 5. x_wave = irfft(rfft(x) * Wc)
  spec_filter<<<dim3(DD, BB), 256, 0, stream>>>(x, wr, wi, x_wave);

  // 6. out = LN2(x_attn + x_wave)
  add_ln<<<MROWS, 256, 0, stream>>>(x_attn, x_wave, ln2_g, ln2_b, out);
}

// Round 2
// 993.265 us; speedup vs baseline: 1.5796x; 1.5796x over previous
//
#include <hip/hip_runtime.h>
#include <hip/hip_bf16.h>
#include <math.h>

// Problem constants (B,S,D,H,WIN) = (2,2048,1024,16,128), DH=64
#define BB    2
#define SS    2048
#define DD    1024
#define HH    16
#define DHH   64
#define WINW  128
#define MROWS (BB * SS)          // 4096

typedef __attribute__((ext_vector_type(8))) short short8;
typedef __attribute__((ext_vector_type(4))) float floatx4;

// ---------------------------------------------------------------------------
// fp32 -> bf16 cast, 4 elems/thread
// ---------------------------------------------------------------------------
__global__ __launch_bounds__(256) void cast_f32_bf16(
    const float* __restrict__ in, __hip_bfloat16* __restrict__ out, int n) {
  const int i = (blockIdx.x * 256 + threadIdx.x) * 4;
  if (i < n) {
    const float4 v = *(const float4*)(in + i);
    out[i + 0] = __float2bfloat16(v.x);
    out[i + 1] = __float2bfloat16(v.y);
    out[i + 2] = __float2bfloat16(v.z);
    out[i + 3] = __float2bfloat16(v.w);
  }
}

// ---------------------------------------------------------------------------
// bf16 MFMA GEMM (NT): C[M,N] = A[M,K] * B[N,K]^T + bias[N]   (fp32 out)
// m97 structure: 128x128 tile, BK=32, 256 threads (4 waves, 2x2), each wave
// 64x64 via 4x4 grid of mfma_f32_16x16x32_bf16. global_load_lds width=16.
// ---------------------------------------------------------------------------
__device__ inline void load16_lds(const __hip_bfloat16* g, __hip_bfloat16* l) {
  __builtin_amdgcn_global_load_lds(
      (const __attribute__((address_space(1))) uint32_t*)g,
      (__attribute__((address_space(3))) uint32_t*)l, 16, 0, 0);
}

__global__ __launch_bounds__(256) void gemm_bf16_nt(
    const __hip_bfloat16* __restrict__ A, const __hip_bfloat16* __restrict__ B,
    const float* __restrict__ bias, float* __restrict__ C,
    int M, int N, int K) {
  __shared__ __attribute__((aligned(16))) __hip_bfloat16 As[128 * 32];
  __shared__ __attribute__((aligned(16))) __hip_bfloat16 Bs[128 * 32];
  const int tid  = threadIdx.x;
  const int lane = tid & 63;
  const int wave = tid >> 6;
  const int wrow = (wave >> 1) * 64;     // wave's 64x64 sub-tile origin
  const int wcol = (wave & 1) * 64;
  const int row0 = blockIdx.y * 128;
  const int col0 = blockIdx.x * 128;

  // staging: thread t loads 16B = 8 bf16; tile row = t>>2, k-part = (t&3)*8
  const int srow = tid >> 2;             // 0..63
  const int skk  = (tid & 3) * 8;        // 0,8,16,24

  const int quad = lane >> 4;            // 0..3
  const int l16  = lane & 15;            // 0..15

  floatx4 acc[4][4] = {};

  for (int k0 = 0; k0 < K; k0 += 32) {
    __syncthreads();   // previous iteration's LDS reads complete
    load16_lds(A + (size_t)(row0 + srow) * K + k0 + skk,       &As[tid * 8]);
    load16_lds(A + (size_t)(row0 + 64 + srow) * K + k0 + skk,  &As[2048 + tid * 8]);
    load16_lds(B + (size_t)(col0 + srow) * K + k0 + skk,       &Bs[tid * 8]);
    load16_lds(B + (size_t)(col0 + 64 + srow) * K + k0 + skk,  &Bs[2048 + tid * 8]);
    __syncthreads();   // compiler inserts vmcnt(0) drain before barrier

    short8 af[4], bf[4];
#pragma unroll
    for (int i = 0; i < 4; ++i)
      af[i] = *(const short8*)&As[(wrow + i * 16 + l16) * 32 + quad * 8];
#pragma unroll
    for (int j = 0; j < 4; ++j)
      bf[j] = *(const short8*)&Bs[(wcol + j * 16 + l16) * 32 + quad * 8];
#pragma unroll
    for (int i = 0; i < 4; ++i)
#pragma unroll
      for (int j = 0; j < 4; ++j)
        acc[i][j] = __builtin_amdgcn_mfma_f32_16x16x32_bf16(af[i], bf[j], acc[i][j], 0, 0, 0);
  }

  // epilogue: C/D layout col=lane&15, row=quad*4+reg
#pragma unroll
  for (int i = 0; i < 4; ++i) {
#pragma unroll
    for (int j = 0; j < 4; ++j) {
      const int col = col0 + wcol + j * 16 + l16;
      const float bs = bias[col];
#pragma unroll
      for (int r = 0; r < 4; ++r) {
        const int row = row0 + wrow + i * 16 + quad * 4 + r;
        C[(size_t)row * N + col] = acc[i][j][r] + bs;
      }
    }
  }
}

// ---------------------------------------------------------------------------
// Sliding-window attention. qkv layout [B,S,3D] fp32; one wave per (b,h,q).
// Band: keys in [q-128, q+128] clamped -> <=257 scores in LDS. bf16 output.
// ---------------------------------------------------------------------------
__global__ __launch_bounds__(256) void sw_attn(const float* __restrict__ qkv,
                                               __hip_bfloat16* __restrict__ attn) {
  const int wave = threadIdx.x >> 6;
  const int lane = threadIdx.x & 63;
  const int q = blockIdx.x * 4 + wave;
  const int h = blockIdx.y;
  const int b = blockIdx.z;

  __shared__ float sc[4][257];
  __shared__ float qs[4][DHH];

  const size_t rowq = ((size_t)b * SS + q) * (3 * DD);
  qs[wave][lane] = qkv[rowq + h * DHH + lane];
  __syncthreads();

  const int k0 = (q - WINW) > 0 ? (q - WINW) : 0;
  const int k1 = (q + WINW) < (SS - 1) ? (q + WINW) : (SS - 1);
  const int nk = k1 - k0 + 1;

  float lmax = -1e30f;
  for (int j = lane; j < nk; j += 64) {
    const float* kp = qkv + ((size_t)b * SS + (k0 + j)) * (3 * DD) + DD + h * DHH;
    float dot = 0.f;
#pragma unroll
    for (int dd = 0; dd < DHH; dd += 4) {
      const float4 kv = *(const float4*)(kp + dd);
      dot += qs[wave][dd + 0] * kv.x + qs[wave][dd + 1] * kv.y +
             qs[wave][dd + 2] * kv.z + qs[wave][dd + 3] * kv.w;
    }
    dot *= 0.125f;          // DH^-0.5
    sc[wave][j] = dot;
    lmax = fmaxf(lmax, dot);
  }
#pragma unroll
  for (int off = 32; off; off >>= 1) lmax = fmaxf(lmax, __shfl_xor(lmax, off, 64));

  float lsum = 0.f;
  for (int j = lane; j < nk; j += 64) {
    const float p = __expf(sc[wave][j] - lmax);
    sc[wave][j] = p;
    lsum += p;
  }
#pragma unroll
  for (int off = 32; off; off >>= 1) lsum += __shfl_xor(lsum, off, 64);
  __syncthreads();

  const float inv = 1.f / lsum;
  float acc = 0.f;
  for (int j = 0; j < nk; ++j) {
    const float* vp = qkv + ((size_t)b * SS + (k0 + j)) * (3 * DD) + 2 * DD + h * DHH;
    acc += sc[wave][j] * vp[lane];
  }
  attn[((size_t)b * SS + q) * DD + h * DHH + lane] = __float2bfloat16(acc * inv);
}

// ---------------------------------------------------------------------------
// out = LayerNorm(a + b) * g + beta, row length D=1024, one block per row.
// ---------------------------------------------------------------------------
__global__ __launch_bounds__(256) void add_ln(
    const float* __restrict__ a, const float* __restrict__ b,
    const float* __restrict__ g, const float* __restrict__ be,
    float* __restrict__ out) {
  const int row = blockIdx.x;
  const int tid = threadIdx.x;
  const int lane = tid & 63;
  const int wave = tid >> 6;

  const float4 av = *(const float4*)(a + (size_t)row * DD + tid * 4);
  const float4 bv = *(const float4*)(b + (size_t)row * DD + tid * 4);
  float v[4] = {av.x + bv.x, av.y + bv.y, av.z + bv.z, av.w + bv.w};

  float s = v[0] + v[1] + v[2] + v[3];
  float s2 = v[0] * v[0] + v[1] * v[1] + v[2] * v[2] + v[3] * v[3];
#pragma unroll
  for (int off = 32; off; off >>= 1) {
    s += __shfl_xor(s, off, 64);
    s2 += __shfl_xor(s2, off, 64);
  }
  __shared__ float red[8];
  if (lane == 0) { red[wave] = s; red[4 + wave] = s2; }
  __syncthreads();
  s = red[0] + red[1] + red[2] + red[3];
  s2 = red[4] + red[5] + red[6] + red[7];

  const float mu = s * (1.f / DD);
  const float var = s2 * (1.f / DD) - mu * mu;
  const float r = rsqrtf(var + 1e-5f);

  const float4 gv = *(const float4*)(g + tid * 4);
  const float4 bev = *(const float4*)(be + tid * 4);
  float4 o;
  o.x = (v[0] - mu) * r * gv.x + bev.x;
  o.y = (v[1] - mu) * r * gv.y + bev.y;
  o.z = (v[2] - mu) * r * gv.z + bev.z;
  o.w = (v[3] - mu) * r * gv.w + bev.w;
  *(float4*)(out + (size_t)row * DD + tid * 4) = o;
}

// ---------------------------------------------------------------------------
// Spectral filter: per (b,d) signal of length 2048.
// Forward DIF FFT -> pointwise complex filter in bit-reversed order (with
// Hermitian extension) -> inverse DIT FFT with conjugate twiddles, scale 1/N.
// ---------------------------------------------------------------------------
__global__ __launch_bounds__(256) void spec_filter(
    const float* __restrict__ x, const float* __restrict__ wr,
    const float* __restrict__ wi, float* __restrict__ y) {
  __shared__ float re[SS];
  __shared__ float im[SS];
  const int d = blockIdx.x;
  const int b = blockIdx.y;
  const int tid = threadIdx.x;

  const float* xp = x + (size_t)b * SS * DD + d;
  for (int s = tid; s < SS; s += 256) {
    re[s] = xp[(size_t)s * DD];
    im[s] = 0.f;
  }

  // forward DIF
  for (int stage = 11; stage >= 1; --stage) {
    __syncthreads();
    const int half = 1 << (stage - 1);
    const float ang0 = -6.283185307179586f / (float)(1 << stage);
    for (int t = tid; t < SS / 2; t += 256) {
      const int gI = t >> (stage - 1);
      const int p = t & (half - 1);
      const int i = (gI << stage) + p;
      const int j = i + half;
      float sn, c;
      __sincosf(ang0 * (float)p, &sn, &c);
      const float ar = re[i], ai = im[i], br = re[j], bi = im[j];
      re[i] = ar + br; im[i] = ai + bi;
      const float dr = ar - br, di = ai - bi;
      re[j] = dr * c - di * sn;
      im[j] = dr * sn + di * c;
    }
  }
  __syncthreads();

  // pointwise multiply (bit-reversed positions hold freq k = bitrev11(p))
  for (int p = tid; p < SS; p += 256) {
    const int k = __brev((unsigned)p) >> 21;
    float wre, wim;
    if (k <= SS / 2) {
      wre = wr[(size_t)k * DD + d];
      wim = wi[(size_t)k * DD + d];
    } else {
      wre = wr[(size_t)(SS - k) * DD + d];
      wim = -wi[(size_t)(SS - k) * DD + d];
    }
    const float ar = re[p], ai = im[p];
    re[p] = ar * wre - ai * wim;
    im[p] = ar * wim + ai * wre;
  }

  // inverse DIT (conjugate twiddles)
  for (int stage = 1; stage <= 11; ++stage) {
    __syncthreads();
    const int half = 1 << (stage - 1);
    const float ang0 = 6.283185307179586f / (float)(1 << stage);
    for (int t = tid; t < SS / 2; t += 256) {
      const int gI = t >> (stage - 1);
      const int p = t & (half - 1);
      const int i = (gI << stage) + p;
      const int j = i + half;
      float sn, c;
      __sincosf(ang0 * (float)p, &sn, &c);
      const float br = re[j], bi = im[j];
      const float tr = br * c - bi * sn;
      const float ti = br * sn + bi * c;
      const float ar = re[i], ai = im[i];
      re[i] = ar + tr; im[i] = ai + ti;
      re[j] = ar - tr; im[j] = ar == ar ? ai - ti : ai - ti;  // ai - ti
    }
  }
  __syncthreads();

  float* yp = y + (size_t)b * SS * DD + d;
  const float scale = 1.f / (float)SS;
  for (int s = tid; s < SS; s += 256) yp[(size_t)s * DD] = re[s] * scale;
}

// ---------------------------------------------------------------------------
extern "C" void kernel_launch(void* const* d_in, const int* in_sizes, int n_in,
                              void* d_out, int out_size, void* d_ws, size_t ws_size,
                              hipStream_t stream) {
  const float* x     = (const float*)d_in[0];
  const float* in_w  = (const float*)d_in[1];
  const float* in_b  = (const float*)d_in[2];
  const float* out_w = (const float*)d_in[3];
  const float* out_b = (const float*)d_in[4];
  const float* ln1_g = (const float*)d_in[5];
  const float* ln1_b = (const float*)d_in[6];
  const float* wr    = (const float*)d_in[7];
  const float* wi    = (const float*)d_in[8];
  const float* ln2_g = (const float*)d_in[9];
  const float* ln2_b = (const float*)d_in[10];
  float* out = (float*)d_out;

  float* ws = (float*)d_ws;
  // Workspace phases (64 MB total):
  //   [0,48)MB qkv fp32 -> later attn_out/x_attn/x_wave fp32
  //   [48,56)MB x_bf16 -> later attn_bf16
  //   [56,62)MB in_w bf16 ; [62,64)MB out_w bf16
  float* qkv = ws;
  __hip_bfloat16* x_bf    = (__hip_bfloat16*)(ws + 12582912);  // 48 MB
  __hip_bfloat16* attn_bf = x_bf;                              // reuse
  __hip_bfloat16* w_in_bf = (__hip_bfloat16*)(ws + 14680064);  // 56 MB
  __hip_bfloat16* w_out_bf= (__hip_bfloat16*)(ws + 16252928);  // 62 MB
  float* attn_out = ws;                                        // reuse qkv
  float* x_attn   = ws + 4194304;                              // 16 MB
  float* x_wave   = ws + 8388608;                              // 32 MB

  // 0. casts to bf16
  cast_f32_bf16<<<4194304 / 1024, 256, 0, stream>>>(x, x_bf, 4194304);
  cast_f32_bf16<<<3145728 / 1024, 256, 0, stream>>>(in_w, w_in_bf, 3145728);
  cast_f32_bf16<<<1048576 / 1024, 256, 0, stream>>>(out_w, w_out_bf, 1048576);

  // 1. qkv = x @ in_w^T + in_b    [4096, 3072]
  gemm_bf16_nt<<<dim3(3072 / 128, MROWS / 128), 256, 0, stream>>>(
      x_bf, w_in_bf, in_b, qkv, MROWS, 3 * DD, DD);

  // 2. sliding-window attention -> bf16 [4096, 1024]
  sw_attn<<<dim3(SS / 4, HH, BB), 256, 0, stream>>>(qkv, attn_bf);

  // 3. attn_out = attn @ out_w^T + out_b
  gemm_bf16_nt<<<dim3(DD / 128, MROWS / 128), 256, 0, stream>>>(
      attn_bf, w_out_bf, out_b, attn_out, MROWS, DD, DD);

  // 4. x_attn = LN1(x + attn_out)
  add_ln<<<MROWS, 256, 0, stream>>>(x, attn_out, ln1_g, ln1_b, x_attn);

  // 5. x_wave = irfft(rfft(x) * Wc)
  spec_filter<<<dim3(DD, BB), 256, 0, stream>>>(x, wr, wi, x_wave);

  // 6. out = LN2(x_attn + x_wave)
  add_ln<<<MROWS, 256, 0, stream>>>(x_attn, x_wave, ln2_g, ln2_b, out);
}

// Round 3
// 336.667 us; speedup vs baseline: 4.6602x; 2.9503x over previous
//
#include <hip/hip_runtime.h>
#include <hip/hip_bf16.h>
#include <math.h>

// Problem constants (B,S,D,H,WIN) = (2,2048,1024,16,128), DH=64
#define BB    2
#define SS    2048
#define DD    1024
#define HH    16
#define DHH   64
#define WINW  128
#define MROWS (BB * SS)          // 4096

typedef __attribute__((ext_vector_type(8))) short short8;
typedef __attribute__((ext_vector_type(4))) short short4v;
typedef __attribute__((ext_vector_type(4))) float floatx4;

// ---------------------------------------------------------------------------
// fp32 -> bf16 cast, 4 elems/thread
// ---------------------------------------------------------------------------
__global__ __launch_bounds__(256) void cast_f32_bf16(
    const float* __restrict__ in, __hip_bfloat16* __restrict__ out, int n) {
  const int i = (blockIdx.x * 256 + threadIdx.x) * 4;
  if (i < n) {
    const float4 v = *(const float4*)(in + i);
    out[i + 0] = __float2bfloat16(v.x);
    out[i + 1] = __float2bfloat16(v.y);
    out[i + 2] = __float2bfloat16(v.z);
    out[i + 3] = __float2bfloat16(v.w);
  }
}

// ---------------------------------------------------------------------------
__device__ inline void load16_lds(const __hip_bfloat16* g, __hip_bfloat16* l) {
  __builtin_amdgcn_global_load_lds(
      (const __attribute__((address_space(1))) uint32_t*)g,
      (__attribute__((address_space(3))) uint32_t*)l, 16, 0, 0);
}

// ---------------------------------------------------------------------------
// bf16 MFMA GEMM (NT): C[M,N] = A[M,K] * B[N,K]^T + bias[N]
// 128x128 tile, BK=32, 256 threads (4 waves 2x2), mfma_f32_16x16x32_bf16.
// Two variants: fp32 output, bf16 output.
// ---------------------------------------------------------------------------
#define GEMM_BODY(STORE)                                                       \
  __shared__ __attribute__((aligned(16))) __hip_bfloat16 As[128 * 32];         \
  __shared__ __attribute__((aligned(16))) __hip_bfloat16 Bs[128 * 32];         \
  const int tid  = threadIdx.x;                                                \
  const int lane = tid & 63;                                                   \
  const int wave = tid >> 6;                                                   \
  const int wrow = (wave >> 1) * 64;                                           \
  const int wcol = (wave & 1) * 64;                                            \
  const int row0 = blockIdx.y * 128;                                           \
  const int col0 = blockIdx.x * 128;                                           \
  const int srow = tid >> 2;                                                   \
  const int skk  = (tid & 3) * 8;                                              \
  const int quad = lane >> 4;                                                  \
  const int l16  = lane & 15;                                                  \
  floatx4 acc[4][4] = {};                                                      \
  for (int k0 = 0; k0 < K; k0 += 32) {                                         \
    __syncthreads();                                                           \
    load16_lds(A + (size_t)(row0 + srow) * K + k0 + skk,      &As[tid * 8]);   \
    load16_lds(A + (size_t)(row0 + 64 + srow) * K + k0 + skk, &As[2048 + tid * 8]); \
    load16_lds(B + (size_t)(col0 + srow) * K + k0 + skk,      &Bs[tid * 8]);   \
    load16_lds(B + (size_t)(col0 + 64 + srow) * K + k0 + skk, &Bs[2048 + tid * 8]); \
    __syncthreads();                                                           \
    short8 af[4], bf[4];                                                       \
    _Pragma("unroll")                                                          \
    for (int i = 0; i < 4; ++i)                                                \
      af[i] = *(const short8*)&As[(wrow + i * 16 + l16) * 32 + quad * 8];      \
    _Pragma("unroll")                                                          \
    for (int j = 0; j < 4; ++j)                                                \
      bf[j] = *(const short8*)&Bs[(wcol + j * 16 + l16) * 32 + quad * 8];      \
    _Pragma("unroll")                                                          \
    for (int i = 0; i < 4; ++i)                                                \
      _Pragma("unroll")                                                        \
      for (int j = 0; j < 4; ++j)                                              \
        acc[i][j] = __builtin_amdgcn_mfma_f32_16x16x32_bf16(af[i], bf[j], acc[i][j], 0, 0, 0); \
  }                                                                            \
  _Pragma("unroll")                                                            \
  for (int i = 0; i < 4; ++i) {                                                \
    _Pragma("unroll")                                                          \
    for (int j = 0; j < 4; ++j) {                                              \
      const int col = col0 + wcol + j * 16 + l16;                              \
      const float bs = bias[col];                                              \
      _Pragma("unroll")                                                        \
      for (int r = 0; r < 4; ++r) {                                            \
        const int row = row0 + wrow + i * 16 + quad * 4 + r;                   \
        STORE;                                                                 \
      }                                                                        \
    }                                                                          \
  }

__global__ __launch_bounds__(256) void gemm_bf16_nt(
    const __hip_bfloat16* __restrict__ A, const __hip_bfloat16* __restrict__ B,
    const float* __restrict__ bias, float* __restrict__ C,
    int M, int N, int K) {
  GEMM_BODY(C[(size_t)row * N + col] = acc[i][j][r] + bs)
}

__global__ __launch_bounds__(256) void gemm_bf16_nt_bf16out(
    const __hip_bfloat16* __restrict__ A, const __hip_bfloat16* __restrict__ B,
    const float* __restrict__ bias, __hip_bfloat16* __restrict__ C,
    int M, int N, int K) {
  GEMM_BODY(C[(size_t)row * N + col] = __float2bfloat16(acc[i][j][r] + bs))
}

// ---------------------------------------------------------------------------
// MFMA sliding-window attention.
// Block = one (b,h) x 64-query tile (4 waves x 16 queries). Key band
// [q0-128, q0+191] (320 keys, edge-masked) staged in LDS: K/Q as two 32-wide
// half-tiles (m97 layout), V transposed [dh][key]. QK^T and PV via
// mfma_f32_16x16x32_bf16; P round-trips through LDS (C-layout -> A-layout).
// ---------------------------------------------------------------------------
__global__ __launch_bounds__(256, 1) void attn_mfma(
    const __hip_bfloat16* __restrict__ qkv, __hip_bfloat16* __restrict__ attn) {
  __shared__ __attribute__((aligned(16))) __hip_bfloat16 QsA[64 * 32];
  __shared__ __attribute__((aligned(16))) __hip_bfloat16 QsB[64 * 32];
  __shared__ __attribute__((aligned(16))) __hip_bfloat16 KsA[320 * 32];
  __shared__ __attribute__((aligned(16))) __hip_bfloat16 KsB[320 * 32];
  __shared__ __attribute__((aligned(16))) __hip_bfloat16 Vt[64 * 328];
  __shared__ __attribute__((aligned(16))) __hip_bfloat16 Ps[4 * 16 * 328];

  const int tid  = threadIdx.x;
  const int lane = tid & 63;
  const int w    = tid >> 6;
  const int quad = lane >> 4;
  const int l16  = lane & 15;
  const int q0   = blockIdx.x * 64;
  const int h    = blockIdx.y;
  const int b    = blockIdx.z;
  const int kbase = q0 - WINW;   // may be negative; masked analytically

  // ---- staging (all waves cooperate; one barrier before compute) ----
  {
    const int r_ = tid >> 2;            // 0..63
    const int c8 = (tid & 3) * 8;       // 0,8,16,24
    {
      const __hip_bfloat16* src = qkv + ((size_t)(b * SS + q0 + r_)) * (3 * DD) + h * DHH;
      load16_lds(src + c8,      &QsA[r_ * 32 + c8]);
      load16_lds(src + 32 + c8, &QsB[r_ * 32 + c8]);
    }
#pragma unroll
    for (int it = 0; it < 5; ++it) {
      const int r = it * 64 + r_;
      int key = kbase + r; key = key < 0 ? 0 : (key > SS - 1 ? SS - 1 : key);
      const __hip_bfloat16* src = qkv + ((size_t)(b * SS + key)) * (3 * DD) + DD + h * DHH;
      load16_lds(src + c8,      &KsA[r * 32 + c8]);
      load16_lds(src + 32 + c8, &KsB[r * 32 + c8]);
    }
    const int k4 = (tid >> 3) * 4;      // band row base 0..124 step 4
    const int d8 = (tid & 7) * 8;       // dh octet
#pragma unroll
    for (int it = 0; it < 3; ++it) {
      const int rr = it * 128 + k4;
      if (rr < 320) {
        short8 v[4];
#pragma unroll
        for (int u = 0; u < 4; ++u) {
          int key = kbase + rr + u; key = key < 0 ? 0 : (key > SS - 1 ? SS - 1 : key);
          v[u] = *(const short8*)(qkv + ((size_t)(b * SS + key)) * (3 * DD) + 2 * DD + h * DHH + d8);
        }
#pragma unroll
        for (int j = 0; j < 8; ++j) {
          short4v pk; pk[0] = v[0][j]; pk[1] = v[1][j]; pk[2] = v[2][j]; pk[3] = v[3][j];
          *(short4v*)&Vt[(d8 + j) * 328 + rr] = pk;
        }
      }
    }
  }
  __syncthreads();

  // ---- QK^T: 20 key-tiles of 16, dh split 2x32 ----
  const short8 qf0 = *(const short8*)&QsA[(w * 16 + l16) * 32 + quad * 8];
  const short8 qf1 = *(const short8*)&QsB[(w * 16 + l16) * 32 + quad * 8];

  floatx4 sc[20];
#pragma unroll
  for (int kt = 0; kt < 20; ++kt) {
    const short8 bk0 = *(const short8*)&KsA[(kt * 16 + l16) * 32 + quad * 8];
    const short8 bk1 = *(const short8*)&KsB[(kt * 16 + l16) * 32 + quad * 8];
    floatx4 a = {};
    a = __builtin_amdgcn_mfma_f32_16x16x32_bf16(qf0, bk0, a, 0, 0, 0);
    a = __builtin_amdgcn_mfma_f32_16x16x32_bf16(qf1, bk1, a, 0, 0, 0);
    sc[kt] = a;
  }

  // ---- masked softmax (C-layout: col=l16 -> key, row=quad*4+r -> query) ----
  float mx[4] = {-1e30f, -1e30f, -1e30f, -1e30f};
#pragma unroll
  for (int kt = 0; kt < 20; ++kt) {
    const int key = kbase + kt * 16 + l16;
#pragma unroll
    for (int r = 0; r < 4; ++r) {
      const int qq = q0 + w * 16 + quad * 4 + r;
      const int dqk = qq - key;
      const bool ok = (key >= 0) & (key < SS) & (dqk <= WINW) & (dqk >= -WINW);
      const float s = ok ? sc[kt][r] * 0.125f : -1e30f;
      sc[kt][r] = s;
      mx[r] = fmaxf(mx[r], s);
    }
  }
#pragma unroll
  for (int off = 1; off < 16; off <<= 1)
#pragma unroll
    for (int r = 0; r < 4; ++r) mx[r] = fmaxf(mx[r], __shfl_xor(mx[r], off, 64));

  float sum[4] = {0.f, 0.f, 0.f, 0.f};
  __hip_bfloat16* Pw = &Ps[w * 16 * 328];
#pragma unroll
  for (int kt = 0; kt < 20; ++kt) {
#pragma unroll
    for (int r = 0; r < 4; ++r) {
      const float p = __expf(sc[kt][r] - mx[r]);
      sum[r] += p;
      Pw[(quad * 4 + r) * 328 + kt * 16 + l16] = __float2bfloat16(p);
    }
  }
#pragma unroll
  for (int off = 1; off < 16; off <<= 1)
#pragma unroll
    for (int r = 0; r < 4; ++r) sum[r] += __shfl_xor(sum[r], off, 64);

  // ---- PV: O[16q x 64dh] = P[16q x 320k] * Vt^T ----
  floatx4 ob[4] = {};
#pragma unroll
  for (int kt = 0; kt < 10; ++kt) {
    const short8 pf = *(const short8*)&Pw[l16 * 328 + kt * 32 + quad * 8];
#pragma unroll
    for (int t = 0; t < 4; ++t) {
      const short8 vf = *(const short8*)&Vt[(t * 16 + l16) * 328 + kt * 32 + quad * 8];
      ob[t] = __builtin_amdgcn_mfma_f32_16x16x32_bf16(pf, vf, ob[t], 0, 0, 0);
    }
  }

  float inv[4];
#pragma unroll
  for (int r = 0; r < 4; ++r) inv[r] = 1.f / sum[r];
  const int qq0 = q0 + w * 16 + quad * 4;
#pragma unroll
  for (int t = 0; t < 4; ++t)
#pragma unroll
    for (int r = 0; r < 4; ++r)
      attn[((size_t)(b * SS + qq0 + r)) * DD + h * DHH + t * 16 + l16] =
          __float2bfloat16(ob[t][r] * inv[r]);
}

// ---------------------------------------------------------------------------
// out = LayerNorm(a + b) * g + beta, row length D=1024, one block per row.
// ---------------------------------------------------------------------------
__global__ __launch_bounds__(256) void add_ln(
    const float* __restrict__ a, const float* __restrict__ b,
    const float* __restrict__ g, const float* __restrict__ be,
    float* __restrict__ out) {
  const int row = blockIdx.x;
  const int tid = threadIdx.x;
  const int lane = tid & 63;
  const int wave = tid >> 6;

  const float4 av = *(const float4*)(a + (size_t)row * DD + tid * 4);
  const float4 bv = *(const float4*)(b + (size_t)row * DD + tid * 4);
  float v[4] = {av.x + bv.x, av.y + bv.y, av.z + bv.z, av.w + bv.w};

  float s = v[0] + v[1] + v[2] + v[3];
  float s2 = v[0] * v[0] + v[1] * v[1] + v[2] * v[2] + v[3] * v[3];
#pragma unroll
  for (int off = 32; off; off >>= 1) {
    s += __shfl_xor(s, off, 64);
    s2 += __shfl_xor(s2, off, 64);
  }
  __shared__ float red[8];
  if (lane == 0) { red[wave] = s; red[4 + wave] = s2; }
  __syncthreads();
  s = red[0] + red[1] + red[2] + red[3];
  s2 = red[4] + red[5] + red[6] + red[7];

  const float mu = s * (1.f / DD);
  const float var = s2 * (1.f / DD) - mu * mu;
  const float r = rsqrtf(var + 1e-5f);

  const float4 gv = *(const float4*)(g + tid * 4);
  const float4 bev = *(const float4*)(be + tid * 4);
  float4 o;
  o.x = (v[0] - mu) * r * gv.x + bev.x;
  o.y = (v[1] - mu) * r * gv.y + bev.y;
  o.z = (v[2] - mu) * r * gv.z + bev.z;
  o.w = (v[3] - mu) * r * gv.w + bev.w;
  *(float4*)(out + (size_t)row * DD + tid * 4) = o;
}

// ---------------------------------------------------------------------------
// Spectral filter: per (b,d) signal of length 2048.
// DIF forward -> pointwise filter in bit-reversed order -> DIT inverse.
// ---------------------------------------------------------------------------
__global__ __launch_bounds__(256) void spec_filter(
    const float* __restrict__ x, const float* __restrict__ wr,
    const float* __restrict__ wi, float* __restrict__ y) {
  __shared__ float re[SS];
  __shared__ float im[SS];
  const int d = blockIdx.x;
  const int b = blockIdx.y;
  const int tid = threadIdx.x;

  const float* xp = x + (size_t)b * SS * DD + d;
  for (int s = tid; s < SS; s += 256) {
    re[s] = xp[(size_t)s * DD];
    im[s] = 0.f;
  }

  for (int stage = 11; stage >= 1; --stage) {
    __syncthreads();
    const int half = 1 << (stage - 1);
    const float ang0 = -6.283185307179586f / (float)(1 << stage);
    for (int t = tid; t < SS / 2; t += 256) {
      const int gI = t >> (stage - 1);
      const int p = t & (half - 1);
      const int i = (gI << stage) + p;
      const int j = i + half;
      float sn, c;
      __sincosf(ang0 * (float)p, &sn, &c);
      const float ar = re[i], ai = im[i], br = re[j], bi = im[j];
      re[i] = ar + br; im[i] = ai + bi;
      const float dr = ar - br, di = ai - bi;
      re[j] = dr * c - di * sn;
      im[j] = dr * sn + di * c;
    }
  }
  __syncthreads();

  for (int p = tid; p < SS; p += 256) {
    const int k = __brev((unsigned)p) >> 21;
    float wre, wim;
    if (k <= SS / 2) {
      wre = wr[(size_t)k * DD + d];
      wim = wi[(size_t)k * DD + d];
    } else {
      wre = wr[(size_t)(SS - k) * DD + d];
      wim = -wi[(size_t)(SS - k) * DD + d];
    }
    const float ar = re[p], ai = im[p];
    re[p] = ar * wre - ai * wim;
    im[p] = ar * wim + ai * wre;
  }

  for (int stage = 1; stage <= 11; ++stage) {
    __syncthreads();
    const int half = 1 << (stage - 1);
    const float ang0 = 6.283185307179586f / (float)(1 << stage);
    for (int t = tid; t < SS / 2; t += 256) {
      const int gI = t >> (stage - 1);
      const int p = t & (half - 1);
      const int i = (gI << stage) + p;
      const int j = i + half;
      float sn, c;
      __sincosf(ang0 * (float)p, &sn, &c);
      const float br = re[j], bi = im[j];
      const float tr = br * c - bi * sn;
      const float ti = br * sn + bi * c;
      const float ar = re[i], ai = im[i];
      re[i] = ar + tr; im[i] = ai + ti;
      re[j] = ar - tr; im[j] = ai - ti;
    }
  }
  __syncthreads();

  float* yp = y + (size_t)b * SS * DD + d;
  const float scale = 1.f / (float)SS;
  for (int s = tid; s < SS; s += 256) yp[(size_t)s * DD] = re[s] * scale;
}

// ---------------------------------------------------------------------------
extern "C" void kernel_launch(void* const* d_in, const int* in_sizes, int n_in,
                              void* d_out, int out_size, void* d_ws, size_t ws_size,
                              hipStream_t stream) {
  const float* x     = (const float*)d_in[0];
  const float* in_w  = (const float*)d_in[1];
  const float* in_b  = (const float*)d_in[2];
  const float* out_w = (const float*)d_in[3];
  const float* out_b = (const float*)d_in[4];
  const float* ln1_g = (const float*)d_in[5];
  const float* ln1_b = (const float*)d_in[6];
  const float* wr    = (const float*)d_in[7];
  const float* wi    = (const float*)d_in[8];
  const float* ln2_g = (const float*)d_in[9];
  const float* ln2_b = (const float*)d_in[10];
  float* out = (float*)d_out;

  char* ws = (char*)d_ws;
  // Workspace phases (64 MB):
  //  [0,24)   qkv_bf16 [4096x3072]      -> dead after attn -> x_attn fp32 [0,16)
  //  [24,32)  attn_bf16 [4096x1024]     -> dead after GEMM2 \
  //  [32,40)  x_bf16                    -> dead after GEMM1  } x_wave fp32 [24,40)
  //  [40,46)  in_w bf16 ; [46,48) out_w bf16 (dead after GEMMs)
  //  [48,64)  attn_out fp32 [4096x1024]
  __hip_bfloat16* qkv_bf   = (__hip_bfloat16*)(ws);
  __hip_bfloat16* attn_bf  = (__hip_bfloat16*)(ws + 25165824);
  __hip_bfloat16* x_bf     = (__hip_bfloat16*)(ws + 33554432);
  __hip_bfloat16* w_in_bf  = (__hip_bfloat16*)(ws + 41943040);
  __hip_bfloat16* w_out_bf = (__hip_bfloat16*)(ws + 48234496);
  float* attn_out = (float*)(ws + 50331648);
  float* x_attn   = (float*)(ws);
  float* x_wave   = (float*)(ws + 25165824);

  // 0. casts to bf16
  cast_f32_bf16<<<4194304 / 1024, 256, 0, stream>>>(x, x_bf, 4194304);
  cast_f32_bf16<<<3145728 / 1024, 256, 0, stream>>>(in_w, w_in_bf, 3145728);
  cast_f32_bf16<<<1048576 / 1024, 256, 0, stream>>>(out_w, w_out_bf, 1048576);

  // 1. qkv = x @ in_w^T + in_b   -> bf16 [4096, 3072]
  gemm_bf16_nt_bf16out<<<dim3(3072 / 128, MROWS / 128), 256, 0, stream>>>(
      x_bf, w_in_bf, in_b, qkv_bf, MROWS, 3 * DD, DD);

  // 2. MFMA sliding-window attention -> bf16 [4096, 1024]
  attn_mfma<<<dim3(SS / 64, HH, BB), 256, 0, stream>>>(qkv_bf, attn_bf);

  // 3. attn_out = attn @ out_w^T + out_b   (fp32)
  gemm_bf16_nt<<<dim3(DD / 128, MROWS / 128), 256, 0, stream>>>(
      attn_bf, w_out_bf, out_b, attn_out, MROWS, DD, DD);

  // 4. x_attn = LN1(x + attn_out)
  add_ln<<<MROWS, 256, 0, stream>>>(x, attn_out, ln1_g, ln1_b, x_attn);

  // 5. x_wave = irfft(rfft(x) * Wc)
  spec_filter<<<dim3(DD, BB), 256, 0, stream>>>(x, wr, wi, x_wave);

  // 6. out = LN2(x_attn + x_wave)
  add_ln<<<MROWS, 256, 0, stream>>>(x_attn, x_wave, ln2_g, ln2_b, out);
}

// Round 4
// 303.489 us; speedup vs baseline: 5.1697x; 1.1093x over previous
//
#include <hip/hip_runtime.h>
#include <hip/hip_bf16.h>
#include <math.h>

// Problem constants (B,S,D,H,WIN) = (2,2048,1024,16,128), DH=64
#define BB    2
#define SS    2048
#define DD    1024
#define HH    16
#define DHH   64
#define WINW  128
#define MROWS (BB * SS)          // 4096

typedef __attribute__((ext_vector_type(8))) short short8;
typedef __attribute__((ext_vector_type(4))) short short4v;
typedef __attribute__((ext_vector_type(4))) float floatx4;

// ---------------------------------------------------------------------------
// fp32 -> bf16 cast, 4 elems/thread
// ---------------------------------------------------------------------------
__global__ __launch_bounds__(256) void cast_f32_bf16(
    const float* __restrict__ in, __hip_bfloat16* __restrict__ out, int n) {
  const int i = (blockIdx.x * 256 + threadIdx.x) * 4;
  if (i < n) {
    const float4 v = *(const float4*)(in + i);
    out[i + 0] = __float2bfloat16(v.x);
    out[i + 1] = __float2bfloat16(v.y);
    out[i + 2] = __float2bfloat16(v.z);
    out[i + 3] = __float2bfloat16(v.w);
  }
}

// ---------------------------------------------------------------------------
// fp32 transpose: src[R][C] -> dst[C][R], 64x64 tiles, batch via blockIdx.z.
// C must be a multiple of 64; R is bounds-checked (wr/wi have R=1025).
// ---------------------------------------------------------------------------
__global__ __launch_bounds__(256) void transpose_f32(
    const float* __restrict__ src, float* __restrict__ dst, int R, int C) {
  __shared__ float tile[64][65];
  const size_t base = (size_t)blockIdx.z * R * C;
  const int c0 = blockIdx.x * 64;
  const int r0 = blockIdx.y * 64;
  const int tx = threadIdx.x & 63;
  const int ty = threadIdx.x >> 6;   // 0..3
#pragma unroll
  for (int i = 0; i < 16; ++i) {
    const int r = ty * 16 + i;
    if (r0 + r < R)
      tile[r][tx] = src[base + (size_t)(r0 + r) * C + c0 + tx];
  }
  __syncthreads();
#pragma unroll
  for (int i = 0; i < 16; ++i) {
    const int c = ty * 16 + i;
    if (r0 + tx < R)
      dst[base + (size_t)(c0 + c) * R + r0 + tx] = tile[tx][c];
  }
}

// ---------------------------------------------------------------------------
__device__ inline void load16_lds(const __hip_bfloat16* g, __hip_bfloat16* l) {
  __builtin_amdgcn_global_load_lds(
      (const __attribute__((address_space(1))) uint32_t*)g,
      (__attribute__((address_space(3))) uint32_t*)l, 16, 0, 0);
}

// ---------------------------------------------------------------------------
// bf16 MFMA GEMM (NT): C[M,N] = A[M,K] * B[N,K]^T + bias[N]
// 128x128 tile, BK=32, 256 threads (4 waves 2x2), mfma_f32_16x16x32_bf16.
// ---------------------------------------------------------------------------
#define GEMM_BODY(STORE)                                                       \
  __shared__ __attribute__((aligned(16))) __hip_bfloat16 As[128 * 32];         \
  __shared__ __attribute__((aligned(16))) __hip_bfloat16 Bs[128 * 32];         \
  const int tid  = threadIdx.x;                                                \
  const int lane = tid & 63;                                                   \
  const int wave = tid >> 6;                                                   \
  const int wrow = (wave >> 1) * 64;                                           \
  const int wcol = (wave & 1) * 64;                                            \
  const int row0 = blockIdx.y * 128;                                           \
  const int col0 = blockIdx.x * 128;                                           \
  const int srow = tid >> 2;                                                   \
  const int skk  = (tid & 3) * 8;                                              \
  const int quad = lane >> 4;                                                  \
  const int l16  = lane & 15;                                                  \
  floatx4 acc[4][4] = {};                                                      \
  for (int k0 = 0; k0 < K; k0 += 32) {                                         \
    __syncthreads();                                                           \
    load16_lds(A + (size_t)(row0 + srow) * K + k0 + skk,      &As[tid * 8]);   \
    load16_lds(A + (size_t)(row0 + 64 + srow) * K + k0 + skk, &As[2048 + tid * 8]); \
    load16_lds(B + (size_t)(col0 + srow) * K + k0 + skk,      &Bs[tid * 8]);   \
    load16_lds(B + (size_t)(col0 + 64 + srow) * K + k0 + skk, &Bs[2048 + tid * 8]); \
    __syncthreads();                                                           \
    short8 af[4], bf[4];                                                       \
    _Pragma("unroll")                                                          \
    for (int i = 0; i < 4; ++i)                                                \
      af[i] = *(const short8*)&As[(wrow + i * 16 + l16) * 32 + quad * 8];      \
    _Pragma("unroll")                                                          \
    for (int j = 0; j < 4; ++j)                                                \
      bf[j] = *(const short8*)&Bs[(wcol + j * 16 + l16) * 32 + quad * 8];      \
    _Pragma("unroll")                                                          \
    for (int i = 0; i < 4; ++i)                                                \
      _Pragma("unroll")                                                        \
      for (int j = 0; j < 4; ++j)                                              \
        acc[i][j] = __builtin_amdgcn_mfma_f32_16x16x32_bf16(af[i], bf[j], acc[i][j], 0, 0, 0); \
  }                                                                            \
  _Pragma("unroll")                                                            \
  for (int i = 0; i < 4; ++i) {                                                \
    _Pragma("unroll")                                                          \
    for (int j = 0; j < 4; ++j) {                                              \
      const int col = col0 + wcol + j * 16 + l16;                              \
      const float bs = bias[col];                                              \
      _Pragma("unroll")                                                        \
      for (int r = 0; r < 4; ++r) {                                            \
        const int row = row0 + wrow + i * 16 + quad * 4 + r;                   \
        STORE;                                                                 \
      }                                                                        \
    }                                                                          \
  }

__global__ __launch_bounds__(256) void gemm_bf16_nt(
    const __hip_bfloat16* __restrict__ A, const __hip_bfloat16* __restrict__ B,
    const float* __restrict__ bias, float* __restrict__ C,
    int M, int N, int K) {
  GEMM_BODY(C[(size_t)row * N + col] = acc[i][j][r] + bs)
}

__global__ __launch_bounds__(256) void gemm_bf16_nt_bf16out(
    const __hip_bfloat16* __restrict__ A, const __hip_bfloat16* __restrict__ B,
    const float* __restrict__ bias, __hip_bfloat16* __restrict__ C,
    int M, int N, int K) {
  GEMM_BODY(C[(size_t)row * N + col] = __float2bfloat16(acc[i][j][r] + bs))
}

// ---------------------------------------------------------------------------
// MFMA sliding-window attention (unchanged from R3).
// ---------------------------------------------------------------------------
__global__ __launch_bounds__(256, 1) void attn_mfma(
    const __hip_bfloat16* __restrict__ qkv, __hip_bfloat16* __restrict__ attn) {
  __shared__ __attribute__((aligned(16))) __hip_bfloat16 QsA[64 * 32];
  __shared__ __attribute__((aligned(16))) __hip_bfloat16 QsB[64 * 32];
  __shared__ __attribute__((aligned(16))) __hip_bfloat16 KsA[320 * 32];
  __shared__ __attribute__((aligned(16))) __hip_bfloat16 KsB[320 * 32];
  __shared__ __attribute__((aligned(16))) __hip_bfloat16 Vt[64 * 328];
  __shared__ __attribute__((aligned(16))) __hip_bfloat16 Ps[4 * 16 * 328];

  const int tid  = threadIdx.x;
  const int lane = tid & 63;
  const int w    = tid >> 6;
  const int quad = lane >> 4;
  const int l16  = lane & 15;
  const int q0   = blockIdx.x * 64;
  const int h    = blockIdx.y;
  const int b    = blockIdx.z;
  const int kbase = q0 - WINW;

  {
    const int r_ = tid >> 2;
    const int c8 = (tid & 3) * 8;
    {
      const __hip_bfloat16* src = qkv + ((size_t)(b * SS + q0 + r_)) * (3 * DD) + h * DHH;
      load16_lds(src + c8,      &QsA[r_ * 32 + c8]);
      load16_lds(src + 32 + c8, &QsB[r_ * 32 + c8]);
    }
#pragma unroll
    for (int it = 0; it < 5; ++it) {
      const int r = it * 64 + r_;
      int key = kbase + r; key = key < 0 ? 0 : (key > SS - 1 ? SS - 1 : key);
      const __hip_bfloat16* src = qkv + ((size_t)(b * SS + key)) * (3 * DD) + DD + h * DHH;
      load16_lds(src + c8,      &KsA[r * 32 + c8]);
      load16_lds(src + 32 + c8, &KsB[r * 32 + c8]);
    }
    const int k4 = (tid >> 3) * 4;
    const int d8 = (tid & 7) * 8;
#pragma unroll
    for (int it = 0; it < 3; ++it) {
      const int rr = it * 128 + k4;
      if (rr < 320) {
        short8 v[4];
#pragma unroll
        for (int u = 0; u < 4; ++u) {
          int key = kbase + rr + u; key = key < 0 ? 0 : (key > SS - 1 ? SS - 1 : key);
          v[u] = *(const short8*)(qkv + ((size_t)(b * SS + key)) * (3 * DD) + 2 * DD + h * DHH + d8);
        }
#pragma unroll
        for (int j = 0; j < 8; ++j) {
          short4v pk; pk[0] = v[0][j]; pk[1] = v[1][j]; pk[2] = v[2][j]; pk[3] = v[3][j];
          *(short4v*)&Vt[(d8 + j) * 328 + rr] = pk;
        }
      }
    }
  }
  __syncthreads();

  const short8 qf0 = *(const short8*)&QsA[(w * 16 + l16) * 32 + quad * 8];
  const short8 qf1 = *(const short8*)&QsB[(w * 16 + l16) * 32 + quad * 8];

  floatx4 sc[20];
#pragma unroll
  for (int kt = 0; kt < 20; ++kt) {
    const short8 bk0 = *(const short8*)&KsA[(kt * 16 + l16) * 32 + quad * 8];
    const short8 bk1 = *(const short8*)&KsB[(kt * 16 + l16) * 32 + quad * 8];
    floatx4 a = {};
    a = __builtin_amdgcn_mfma_f32_16x16x32_bf16(qf0, bk0, a, 0, 0, 0);
    a = __builtin_amdgcn_mfma_f32_16x16x32_bf16(qf1, bk1, a, 0, 0, 0);
    sc[kt] = a;
  }

  float mx[4] = {-1e30f, -1e30f, -1e30f, -1e30f};
#pragma unroll
  for (int kt = 0; kt < 20; ++kt) {
    const int key = kbase + kt * 16 + l16;
#pragma unroll
    for (int r = 0; r < 4; ++r) {
      const int qq = q0 + w * 16 + quad * 4 + r;
      const int dqk = qq - key;
      const bool ok = (key >= 0) & (key < SS) & (dqk <= WINW) & (dqk >= -WINW);
      const float s = ok ? sc[kt][r] * 0.125f : -1e30f;
      sc[kt][r] = s;
      mx[r] = fmaxf(mx[r], s);
    }
  }
#pragma unroll
  for (int off = 1; off < 16; off <<= 1)
#pragma unroll
    for (int r = 0; r < 4; ++r) mx[r] = fmaxf(mx[r], __shfl_xor(mx[r], off, 64));

  float sum[4] = {0.f, 0.f, 0.f, 0.f};
  __hip_bfloat16* Pw = &Ps[w * 16 * 328];
#pragma unroll
  for (int kt = 0; kt < 20; ++kt) {
#pragma unroll
    for (int r = 0; r < 4; ++r) {
      const float p = __expf(sc[kt][r] - mx[r]);
      sum[r] += p;
      Pw[(quad * 4 + r) * 328 + kt * 16 + l16] = __float2bfloat16(p);
    }
  }
#pragma unroll
  for (int off = 1; off < 16; off <<= 1)
#pragma unroll
    for (int r = 0; r < 4; ++r) sum[r] += __shfl_xor(sum[r], off, 64);

  floatx4 ob[4] = {};
#pragma unroll
  for (int kt = 0; kt < 10; ++kt) {
    const short8 pf = *(const short8*)&Pw[l16 * 328 + kt * 32 + quad * 8];
#pragma unroll
    for (int t = 0; t < 4; ++t) {
      const short8 vf = *(const short8*)&Vt[(t * 16 + l16) * 328 + kt * 32 + quad * 8];
      ob[t] = __builtin_amdgcn_mfma_f32_16x16x32_bf16(pf, vf, ob[t], 0, 0, 0);
    }
  }

  float inv[4];
#pragma unroll
  for (int r = 0; r < 4; ++r) inv[r] = 1.f / sum[r];
  const int qq0 = q0 + w * 16 + quad * 4;
#pragma unroll
  for (int t = 0; t < 4; ++t)
#pragma unroll
    for (int r = 0; r < 4; ++r)
      attn[((size_t)(b * SS + qq0 + r)) * DD + h * DHH + t * 16 + l16] =
          __float2bfloat16(ob[t][r] * inv[r]);
}

// ---------------------------------------------------------------------------
// out = LayerNorm(a + b) * g + beta, row length D=1024, one block per row.
// ---------------------------------------------------------------------------
__global__ __launch_bounds__(256) void add_ln(
    const float* __restrict__ a, const float* __restrict__ b,
    const float* __restrict__ g, const float* __restrict__ be,
    float* __restrict__ out) {
  const int row = blockIdx.x;
  const int tid = threadIdx.x;
  const int lane = tid & 63;
  const int wave = tid >> 6;

  const float4 av = *(const float4*)(a + (size_t)row * DD + tid * 4);
  const float4 bv = *(const float4*)(b + (size_t)row * DD + tid * 4);
  float v[4] = {av.x + bv.x, av.y + bv.y, av.z + bv.z, av.w + bv.w};

  float s = v[0] + v[1] + v[2] + v[3];
  float s2 = v[0] * v[0] + v[1] * v[1] + v[2] * v[2] + v[3] * v[3];
#pragma unroll
  for (int off = 32; off; off >>= 1) {
    s += __shfl_xor(s, off, 64);
    s2 += __shfl_xor(s2, off, 64);
  }
  __shared__ float red[8];
  if (lane == 0) { red[wave] = s; red[4 + wave] = s2; }
  __syncthreads();
  s = red[0] + red[1] + red[2] + red[3];
  s2 = red[4] + red[5] + red[6] + red[7];

  const float mu = s * (1.f / DD);
  const float var = s2 * (1.f / DD) - mu * mu;
  const float r = rsqrtf(var + 1e-5f);

  const float4 gv = *(const float4*)(g + tid * 4);
  const float4 bev = *(const float4*)(be + tid * 4);
  float4 o;
  o.x = (v[0] - mu) * r * gv.x + bev.x;
  o.y = (v[1] - mu) * r * gv.y + bev.y;
  o.z = (v[2] - mu) * r * gv.z + bev.z;
  o.w = (v[3] - mu) * r * gv.w + bev.w;
  *(float4*)(out + (size_t)row * DD + tid * 4) = o;
}

// ---------------------------------------------------------------------------
// Spectral filter on transposed data, two real columns packed as one complex
// FFT. xT layout [B][D][S] (fp32), in-place. wrT/wiT are [D][1025].
// Forward DIF (natural->bitrev), packed Hermitian filter, inverse DIT
// (bitrev->natural, conjugate twiddles), scale 1/S.
// DC/Nyquist bins forced real == irfft semantics (Re(ifft) independent of
// their imaginary parts).
// ---------------------------------------------------------------------------
__global__ __launch_bounds__(256) void spec_fft_pair(
    float* __restrict__ xT, const float* __restrict__ wrT,
    const float* __restrict__ wiT) {
  __shared__ float re[SS], im[SS];
  __shared__ float twc[SS / 2], tws[SS / 2];
  const int tid = threadIdx.x;
  const int d0 = blockIdx.x * 2, d1 = d0 + 1;
  const int b = blockIdx.y;
  float* col0 = xT + ((size_t)b * DD + d0) * SS;
  float* col1 = xT + ((size_t)b * DD + d1) * SS;

  for (int s4 = tid * 4; s4 < SS; s4 += 1024) {
    const float4 a = *(const float4*)(col0 + s4);
    const float4 c = *(const float4*)(col1 + s4);
    re[s4] = a.x; re[s4 + 1] = a.y; re[s4 + 2] = a.z; re[s4 + 3] = a.w;
    im[s4] = c.x; im[s4 + 1] = c.y; im[s4 + 2] = c.z; im[s4 + 3] = c.w;
  }
  for (int j = tid; j < SS / 2; j += 256) {
    float sn, cs;
    __sincosf(-6.283185307179586f * (float)j / (float)SS, &sn, &cs);
    twc[j] = cs; tws[j] = sn;   // e^{-2*pi*i*j/S}
  }

  // forward DIF
  for (int stage = 11; stage >= 1; --stage) {
    __syncthreads();
    const int half = 1 << (stage - 1);
    for (int t = tid; t < SS / 2; t += 256) {
      const int gI = t >> (stage - 1);
      const int p = t & (half - 1);
      const int i = (gI << stage) + p;
      const int j = i + half;
      const int tj = p << (11 - stage);
      const float c = twc[tj], s = tws[tj];
      const float ar = re[i], ai = im[i], br = re[j], bi = im[j];
      re[i] = ar + br; im[i] = ai + bi;
      const float dr = ar - br, di = ai - bi;
      re[j] = dr * c - di * s;
      im[j] = dr * s + di * c;
    }
  }
  __syncthreads();

  // packed Hermitian filter: Z = Z0 + i*Z1; Y0=Z0*W0, Y1=Z1*W1; Y=Y0+i*Y1.
  const float* w0r = wrT + (size_t)d0 * 1025;
  const float* w0i = wiT + (size_t)d0 * 1025;
  const float* w1r = wrT + (size_t)d1 * 1025;
  const float* w1i = wiT + (size_t)d1 * 1025;
  for (int k = tid; k < 1024; k += 256) {
    if (k == 0) {
      re[0] *= w0r[0];            // DC (bitrev pos 0), real
      im[0] *= w1r[0];
      re[1] *= w0r[1024];         // Nyquist (bitrev pos 1), real
      im[1] *= w1r[1024];
    } else {
      const int p1 = __brev((unsigned)k) >> 21;
      const int p2 = __brev((unsigned)(SS - k)) >> 21;
      const float ra = re[p1], ia = im[p1];
      const float rb = re[p2], ib = im[p2];
      const float z0r = 0.5f * (ra + rb), z0i = 0.5f * (ia - ib);
      const float z1r = 0.5f * (ia + ib), z1i = -0.5f * (ra - rb);
      const float a0 = w0r[k], b0 = w0i[k];
      const float a1 = w1r[k], b1 = w1i[k];
      const float y0r = z0r * a0 - z0i * b0, y0i = z0r * b0 + z0i * a0;
      const float y1r = z1r * a1 - z1i * b1, y1i = z1r * b1 + z1i * a1;
      re[p1] = y0r - y1i; im[p1] = y0i + y1r;
      re[p2] = y0r + y1i; im[p2] = y1r - y0i;
    }
  }

  // inverse DIT (conjugate twiddles)
  for (int stage = 1; stage <= 11; ++stage) {
    __syncthreads();
    const int half = 1 << (stage - 1);
    for (int t = tid; t < SS / 2; t += 256) {
      const int gI = t >> (stage - 1);
      const int p = t & (half - 1);
      const int i = (gI << stage) + p;
      const int j = i + half;
      const int tj = p << (11 - stage);
      const float c = twc[tj], s = tws[tj];
      const float br = re[j], bi = im[j];
      const float tr = br * c + bi * s;
      const float ti = bi * c - br * s;
      const float ar = re[i], ai = im[i];
      re[i] = ar + tr; im[i] = ai + ti;
      re[j] = ar - tr; im[j] = ai - ti;
    }
  }
  __syncthreads();

  const float scale = 1.0f / (float)SS;
  for (int s4 = tid * 4; s4 < SS; s4 += 1024) {
    float4 a, c;
    a.x = re[s4] * scale; a.y = re[s4 + 1] * scale;
    a.z = re[s4 + 2] * scale; a.w = re[s4 + 3] * scale;
    c.x = im[s4] * scale; c.y = im[s4 + 1] * scale;
    c.z = im[s4 + 2] * scale; c.w = im[s4 + 3] * scale;
    *(float4*)(col0 + s4) = a;
    *(float4*)(col1 + s4) = c;
  }
}

// ---------------------------------------------------------------------------
extern "C" void kernel_launch(void* const* d_in, const int* in_sizes, int n_in,
                              void* d_out, int out_size, void* d_ws, size_t ws_size,
                              hipStream_t stream) {
  const float* x     = (const float*)d_in[0];
  const float* in_w  = (const float*)d_in[1];
  const float* in_b  = (const float*)d_in[2];
  const float* out_w = (const float*)d_in[3];
  const float* out_b = (const float*)d_in[4];
  const float* ln1_g = (const float*)d_in[5];
  const float* ln1_b = (const float*)d_in[6];
  const float* wr    = (const float*)d_in[7];
  const float* wi    = (const float*)d_in[8];
  const float* ln2_g = (const float*)d_in[9];
  const float* ln2_b = (const float*)d_in[10];
  float* out = (float*)d_out;

  char* ws = (char*)d_ws;
  // Workspace phases (<= 64 MB):
  //  [0,24)   qkv_bf16          -> dead after attn  -> x_attn fp32 [0,16)
  //  [24,32)  attn_bf16         -> dead after GEMM2 -> x_wave fp32 [16,32)
  //  [32,40)  x_bf16, [40,46) in_w bf16, [46,48) out_w bf16
  //           -> all dead after GEMM2 -> xT fp32 [32,48) (FFT in place)
  //  [48,64)  attn_out fp32     -> dead after LN1   -> wrT/wiT [48,56.4)
  __hip_bfloat16* qkv_bf   = (__hip_bfloat16*)(ws);
  __hip_bfloat16* attn_bf  = (__hip_bfloat16*)(ws + 25165824);
  __hip_bfloat16* x_bf     = (__hip_bfloat16*)(ws + 33554432);
  __hip_bfloat16* w_in_bf  = (__hip_bfloat16*)(ws + 41943040);
  __hip_bfloat16* w_out_bf = (__hip_bfloat16*)(ws + 48234496);
  float* attn_out = (float*)(ws + 50331648);
  float* x_attn   = (float*)(ws);
  float* x_wave   = (float*)(ws + 16777216);
  float* xT       = (float*)(ws + 33554432);
  float* wrT      = (float*)(ws + 50331648);
  float* wiT      = (float*)(ws + 54530048);

  // 0. casts to bf16
  cast_f32_bf16<<<4194304 / 1024, 256, 0, stream>>>(x, x_bf, 4194304);
  cast_f32_bf16<<<3145728 / 1024, 256, 0, stream>>>(in_w, w_in_bf, 3145728);
  cast_f32_bf16<<<1048576 / 1024, 256, 0, stream>>>(out_w, w_out_bf, 1048576);

  // 1. qkv = x @ in_w^T + in_b   -> bf16 [4096, 3072]
  gemm_bf16_nt_bf16out<<<dim3(3072 / 128, MROWS / 128), 256, 0, stream>>>(
      x_bf, w_in_bf, in_b, qkv_bf, MROWS, 3 * DD, DD);

  // 2. MFMA sliding-window attention -> bf16 [4096, 1024]
  attn_mfma<<<dim3(SS / 64, HH, BB), 256, 0, stream>>>(qkv_bf, attn_bf);

  // 3. attn_out = attn @ out_w^T + out_b   (fp32)
  gemm_bf16_nt<<<dim3(DD / 128, MROWS / 128), 256, 0, stream>>>(
      attn_bf, w_out_bf, out_b, attn_out, MROWS, DD, DD);

  // 4. x_attn = LN1(x + attn_out)
  add_ln<<<MROWS, 256, 0, stream>>>(x, attn_out, ln1_g, ln1_b, x_attn);

  // 5a. transposes: x [S][D] -> xT [D][S] per batch; wr/wi [1025][D] -> [D][1025]
  transpose_f32<<<dim3(16, 32, 2), 256, 0, stream>>>(x, xT, SS, DD);
  transpose_f32<<<dim3(16, 17, 1), 256, 0, stream>>>(wr, wrT, 1025, DD);
  transpose_f32<<<dim3(16, 17, 1), 256, 0, stream>>>(wi, wiT, 1025, DD);

  // 5b. packed-pair FFT filter, in place on xT
  spec_fft_pair<<<dim3(DD / 2, BB), 256, 0, stream>>>(xT, wrT, wiT);

  // 5c. transpose back: xT [D][S] -> x_wave [S][D]
  transpose_f32<<<dim3(32, 16, 2), 256, 0, stream>>>(xT, x_wave, DD, SS);

  // 6. out = LN2(x_attn + x_wave)
  add_ln<<<MROWS, 256, 0, stream>>>(x_attn, x_wave, ln2_g, ln2_b, out);
}

// Round 5
// 280.161 us; speedup vs baseline: 5.6002x; 1.0833x over previous
//
#include <hip/hip_runtime.h>
#include <hip/hip_bf16.h>
#include <math.h>

// Problem constants (B,S,D,H,WIN) = (2,2048,1024,16,128), DH=64
#define BB    2
#define SS    2048
#define DD    1024
#define HH    16
#define DHH   64
#define WINW  128
#define MROWS (BB * SS)          // 4096

typedef __attribute__((ext_vector_type(8))) short short8;
typedef __attribute__((ext_vector_type(4))) short short4v;
typedef __attribute__((ext_vector_type(4))) float floatx4;

// ---------------------------------------------------------------------------
// fp32 -> bf16 cast, 4 elems/thread
// ---------------------------------------------------------------------------
__global__ __launch_bounds__(256) void cast_f32_bf16(
    const float* __restrict__ in, __hip_bfloat16* __restrict__ out, int n) {
  const int i = (blockIdx.x * 256 + threadIdx.x) * 4;
  if (i < n) {
    const float4 v = *(const float4*)(in + i);
    out[i + 0] = __float2bfloat16(v.x);
    out[i + 1] = __float2bfloat16(v.y);
    out[i + 2] = __float2bfloat16(v.z);
    out[i + 3] = __float2bfloat16(v.w);
  }
}

// ---------------------------------------------------------------------------
// fp32 transpose: src[R][C] -> dst[C][R], 64x64 tiles, batch via blockIdx.z.
// ---------------------------------------------------------------------------
__global__ __launch_bounds__(256) void transpose_f32(
    const float* __restrict__ src, float* __restrict__ dst, int R, int C) {
  __shared__ float tile[64][65];
  const size_t base = (size_t)blockIdx.z * R * C;
  const int c0 = blockIdx.x * 64;
  const int r0 = blockIdx.y * 64;
  const int tx = threadIdx.x & 63;
  const int ty = threadIdx.x >> 6;   // 0..3
#pragma unroll
  for (int i = 0; i < 16; ++i) {
    const int r = ty * 16 + i;
    if (r0 + r < R)
      tile[r][tx] = src[base + (size_t)(r0 + r) * C + c0 + tx];
  }
  __syncthreads();
#pragma unroll
  for (int i = 0; i < 16; ++i) {
    const int c = ty * 16 + i;
    if (r0 + tx < R)
      dst[base + (size_t)(c0 + c) * R + r0 + tx] = tile[tx][c];
  }
}

// ---------------------------------------------------------------------------
__device__ inline void load16_lds(const __hip_bfloat16* g, __hip_bfloat16* l) {
  __builtin_amdgcn_global_load_lds(
      (const __attribute__((address_space(1))) uint32_t*)g,
      (__attribute__((address_space(3))) uint32_t*)l, 16, 0, 0);
}

// ---------------------------------------------------------------------------
// bf16 MFMA GEMM (NT): C[M,N] = A[M,K] * B[N,K]^T + bias[N]
// 128x128 tile, BK=32, 256 threads (4 waves 2x2), mfma_f32_16x16x32_bf16.
// ---------------------------------------------------------------------------
#define GEMM_BODY(STORE)                                                       \
  __shared__ __attribute__((aligned(16))) __hip_bfloat16 As[128 * 32];         \
  __shared__ __attribute__((aligned(16))) __hip_bfloat16 Bs[128 * 32];         \
  const int tid  = threadIdx.x;                                                \
  const int lane = tid & 63;                                                   \
  const int wave = tid >> 6;                                                   \
  const int wrow = (wave >> 1) * 64;                                           \
  const int wcol = (wave & 1) * 64;                                            \
  const int row0 = blockIdx.y * 128;                                           \
  const int col0 = blockIdx.x * 128;                                           \
  const int srow = tid >> 2;                                                   \
  const int skk  = (tid & 3) * 8;                                              \
  const int quad = lane >> 4;                                                  \
  const int l16  = lane & 15;                                                  \
  floatx4 acc[4][4] = {};                                                      \
  for (int k0 = 0; k0 < K; k0 += 32) {                                         \
    __syncthreads();                                                           \
    load16_lds(A + (size_t)(row0 + srow) * K + k0 + skk,      &As[tid * 8]);   \
    load16_lds(A + (size_t)(row0 + 64 + srow) * K + k0 + skk, &As[2048 + tid * 8]); \
    load16_lds(B + (size_t)(col0 + srow) * K + k0 + skk,      &Bs[tid * 8]);   \
    load16_lds(B + (size_t)(col0 + 64 + srow) * K + k0 + skk, &Bs[2048 + tid * 8]); \
    __syncthreads();                                                           \
    short8 af[4], bf[4];                                                       \
    _Pragma("unroll")                                                          \
    for (int i = 0; i < 4; ++i)                                                \
      af[i] = *(const short8*)&As[(wrow + i * 16 + l16) * 32 + quad * 8];      \
    _Pragma("unroll")                                                          \
    for (int j = 0; j < 4; ++j)                                                \
      bf[j] = *(const short8*)&Bs[(wcol + j * 16 + l16) * 32 + quad * 8];      \
    _Pragma("unroll")                                                          \
    for (int i = 0; i < 4; ++i)                                                \
      _Pragma("unroll")                                                        \
      for (int j = 0; j < 4; ++j)                                              \
        acc[i][j] = __builtin_amdgcn_mfma_f32_16x16x32_bf16(af[i], bf[j], acc[i][j], 0, 0, 0); \
  }                                                                            \
  _Pragma("unroll")                                                            \
  for (int i = 0; i < 4; ++i) {                                                \
    _Pragma("unroll")                                                          \
    for (int j = 0; j < 4; ++j) {                                              \
      const int col = col0 + wcol + j * 16 + l16;                              \
      const float bs = bias[col];                                              \
      _Pragma("unroll")                                                        \
      for (int r = 0; r < 4; ++r) {                                            \
        const int row = row0 + wrow + i * 16 + quad * 4 + r;                   \
        STORE;                                                                 \
      }                                                                        \
    }                                                                          \
  }

__global__ __launch_bounds__(256) void gemm_bf16_nt(
    const __hip_bfloat16* __restrict__ A, const __hip_bfloat16* __restrict__ B,
    const float* __restrict__ bias, float* __restrict__ C,
    int M, int N, int K) {
  GEMM_BODY(C[(size_t)row * N + col] = acc[i][j][r] + bs)
}

__global__ __launch_bounds__(256) void gemm_bf16_nt_bf16out(
    const __hip_bfloat16* __restrict__ A, const __hip_bfloat16* __restrict__ B,
    const float* __restrict__ bias, __hip_bfloat16* __restrict__ C,
    int M, int N, int K) {
  GEMM_BODY(C[(size_t)row * N + col] = __float2bfloat16(acc[i][j][r] + bs))
}

// ---------------------------------------------------------------------------
// MFMA sliding-window attention (unchanged from R3).
// ---------------------------------------------------------------------------
__global__ __launch_bounds__(256, 1) void attn_mfma(
    const __hip_bfloat16* __restrict__ qkv, __hip_bfloat16* __restrict__ attn) {
  __shared__ __attribute__((aligned(16))) __hip_bfloat16 QsA[64 * 32];
  __shared__ __attribute__((aligned(16))) __hip_bfloat16 QsB[64 * 32];
  __shared__ __attribute__((aligned(16))) __hip_bfloat16 KsA[320 * 32];
  __shared__ __attribute__((aligned(16))) __hip_bfloat16 KsB[320 * 32];
  __shared__ __attribute__((aligned(16))) __hip_bfloat16 Vt[64 * 328];
  __shared__ __attribute__((aligned(16))) __hip_bfloat16 Ps[4 * 16 * 328];

  const int tid  = threadIdx.x;
  const int lane = tid & 63;
  const int w    = tid >> 6;
  const int quad = lane >> 4;
  const int l16  = lane & 15;
  const int q0   = blockIdx.x * 64;
  const int h    = blockIdx.y;
  const int b    = blockIdx.z;
  const int kbase = q0 - WINW;

  {
    const int r_ = tid >> 2;
    const int c8 = (tid & 3) * 8;
    {
      const __hip_bfloat16* src = qkv + ((size_t)(b * SS + q0 + r_)) * (3 * DD) + h * DHH;
      load16_lds(src + c8,      &QsA[r_ * 32 + c8]);
      load16_lds(src + 32 + c8, &QsB[r_ * 32 + c8]);
    }
#pragma unroll
    for (int it = 0; it < 5; ++it) {
      const int r = it * 64 + r_;
      int key = kbase + r; key = key < 0 ? 0 : (key > SS - 1 ? SS - 1 : key);
      const __hip_bfloat16* src = qkv + ((size_t)(b * SS + key)) * (3 * DD) + DD + h * DHH;
      load16_lds(src + c8,      &KsA[r * 32 + c8]);
      load16_lds(src + 32 + c8, &KsB[r * 32 + c8]);
    }
    const int k4 = (tid >> 3) * 4;
    const int d8 = (tid & 7) * 8;
#pragma unroll
    for (int it = 0; it < 3; ++it) {
      const int rr = it * 128 + k4;
      if (rr < 320) {
        short8 v[4];
#pragma unroll
        for (int u = 0; u < 4; ++u) {
          int key = kbase + rr + u; key = key < 0 ? 0 : (key > SS - 1 ? SS - 1 : key);
          v[u] = *(const short8*)(qkv + ((size_t)(b * SS + key)) * (3 * DD) + 2 * DD + h * DHH + d8);
        }
#pragma unroll
        for (int j = 0; j < 8; ++j) {
          short4v pk; pk[0] = v[0][j]; pk[1] = v[1][j]; pk[2] = v[2][j]; pk[3] = v[3][j];
          *(short4v*)&Vt[(d8 + j) * 328 + rr] = pk;
        }
      }
    }
  }
  __syncthreads();

  const short8 qf0 = *(const short8*)&QsA[(w * 16 + l16) * 32 + quad * 8];
  const short8 qf1 = *(const short8*)&QsB[(w * 16 + l16) * 32 + quad * 8];

  floatx4 sc[20];
#pragma unroll
  for (int kt = 0; kt < 20; ++kt) {
    const short8 bk0 = *(const short8*)&KsA[(kt * 16 + l16) * 32 + quad * 8];
    const short8 bk1 = *(const short8*)&KsB[(kt * 16 + l16) * 32 + quad * 8];
    floatx4 a = {};
    a = __builtin_amdgcn_mfma_f32_16x16x32_bf16(qf0, bk0, a, 0, 0, 0);
    a = __builtin_amdgcn_mfma_f32_16x16x32_bf16(qf1, bk1, a, 0, 0, 0);
    sc[kt] = a;
  }

  float mx[4] = {-1e30f, -1e30f, -1e30f, -1e30f};
#pragma unroll
  for (int kt = 0; kt < 20; ++kt) {
    const int key = kbase + kt * 16 + l16;
#pragma unroll
    for (int r = 0; r < 4; ++r) {
      const int qq = q0 + w * 16 + quad * 4 + r;
      const int dqk = qq - key;
      const bool ok = (key >= 0) & (key < SS) & (dqk <= WINW) & (dqk >= -WINW);
      const float s = ok ? sc[kt][r] * 0.125f : -1e30f;
      sc[kt][r] = s;
      mx[r] = fmaxf(mx[r], s);
    }
  }
#pragma unroll
  for (int off = 1; off < 16; off <<= 1)
#pragma unroll
    for (int r = 0; r < 4; ++r) mx[r] = fmaxf(mx[r], __shfl_xor(mx[r], off, 64));

  float sum[4] = {0.f, 0.f, 0.f, 0.f};
  __hip_bfloat16* Pw = &Ps[w * 16 * 328];
#pragma unroll
  for (int kt = 0; kt < 20; ++kt) {
#pragma unroll
    for (int r = 0; r < 4; ++r) {
      const float p = __expf(sc[kt][r] - mx[r]);
      sum[r] += p;
      Pw[(quad * 4 + r) * 328 + kt * 16 + l16] = __float2bfloat16(p);
    }
  }
#pragma unroll
  for (int off = 1; off < 16; off <<= 1)
#pragma unroll
    for (int r = 0; r < 4; ++r) sum[r] += __shfl_xor(sum[r], off, 64);

  floatx4 ob[4] = {};
#pragma unroll
  for (int kt = 0; kt < 10; ++kt) {
    const short8 pf = *(const short8*)&Pw[l16 * 328 + kt * 32 + quad * 8];
#pragma unroll
    for (int t = 0; t < 4; ++t) {
      const short8 vf = *(const short8*)&Vt[(t * 16 + l16) * 328 + kt * 32 + quad * 8];
      ob[t] = __builtin_amdgcn_mfma_f32_16x16x32_bf16(pf, vf, ob[t], 0, 0, 0);
    }
  }

  float inv[4];
#pragma unroll
  for (int r = 0; r < 4; ++r) inv[r] = 1.f / sum[r];
  const int qq0 = q0 + w * 16 + quad * 4;
#pragma unroll
  for (int t = 0; t < 4; ++t)
#pragma unroll
    for (int r = 0; r < 4; ++r)
      attn[((size_t)(b * SS + qq0 + r)) * DD + h * DHH + t * 16 + l16] =
          __float2bfloat16(ob[t][r] * inv[r]);
}

// ---------------------------------------------------------------------------
// out = LayerNorm(a + b) * g + beta, row length D=1024, one block per row.
// ---------------------------------------------------------------------------
__global__ __launch_bounds__(256) void add_ln(
    const float* __restrict__ a, const float* __restrict__ b,
    const float* __restrict__ g, const float* __restrict__ be,
    float* __restrict__ out) {
  const int row = blockIdx.x;
  const int tid = threadIdx.x;
  const int lane = tid & 63;
  const int wave = tid >> 6;

  const float4 av = *(const float4*)(a + (size_t)row * DD + tid * 4);
  const float4 bv = *(const float4*)(b + (size_t)row * DD + tid * 4);
  float v[4] = {av.x + bv.x, av.y + bv.y, av.z + bv.z, av.w + bv.w};

  float s = v[0] + v[1] + v[2] + v[3];
  float s2 = v[0] * v[0] + v[1] * v[1] + v[2] * v[2] + v[3] * v[3];
#pragma unroll
  for (int off = 32; off; off >>= 1) {
    s += __shfl_xor(s, off, 64);
    s2 += __shfl_xor(s2, off, 64);
  }
  __shared__ float red[8];
  if (lane == 0) { red[wave] = s; red[4 + wave] = s2; }
  __syncthreads();
  s = red[0] + red[1] + red[2] + red[3];
  s2 = red[4] + red[5] + red[6] + red[7];

  const float mu = s * (1.f / DD);
  const float var = s2 * (1.f / DD) - mu * mu;
  const float r = rsqrtf(var + 1e-5f);

  const float4 gv = *(const float4*)(g + tid * 4);
  const float4 bev = *(const float4*)(be + tid * 4);
  float4 o;
  o.x = (v[0] - mu) * r * gv.x + bev.x;
  o.y = (v[1] - mu) * r * gv.y + bev.y;
  o.z = (v[2] - mu) * r * gv.z + bev.z;
  o.w = (v[3] - mu) * r * gv.w + bev.w;
  *(float4*)(out + (size_t)row * DD + tid * 4) = o;
}

// ---------------------------------------------------------------------------
// Spectral filter on transposed data, two real columns packed as one complex
// FFT. xT layout [B][D][S] (fp32), in-place. wrT/wiT are [D][1025].
// LDS is padded a -> a + (a>>5) to kill bank conflicts (bit-reversed filter
// indices and small-stage butterflies otherwise all land on bank 0).
// Twiddles via __sincosf on the fly (VALU has headroom; tables caused the
// bank-0 storm). 1/S scale folded into the filter coefficients.
// ---------------------------------------------------------------------------
#define PADI(a) ((a) + ((a) >> 5))

__global__ __launch_bounds__(256) void spec_fft_pair(
    float* __restrict__ xT, const float* __restrict__ wrT,
    const float* __restrict__ wiT) {
  __shared__ float re[SS + SS / 32], im[SS + SS / 32];
  const int tid = threadIdx.x;
  const int d0 = blockIdx.x * 2, d1 = d0 + 1;
  const int b = blockIdx.y;
  float* col0 = xT + ((size_t)b * DD + d0) * SS;
  float* col1 = xT + ((size_t)b * DD + d1) * SS;

  for (int s4 = tid * 4; s4 < SS; s4 += 1024) {
    const float4 a = *(const float4*)(col0 + s4);
    const float4 c = *(const float4*)(col1 + s4);
    const int p = PADI(s4);            // groups of 4 never straddle a pad
    re[p] = a.x; re[p + 1] = a.y; re[p + 2] = a.z; re[p + 3] = a.w;
    im[p] = c.x; im[p + 1] = c.y; im[p + 2] = c.z; im[p + 3] = c.w;
  }

  // forward DIF (natural in -> bit-reversed out)
  for (int stage = 11; stage >= 1; --stage) {
    __syncthreads();
    const int half = 1 << (stage - 1);
    const float ang0 = -6.283185307179586f / (float)(1 << stage);
#pragma unroll 4
    for (int t = tid; t < SS / 2; t += 256) {
      const int gI = t >> (stage - 1);
      const int p = t & (half - 1);
      const int i = (gI << stage) + p;
      const int j = i + half;
      float sn, cs;
      __sincosf(ang0 * (float)p, &sn, &cs);
      const int ii = PADI(i), jj = PADI(j);
      const float ar = re[ii], ai = im[ii], br = re[jj], bi = im[jj];
      re[ii] = ar + br; im[ii] = ai + bi;
      const float dr = ar - br, di = ai - bi;
      re[jj] = dr * cs - di * sn;
      im[jj] = dr * sn + di * cs;
    }
  }
  __syncthreads();

  // packed Hermitian filter: Z = Z0 + i*Z1; Y0=Z0*W0*sc, Y1=Z1*W1*sc.
  const float* w0r = wrT + (size_t)d0 * 1025;
  const float* w0i = wiT + (size_t)d0 * 1025;
  const float* w1r = wrT + (size_t)d1 * 1025;
  const float* w1i = wiT + (size_t)d1 * 1025;
  const float sc = 1.0f / (float)SS;
  for (int k = tid; k < 1024; k += 256) {
    if (k == 0) {
      re[0] *= w0r[0] * sc;            // DC (bitrev pos 0), forced real
      im[0] *= w1r[0] * sc;
      re[1] *= w0r[1024] * sc;         // Nyquist (bitrev pos 1), forced real
      im[1] *= w1r[1024] * sc;
    } else {
      const int p1 = PADI(__brev((unsigned)k) >> 21);
      const int p2 = PADI(__brev((unsigned)(SS - k)) >> 21);
      const float ra = re[p1], ia = im[p1];
      const float rb = re[p2], ib = im[p2];
      const float z0r = 0.5f * (ra + rb), z0i = 0.5f * (ia - ib);
      const float z1r = 0.5f * (ia + ib), z1i = -0.5f * (ra - rb);
      const float a0 = w0r[k] * sc, b0 = w0i[k] * sc;
      const float a1 = w1r[k] * sc, b1 = w1i[k] * sc;
      const float y0r = z0r * a0 - z0i * b0, y0i = z0r * b0 + z0i * a0;
      const float y1r = z1r * a1 - z1i * b1, y1i = z1r * b1 + z1i * a1;
      re[p1] = y0r - y1i; im[p1] = y0i + y1r;
      re[p2] = y0r + y1i; im[p2] = y1r - y0i;
    }
  }

  // inverse DIT (bit-reversed in -> natural out, conjugate twiddles)
  for (int stage = 1; stage <= 11; ++stage) {
    __syncthreads();
    const int half = 1 << (stage - 1);
    const float ang0 = 6.283185307179586f / (float)(1 << stage);
#pragma unroll 4
    for (int t = tid; t < SS / 2; t += 256) {
      const int gI = t >> (stage - 1);
      const int p = t & (half - 1);
      const int i = (gI << stage) + p;
      const int j = i + half;
      float sn, cs;
      __sincosf(ang0 * (float)p, &sn, &cs);
      const int ii = PADI(i), jj = PADI(j);
      const float br = re[jj], bi = im[jj];
      const float tr = br * cs - bi * sn;
      const float ti = br * sn + bi * cs;
      const float ar = re[ii], ai = im[ii];
      re[ii] = ar + tr; im[ii] = ai + ti;
      re[jj] = ar - tr; im[jj] = ai - ti;
    }
  }
  __syncthreads();

  for (int s4 = tid * 4; s4 < SS; s4 += 1024) {
    const int p = PADI(s4);
    float4 a, c;
    a.x = re[p]; a.y = re[p + 1]; a.z = re[p + 2]; a.w = re[p + 3];
    c.x = im[p]; c.y = im[p + 1]; c.z = im[p + 2]; c.w = im[p + 3];
    *(float4*)(col0 + s4) = a;
    *(float4*)(col1 + s4) = c;
  }
}

// ---------------------------------------------------------------------------
extern "C" void kernel_launch(void* const* d_in, const int* in_sizes, int n_in,
                              void* d_out, int out_size, void* d_ws, size_t ws_size,
                              hipStream_t stream) {
  const float* x     = (const float*)d_in[0];
  const float* in_w  = (const float*)d_in[1];
  const float* in_b  = (const float*)d_in[2];
  const float* out_w = (const float*)d_in[3];
  const float* out_b = (const float*)d_in[4];
  const float* ln1_g = (const float*)d_in[5];
  const float* ln1_b = (const float*)d_in[6];
  const float* wr    = (const float*)d_in[7];
  const float* wi    = (const float*)d_in[8];
  const float* ln2_g = (const float*)d_in[9];
  const float* ln2_b = (const float*)d_in[10];
  float* out = (float*)d_out;

  char* ws = (char*)d_ws;
  // Workspace phases (<= 64 MB):
  //  [0,24)   qkv_bf16          -> dead after attn  -> x_attn fp32 [0,16)
  //  [24,32)  attn_bf16         -> dead after GEMM2 -> x_wave fp32 [16,32)
  //  [32,40)  x_bf16, [40,46) in_w bf16, [46,48) out_w bf16
  //           -> all dead after GEMM2 -> xT fp32 [32,48) (FFT in place)
  //  [48,64)  attn_out fp32     -> dead after LN1   -> wrT/wiT [48,56.4)
  __hip_bfloat16* qkv_bf   = (__hip_bfloat16*)(ws);
  __hip_bfloat16* attn_bf  = (__hip_bfloat16*)(ws + 25165824);
  __hip_bfloat16* x_bf     = (__hip_bfloat16*)(ws + 33554432);
  __hip_bfloat16* w_in_bf  = (__hip_bfloat16*)(ws + 41943040);
  __hip_bfloat16* w_out_bf = (__hip_bfloat16*)(ws + 48234496);
  float* attn_out = (float*)(ws + 50331648);
  float* x_attn   = (float*)(ws);
  float* x_wave   = (float*)(ws + 16777216);
  float* xT       = (float*)(ws + 33554432);
  float* wrT      = (float*)(ws + 50331648);
  float* wiT      = (float*)(ws + 54530048);

  // 0. casts to bf16
  cast_f32_bf16<<<4194304 / 1024, 256, 0, stream>>>(x, x_bf, 4194304);
  cast_f32_bf16<<<3145728 / 1024, 256, 0, stream>>>(in_w, w_in_bf, 3145728);
  cast_f32_bf16<<<1048576 / 1024, 256, 0, stream>>>(out_w, w_out_bf, 1048576);

  // 1. qkv = x @ in_w^T + in_b   -> bf16 [4096, 3072]
  gemm_bf16_nt_bf16out<<<dim3(3072 / 128, MROWS / 128), 256, 0, stream>>>(
      x_bf, w_in_bf, in_b, qkv_bf, MROWS, 3 * DD, DD);

  // 2. MFMA sliding-window attention -> bf16 [4096, 1024]
  attn_mfma<<<dim3(SS / 64, HH, BB), 256, 0, stream>>>(qkv_bf, attn_bf);

  // 3. attn_out = attn @ out_w^T + out_b   (fp32)
  gemm_bf16_nt<<<dim3(DD / 128, MROWS / 128), 256, 0, stream>>>(
      attn_bf, w_out_bf, out_b, attn_out, MROWS, DD, DD);

  // 4. x_attn = LN1(x + attn_out)
  add_ln<<<MROWS, 256, 0, stream>>>(x, attn_out, ln1_g, ln1_b, x_attn);

  // 5a. transposes: x [S][D] -> xT [D][S] per batch; wr/wi [1025][D] -> [D][1025]
  transpose_f32<<<dim3(16, 32, 2), 256, 0, stream>>>(x, xT, SS, DD);
  transpose_f32<<<dim3(16, 17, 1), 256, 0, stream>>>(wr, wrT, 1025, DD);
  transpose_f32<<<dim3(16, 17, 1), 256, 0, stream>>>(wi, wiT, 1025, DD);

  // 5b. packed-pair FFT filter, in place on xT
  spec_fft_pair<<<dim3(DD / 2, BB), 256, 0, stream>>>(xT, wrT, wiT);

  // 5c. transpose back: xT [D][S] -> x_wave [S][D]
  transpose_f32<<<dim3(32, 16, 2), 256, 0, stream>>>(xT, x_wave, DD, SS);

  // 6. out = LN2(x_attn + x_wave)
  add_ln<<<MROWS, 256, 0, stream>>>(x_attn, x_wave, ln2_g, ln2_b, out);
}

// Round 6
// 257.730 us; speedup vs baseline: 6.0876x; 1.0870x over previous
//
#include <hip/hip_runtime.h>
#include <hip/hip_bf16.h>
#include <math.h>

// Problem constants (B,S,D,H,WIN) = (2,2048,1024,16,128), DH=64
#define BB    2
#define SS    2048
#define DD    1024
#define HH    16
#define DHH   64
#define WINW  128
#define MROWS (BB * SS)          // 4096

typedef __attribute__((ext_vector_type(8))) short short8;
typedef __attribute__((ext_vector_type(4))) short short4v;
typedef __attribute__((ext_vector_type(4))) float floatx4;

// ---------------------------------------------------------------------------
// Fused: x [B][S][D] fp32 -> xT [B][D][S] fp32  AND  x_bf row-major bf16.
// ---------------------------------------------------------------------------
__global__ __launch_bounds__(256) void transpose_x_cast(
    const float* __restrict__ src, float* __restrict__ dstT,
    __hip_bfloat16* __restrict__ dst_bf) {
  __shared__ float tile[64][65];
  const size_t base = (size_t)blockIdx.z * SS * DD;
  const int c0 = blockIdx.x * 64;   // D
  const int r0 = blockIdx.y * 64;   // S
  const int tx = threadIdx.x & 63;
  const int ty = threadIdx.x >> 6;
#pragma unroll
  for (int i = 0; i < 16; ++i) {
    const int r = ty * 16 + i;
    const float v = src[base + (size_t)(r0 + r) * DD + c0 + tx];
    tile[r][tx] = v;
    dst_bf[base + (size_t)(r0 + r) * DD + c0 + tx] = __float2bfloat16(v);
  }
  __syncthreads();
#pragma unroll
  for (int i = 0; i < 16; ++i) {
    const int c = ty * 16 + i;
    dstT[base + (size_t)(c0 + c) * SS + r0 + tx] = tile[tx][c];
  }
}

// ---------------------------------------------------------------------------
// Both weight casts in one launch. w_in: 3*D*D elems, then w_out: D*D.
// ---------------------------------------------------------------------------
__global__ __launch_bounds__(256) void cast_w(
    const float* __restrict__ w_in, const float* __restrict__ w_out,
    __hip_bfloat16* __restrict__ o_in, __hip_bfloat16* __restrict__ o_out) {
  const int i = (blockIdx.x * 256 + threadIdx.x) * 4;
  const float* src; __hip_bfloat16* dst; int j;
  if (i < 3 * DD * DD) { src = w_in; dst = o_in; j = i; }
  else { src = w_out; dst = o_out; j = i - 3 * DD * DD; }
  const float4 v = *(const float4*)(src + j);
  dst[j + 0] = __float2bfloat16(v.x);
  dst[j + 1] = __float2bfloat16(v.y);
  dst[j + 2] = __float2bfloat16(v.z);
  dst[j + 3] = __float2bfloat16(v.w);
}

// ---------------------------------------------------------------------------
// wr and wi transposes in one launch (z selects). [1025][1024] -> [1024][1025]
// ---------------------------------------------------------------------------
__global__ __launch_bounds__(256) void transpose_wrwi(
    const float* __restrict__ wr, const float* __restrict__ wi,
    float* __restrict__ wrT, float* __restrict__ wiT) {
  __shared__ float tile[64][65];
  const float* src = blockIdx.z ? wi : wr;
  float* dst = blockIdx.z ? wiT : wrT;
  const int R = 1025, C = DD;
  const int c0 = blockIdx.x * 64;
  const int r0 = blockIdx.y * 64;
  const int tx = threadIdx.x & 63;
  const int ty = threadIdx.x >> 6;
#pragma unroll
  for (int i = 0; i < 16; ++i) {
    const int r = ty * 16 + i;
    if (r0 + r < R) tile[r][tx] = src[(size_t)(r0 + r) * C + c0 + tx];
  }
  __syncthreads();
#pragma unroll
  for (int i = 0; i < 16; ++i) {
    const int c = ty * 16 + i;
    if (r0 + tx < R) dst[(size_t)(c0 + c) * R + r0 + tx] = tile[tx][c];
  }
}

// ---------------------------------------------------------------------------
// fp32 transpose: src[R][C] -> dst[C][R], 64x64 tiles, batch via blockIdx.z.
// ---------------------------------------------------------------------------
__global__ __launch_bounds__(256) void transpose_f32(
    const float* __restrict__ src, float* __restrict__ dst, int R, int C) {
  __shared__ float tile[64][65];
  const size_t base = (size_t)blockIdx.z * R * C;
  const int c0 = blockIdx.x * 64;
  const int r0 = blockIdx.y * 64;
  const int tx = threadIdx.x & 63;
  const int ty = threadIdx.x >> 6;
#pragma unroll
  for (int i = 0; i < 16; ++i) {
    const int r = ty * 16 + i;
    tile[r][tx] = src[base + (size_t)(r0 + r) * C + c0 + tx];
  }
  __syncthreads();
#pragma unroll
  for (int i = 0; i < 16; ++i) {
    const int c = ty * 16 + i;
    dst[base + (size_t)(c0 + c) * R + r0 + tx] = tile[tx][c];
  }
}

// ---------------------------------------------------------------------------
__device__ inline void load16_lds(const __hip_bfloat16* g, __hip_bfloat16* l) {
  __builtin_amdgcn_global_load_lds(
      (const __attribute__((address_space(1))) uint32_t*)g,
      (__attribute__((address_space(3))) uint32_t*)l, 16, 0, 0);
}

// ---------------------------------------------------------------------------
// bf16 MFMA GEMM (NT): C[M,N] = A[M,K] * B[N,K]^T + bias[N]
// 128x128 tile, BK=32, 256 threads (4 waves 2x2), mfma_f32_16x16x32_bf16.
// XCD-aware swizzle: each XCD gets a contiguous column-panel (row-fast) so
// its private L2 holds the B panel; A re-reads hit shared L3.
// Requires gridDim.y == 32 and gridDim.x*gridDim.y % 8 == 0.
// ---------------------------------------------------------------------------
#define GEMM_BODY(STORE)                                                       \
  __shared__ __attribute__((aligned(16))) __hip_bfloat16 As[128 * 32];         \
  __shared__ __attribute__((aligned(16))) __hip_bfloat16 Bs[128 * 32];         \
  const int tid  = threadIdx.x;                                                \
  const int lane = tid & 63;                                                   \
  const int wave = tid >> 6;                                                   \
  const int wrow = (wave >> 1) * 64;                                           \
  const int wcol = (wave & 1) * 64;                                            \
  int id_ = blockIdx.y * gridDim.x + blockIdx.x;                               \
  const int per_ = (gridDim.x * gridDim.y) >> 3;                               \
  id_ = (id_ & 7) * per_ + (id_ >> 3);                                         \
  const int row0 = (id_ & 31) * 128;                                           \
  const int col0 = (id_ >> 5) * 128;                                           \
  const int srow = tid >> 2;                                                   \
  const int skk  = (tid & 3) * 8;                                              \
  const int quad = lane >> 4;                                                  \
  const int l16  = lane & 15;                                                  \
  floatx4 acc[4][4] = {};                                                      \
  for (int k0 = 0; k0 < K; k0 += 32) {                                         \
    __syncthreads();                                                           \
    load16_lds(A + (size_t)(row0 + srow) * K + k0 + skk,      &As[tid * 8]);   \
    load16_lds(A + (size_t)(row0 + 64 + srow) * K + k0 + skk, &As[2048 + tid * 8]); \
    load16_lds(B + (size_t)(col0 + srow) * K + k0 + skk,      &Bs[tid * 8]);   \
    load16_lds(B + (size_t)(col0 + 64 + srow) * K + k0 + skk, &Bs[2048 + tid * 8]); \
    __syncthreads();                                                           \
    short8 af[4], bf[4];                                                       \
    _Pragma("unroll")                                                          \
    for (int i = 0; i < 4; ++i)                                                \
      af[i] = *(const short8*)&As[(wrow + i * 16 + l16) * 32 + quad * 8];      \
    _Pragma("unroll")                                                          \
    for (int j = 0; j < 4; ++j)                                                \
      bf[j] = *(const short8*)&Bs[(wcol + j * 16 + l16) * 32 + quad * 8];      \
    _Pragma("unroll")                                                          \
    for (int i = 0; i < 4; ++i)                                                \
      _Pragma("unroll")                                                        \
      for (int j = 0; j < 4; ++j)                                              \
        acc[i][j] = __builtin_amdgcn_mfma_f32_16x16x32_bf16(af[i], bf[j], acc[i][j], 0, 0, 0); \
  }                                                                            \
  _Pragma("unroll")                                                            \
  for (int i = 0; i < 4; ++i) {                                                \
    _Pragma("unroll")                                                          \
    for (int j = 0; j < 4; ++j) {                                              \
      const int col = col0 + wcol + j * 16 + l16;                              \
      const float bs = bias[col];                                              \
      _Pragma("unroll")                                                        \
      for (int r = 0; r < 4; ++r) {                                            \
        const int row = row0 + wrow + i * 16 + quad * 4 + r;                   \
        STORE;                                                                 \
      }                                                                        \
    }                                                                          \
  }

__global__ __launch_bounds__(256) void gemm_bf16_nt(
    const __hip_bfloat16* __restrict__ A, const __hip_bfloat16* __restrict__ B,
    const float* __restrict__ bias, float* __restrict__ C,
    int M, int N, int K) {
  GEMM_BODY(C[(size_t)row * N + col] = acc[i][j][r] + bs)
}

__global__ __launch_bounds__(256) void gemm_bf16_nt_bf16out(
    const __hip_bfloat16* __restrict__ A, const __hip_bfloat16* __restrict__ B,
    const float* __restrict__ bias, __hip_bfloat16* __restrict__ C,
    int M, int N, int K) {
  GEMM_BODY(C[(size_t)row * N + col] = __float2bfloat16(acc[i][j][r] + bs))
}

// ---------------------------------------------------------------------------
// Flash-style MFMA sliding-window attention, 2 key-chunks of 160, online
// softmax. Block = (b,h) x 64 queries (4 waves x 16). LDS 70 KB -> 2 blk/CU.
// ---------------------------------------------------------------------------
__global__ __launch_bounds__(256, 2) void attn_mfma(
    const __hip_bfloat16* __restrict__ qkv, __hip_bfloat16* __restrict__ attn) {
  __shared__ __attribute__((aligned(16))) __hip_bfloat16 QsA[64 * 32];
  __shared__ __attribute__((aligned(16))) __hip_bfloat16 QsB[64 * 32];
  __shared__ __attribute__((aligned(16))) __hip_bfloat16 KsA[160 * 32];
  __shared__ __attribute__((aligned(16))) __hip_bfloat16 KsB[160 * 32];
  __shared__ __attribute__((aligned(16))) __hip_bfloat16 Vt[64 * 168];
  __shared__ __attribute__((aligned(16))) __hip_bfloat16 Ps[64 * 168];

  const int tid  = threadIdx.x;
  const int lane = tid & 63;
  const int w    = tid >> 6;
  const int quad = lane >> 4;
  const int l16  = lane & 15;
  const int q0   = blockIdx.x * 64;
  const int h    = blockIdx.y;
  const int b    = blockIdx.z;
  const int kbase = q0 - WINW;

  const int r_ = tid >> 2;            // 0..63
  const int c8 = (tid & 3) * 8;       // 0,8,16,24

  // Q staging (once)
  {
    const __hip_bfloat16* src = qkv + ((size_t)(b * SS + q0 + r_)) * (3 * DD) + h * DHH;
    load16_lds(src + c8,      &QsA[r_ * 32 + c8]);
    load16_lds(src + 32 + c8, &QsB[r_ * 32 + c8]);
  }

  short8 qf0, qf1;
  float m_run[4] = {-1e30f, -1e30f, -1e30f, -1e30f};
  float l_run[4] = {0.f, 0.f, 0.f, 0.f};
  floatx4 ob[4] = {};

  for (int c = 0; c < 2; ++c) {
    const int ck0 = kbase + c * 160;
    __syncthreads();   // prev-chunk LDS reads complete before restaging
    // K staging: chunk rows 0..159 (wave-uniform guards)
#pragma unroll
    for (int it = 0; it < 3; ++it) {
      const int r = it * 64 + r_;
      if (r < 160) {
        int key = ck0 + r; key = key < 0 ? 0 : (key > SS - 1 ? SS - 1 : key);
        const __hip_bfloat16* src = qkv + ((size_t)(b * SS + key)) * (3 * DD) + DD + h * DHH;
        load16_lds(src + c8,      &KsA[r * 32 + c8]);
        load16_lds(src + 32 + c8, &KsB[r * 32 + c8]);
      }
    }
    // V staging transposed [dh][key]
    {
      const int k4 = (tid >> 3) * 4;
      const int d8 = (tid & 7) * 8;
#pragma unroll
      for (int it = 0; it < 2; ++it) {
        const int rr = it * 128 + k4;
        if (rr < 160) {
          short8 v[4];
#pragma unroll
          for (int u = 0; u < 4; ++u) {
            int key = ck0 + rr + u; key = key < 0 ? 0 : (key > SS - 1 ? SS - 1 : key);
            v[u] = *(const short8*)(qkv + ((size_t)(b * SS + key)) * (3 * DD) + 2 * DD + h * DHH + d8);
          }
#pragma unroll
          for (int j = 0; j < 8; ++j) {
            short4v pk; pk[0] = v[0][j]; pk[1] = v[1][j]; pk[2] = v[2][j]; pk[3] = v[3][j];
            *(short4v*)&Vt[(d8 + j) * 168 + rr] = pk;
          }
        }
      }
    }
    __syncthreads();

    if (c == 0) {
      qf0 = *(const short8*)&QsA[(w * 16 + l16) * 32 + quad * 8];
      qf1 = *(const short8*)&QsB[(w * 16 + l16) * 32 + quad * 8];
    }

    // QK^T: 10 key-tiles of 16
    floatx4 sc[10];
#pragma unroll
    for (int kt = 0; kt < 10; ++kt) {
      const short8 bk0 = *(const short8*)&KsA[(kt * 16 + l16) * 32 + quad * 8];
      const short8 bk1 = *(const short8*)&KsB[(kt * 16 + l16) * 32 + quad * 8];
      floatx4 a = {};
      a = __builtin_amdgcn_mfma_f32_16x16x32_bf16(qf0, bk0, a, 0, 0, 0);
      a = __builtin_amdgcn_mfma_f32_16x16x32_bf16(qf1, bk1, a, 0, 0, 0);
      sc[kt] = a;
    }

    // masked chunk max (C-layout: col=l16 -> key, row=quad*4+r -> query)
    float cm[4] = {-1e30f, -1e30f, -1e30f, -1e30f};
#pragma unroll
    for (int kt = 0; kt < 10; ++kt) {
      const int key = ck0 + kt * 16 + l16;
#pragma unroll
      for (int r = 0; r < 4; ++r) {
        const int qq = q0 + w * 16 + quad * 4 + r;
        const int dqk = qq - key;
        const bool ok = (key >= 0) & (key < SS) & (dqk <= WINW) & (dqk >= -WINW);
        const float s = ok ? sc[kt][r] * 0.125f : -1e30f;
        sc[kt][r] = s;
        cm[r] = fmaxf(cm[r], s);
      }
    }
#pragma unroll
    for (int off = 1; off < 16; off <<= 1)
#pragma unroll
      for (int r = 0; r < 4; ++r) cm[r] = fmaxf(cm[r], __shfl_xor(cm[r], off, 64));

    float alpha[4], csum[4] = {0.f, 0.f, 0.f, 0.f};
#pragma unroll
    for (int r = 0; r < 4; ++r) {
      const float mn = fmaxf(m_run[r], cm[r]);
      alpha[r] = __expf(m_run[r] - mn);
      m_run[r] = mn;
    }

    __hip_bfloat16* Pw = &Ps[w * 16 * 168];
#pragma unroll
    for (int kt = 0; kt < 10; ++kt) {
#pragma unroll
      for (int r = 0; r < 4; ++r) {
        const float p = __expf(sc[kt][r] - m_run[r]);
        csum[r] += p;
        Pw[(quad * 4 + r) * 168 + kt * 16 + l16] = __float2bfloat16(p);
      }
    }
#pragma unroll
    for (int off = 1; off < 16; off <<= 1)
#pragma unroll
      for (int r = 0; r < 4; ++r) csum[r] += __shfl_xor(csum[r], off, 64);
#pragma unroll
    for (int r = 0; r < 4; ++r) l_run[r] = l_run[r] * alpha[r] + csum[r];
#pragma unroll
    for (int t = 0; t < 4; ++t)
#pragma unroll
      for (int r = 0; r < 4; ++r) ob[t][r] *= alpha[r];

    // PV: O[16q x 64dh] += P[16q x 160k] * Vt^T (same-wave P roundtrip)
#pragma unroll
    for (int kt = 0; kt < 5; ++kt) {
      const short8 pf = *(const short8*)&Pw[l16 * 168 + kt * 32 + quad * 8];
#pragma unroll
      for (int t = 0; t < 4; ++t) {
        const short8 vf = *(const short8*)&Vt[(t * 16 + l16) * 168 + kt * 32 + quad * 8];
        ob[t] = __builtin_amdgcn_mfma_f32_16x16x32_bf16(pf, vf, ob[t], 0, 0, 0);
      }
    }
  }

  float inv[4];
#pragma unroll
  for (int r = 0; r < 4; ++r) inv[r] = 1.f / l_run[r];
  const int qq0 = q0 + w * 16 + quad * 4;
#pragma unroll
  for (int t = 0; t < 4; ++t)
#pragma unroll
    for (int r = 0; r < 4; ++r)
      attn[((size_t)(b * SS + qq0 + r)) * DD + h * DHH + t * 16 + l16] =
          __float2bfloat16(ob[t][r] * inv[r]);
}

// ---------------------------------------------------------------------------
// out = LayerNorm(a + b) * g + beta, row length D=1024, one block per row.
// ---------------------------------------------------------------------------
__global__ __launch_bounds__(256) void add_ln(
    const float* __restrict__ a, const float* __restrict__ b,
    const float* __restrict__ g, const float* __restrict__ be,
    float* __restrict__ out) {
  const int row = blockIdx.x;
  const int tid = threadIdx.x;
  const int lane = tid & 63;
  const int wave = tid >> 6;

  const float4 av = *(const float4*)(a + (size_t)row * DD + tid * 4);
  const float4 bv = *(const float4*)(b + (size_t)row * DD + tid * 4);
  float v[4] = {av.x + bv.x, av.y + bv.y, av.z + bv.z, av.w + bv.w};

  float s = v[0] + v[1] + v[2] + v[3];
  float s2 = v[0] * v[0] + v[1] * v[1] + v[2] * v[2] + v[3] * v[3];
#pragma unroll
  for (int off = 32; off; off >>= 1) {
    s += __shfl_xor(s, off, 64);
    s2 += __shfl_xor(s2, off, 64);
  }
  __shared__ float red[8];
  if (lane == 0) { red[wave] = s; red[4 + wave] = s2; }
  __syncthreads();
  s = red[0] + red[1] + red[2] + red[3];
  s2 = red[4] + red[5] + red[6] + red[7];

  const float mu = s * (1.f / DD);
  const float var = s2 * (1.f / DD) - mu * mu;
  const float r = rsqrtf(var + 1e-5f);

  const float4 gv = *(const float4*)(g + tid * 4);
  const float4 bev = *(const float4*)(be + tid * 4);
  float4 o;
  o.x = (v[0] - mu) * r * gv.x + bev.x;
  o.y = (v[1] - mu) * r * gv.y + bev.y;
  o.z = (v[2] - mu) * r * gv.z + bev.z;
  o.w = (v[3] - mu) * r * gv.w + bev.w;
  *(float4*)(out + (size_t)row * DD + tid * 4) = o;
}

// ---------------------------------------------------------------------------
// Spectral filter on transposed data, two real columns packed as one complex
// FFT. LDS padded a -> a + (a>>5); twiddles on the fly; scale folded in.
// ---------------------------------------------------------------------------
#define PADI(a) ((a) + ((a) >> 5))

__global__ __launch_bounds__(256) void spec_fft_pair(
    float* __restrict__ xT, const float* __restrict__ wrT,
    const float* __restrict__ wiT) {
  __shared__ float re[SS + SS / 32], im[SS + SS / 32];
  const int tid = threadIdx.x;
  const int d0 = blockIdx.x * 2, d1 = d0 + 1;
  const int b = blockIdx.y;
  float* col0 = xT + ((size_t)b * DD + d0) * SS;
  float* col1 = xT + ((size_t)b * DD + d1) * SS;

  for (int s4 = tid * 4; s4 < SS; s4 += 1024) {
    const float4 a = *(const float4*)(col0 + s4);
    const float4 c = *(const float4*)(col1 + s4);
    const int p = PADI(s4);
    re[p] = a.x; re[p + 1] = a.y; re[p + 2] = a.z; re[p + 3] = a.w;
    im[p] = c.x; im[p + 1] = c.y; im[p + 2] = c.z; im[p + 3] = c.w;
  }

  // forward DIF (natural -> bit-reversed)
  for (int stage = 11; stage >= 1; --stage) {
    __syncthreads();
    const int half = 1 << (stage - 1);
    const float ang0 = -6.283185307179586f / (float)(1 << stage);
#pragma unroll 4
    for (int t = tid; t < SS / 2; t += 256) {
      const int gI = t >> (stage - 1);
      const int p = t & (half - 1);
      const int i = (gI << stage) + p;
      const int j = i + half;
      float sn, cs;
      __sincosf(ang0 * (float)p, &sn, &cs);
      const int ii = PADI(i), jj = PADI(j);
      const float ar = re[ii], ai = im[ii], br = re[jj], bi = im[jj];
      re[ii] = ar + br; im[ii] = ai + bi;
      const float dr = ar - br, di = ai - bi;
      re[jj] = dr * cs - di * sn;
      im[jj] = dr * sn + di * cs;
    }
  }
  __syncthreads();

  // packed Hermitian filter
  const float* w0r = wrT + (size_t)d0 * 1025;
  const float* w0i = wiT + (size_t)d0 * 1025;
  const float* w1r = wrT + (size_t)d1 * 1025;
  const float* w1i = wiT + (size_t)d1 * 1025;
  const float sc = 1.0f / (float)SS;
  for (int k = tid; k < 1024; k += 256) {
    if (k == 0) {
      re[0] *= w0r[0] * sc;
      im[0] *= w1r[0] * sc;
      re[1] *= w0r[1024] * sc;
      im[1] *= w1r[1024] * sc;
    } else {
      const int p1 = PADI(__brev((unsigned)k) >> 21);
      const int p2 = PADI(__brev((unsigned)(SS - k)) >> 21);
      const float ra = re[p1], ia = im[p1];
      const float rb = re[p2], ib = im[p2];
      const float z0r = 0.5f * (ra + rb), z0i = 0.5f * (ia - ib);
      const float z1r = 0.5f * (ia + ib), z1i = -0.5f * (ra - rb);
      const float a0 = w0r[k] * sc, b0 = w0i[k] * sc;
      const float a1 = w1r[k] * sc, b1 = w1i[k] * sc;
      const float y0r = z0r * a0 - z0i * b0, y0i = z0r * b0 + z0i * a0;
      const float y1r = z1r * a1 - z1i * b1, y1i = z1r * b1 + z1i * a1;
      re[p1] = y0r - y1i; im[p1] = y0i + y1r;
      re[p2] = y0r + y1i; im[p2] = y1r - y0i;
    }
  }

  // inverse DIT (bit-reversed -> natural, conjugate twiddles)
  for (int stage = 1; stage <= 11; ++stage) {
    __syncthreads();
    const int half = 1 << (stage - 1);
    const float ang0 = 6.283185307179586f / (float)(1 << stage);
#pragma unroll 4
    for (int t = tid; t < SS / 2; t += 256) {
      const int gI = t >> (stage - 1);
      const int p = t & (half - 1);
      const int i = (gI << stage) + p;
      const int j = i + half;
      float sn, cs;
      __sincosf(ang0 * (float)p, &sn, &cs);
      const int ii = PADI(i), jj = PADI(j);
      const float br = re[jj], bi = im[jj];
      const float tr = br * cs - bi * sn;
      const float ti = br * sn + bi * cs;
      const float ar = re[ii], ai = im[ii];
      re[ii] = ar + tr; im[ii] = ai + ti;
      re[jj] = ar - tr; im[jj] = ai - ti;
    }
  }
  __syncthreads();

  for (int s4 = tid * 4; s4 < SS; s4 += 1024) {
    const int p = PADI(s4);
    float4 a, c;
    a.x = re[p]; a.y = re[p + 1]; a.z = re[p + 2]; a.w = re[p + 3];
    c.x = im[p]; c.y = im[p + 1]; c.z = im[p + 2]; c.w = im[p + 3];
    *(float4*)(col0 + s4) = a;
    *(float4*)(col1 + s4) = c;
  }
}

// ---------------------------------------------------------------------------
extern "C" void kernel_launch(void* const* d_in, const int* in_sizes, int n_in,
                              void* d_out, int out_size, void* d_ws, size_t ws_size,
                              hipStream_t stream) {
  const float* x     = (const float*)d_in[0];
  const float* in_w  = (const float*)d_in[1];
  const float* in_b  = (const float*)d_in[2];
  const float* out_w = (const float*)d_in[3];
  const float* out_b = (const float*)d_in[4];
  const float* ln1_g = (const float*)d_in[5];
  const float* ln1_b = (const float*)d_in[6];
  const float* wr    = (const float*)d_in[7];
  const float* wi    = (const float*)d_in[8];
  const float* ln2_g = (const float*)d_in[9];
  const float* ln2_b = (const float*)d_in[10];
  float* out = (float*)d_out;

  char* ws = (char*)d_ws;
  // Workspace (64 MB), phase-reused:
  //  [0,16)    xT fp32                  (steps 1..9)
  //  [16,24)   x_bf16 (dead after GEMM1), [24,30) w_in_bf (dead after GEMM1),
  //            [30,32) w_out_bf (dead after GEMM2) -> x_attn fp32 [16,32) (LN1)
  //  [32,56)   qkv_bf16 (dead after attn) -> attn_out fp32 [32,48) (GEMM2)
  //            -> wrT [32,36.2), wiT [36.2,40.4) (after LN1)
  //  [44,60)   x_wave fp32 (after spec_fft; wrT/wiT + attn_bf dead)
  //  [56,64)   attn_bf16 (dead after GEMM2)
  float* xT                = (float*)(ws);
  __hip_bfloat16* x_bf     = (__hip_bfloat16*)(ws + 16777216);
  __hip_bfloat16* w_in_bf  = (__hip_bfloat16*)(ws + 25165824);
  __hip_bfloat16* w_out_bf = (__hip_bfloat16*)(ws + 31457280);
  float* x_attn            = (float*)(ws + 16777216);
  __hip_bfloat16* qkv_bf   = (__hip_bfloat16*)(ws + 33554432);
  __hip_bfloat16* attn_bf  = (__hip_bfloat16*)(ws + 58720256);
  float* attn_out          = (float*)(ws + 33554432);
  float* wrT               = (float*)(ws + 33554432);
  float* wiT               = (float*)(ws + 37752832);
  float* x_wave            = (float*)(ws + 46137344);

  // 1. x -> xT (fp32 transposed) + x_bf (bf16 row-major), one read of x
  transpose_x_cast<<<dim3(16, 32, 2), 256, 0, stream>>>(x, xT, x_bf);

  // 2. weight casts (one launch)
  cast_w<<<4096, 256, 0, stream>>>(in_w, out_w, w_in_bf, w_out_bf);

  // 3. qkv = x @ in_w^T + in_b  -> bf16 [4096, 3072]
  gemm_bf16_nt_bf16out<<<dim3(3072 / 128, MROWS / 128), 256, 0, stream>>>(
      x_bf, w_in_bf, in_b, qkv_bf, MROWS, 3 * DD, DD);

  // 4. flash MFMA sliding-window attention -> bf16
  attn_mfma<<<dim3(SS / 64, HH, BB), 256, 0, stream>>>(qkv_bf, attn_bf);

  // 5. attn_out = attn @ out_w^T + out_b  (fp32)
  gemm_bf16_nt<<<dim3(DD / 128, MROWS / 128), 256, 0, stream>>>(
      attn_bf, w_out_bf, out_b, attn_out, MROWS, DD, DD);

  // 6. x_attn = LN1(x + attn_out)
  add_ln<<<MROWS, 256, 0, stream>>>(x, attn_out, ln1_g, ln1_b, x_attn);

  // 7. wr/wi -> wrT/wiT (one launch)
  transpose_wrwi<<<dim3(16, 17, 2), 256, 0, stream>>>(wr, wi, wrT, wiT);

  // 8. packed-pair FFT filter, in place on xT
  spec_fft_pair<<<dim3(DD / 2, BB), 256, 0, stream>>>(xT, wrT, wiT);

  // 9. xT -> x_wave [S][D]
  transpose_f32<<<dim3(32, 16, 2), 256, 0, stream>>>(xT, x_wave, DD, SS);

  // 10. out = LN2(x_attn + x_wave)
  add_ln<<<MROWS, 256, 0, stream>>>(x_attn, x_wave, ln2_g, ln2_b, out);
}

// Round 7
// 232.645 us; speedup vs baseline: 6.7440x; 1.1078x over previous
//
#include <hip/hip_runtime.h>
#include <hip/hip_bf16.h>
#include <math.h>

// Problem constants (B,S,D,H,WIN) = (2,2048,1024,16,128), DH=64
#define BB    2
#define SS    2048
#define DD    1024
#define HH    16
#define DHH   64
#define WINW  128
#define MROWS (BB * SS)          // 4096

typedef __attribute__((ext_vector_type(8))) short short8;
typedef __attribute__((ext_vector_type(4))) short short4v;
typedef __attribute__((ext_vector_type(4))) float floatx4;

__device__ __forceinline__ float bf2f(short s) {
  union { unsigned u; float f; } t;
  t.u = ((unsigned)(unsigned short)s) << 16;
  return t.f;
}

// ---------------------------------------------------------------------------
// Fused: x [B][S][D] fp32 -> xT [B][D][S] fp32  AND  x_bf row-major bf16.
// ---------------------------------------------------------------------------
__global__ __launch_bounds__(256) void transpose_x_cast(
    const float* __restrict__ src, float* __restrict__ dstT,
    __hip_bfloat16* __restrict__ dst_bf) {
  __shared__ float tile[64][65];
  const size_t base = (size_t)blockIdx.z * SS * DD;
  const int c0 = blockIdx.x * 64;   // D
  const int r0 = blockIdx.y * 64;   // S
  const int tx = threadIdx.x & 63;
  const int ty = threadIdx.x >> 6;
#pragma unroll
  for (int i = 0; i < 16; ++i) {
    const int r = ty * 16 + i;
    const float v = src[base + (size_t)(r0 + r) * DD + c0 + tx];
    tile[r][tx] = v;
    dst_bf[base + (size_t)(r0 + r) * DD + c0 + tx] = __float2bfloat16(v);
  }
  __syncthreads();
#pragma unroll
  for (int i = 0; i < 16; ++i) {
    const int c = ty * 16 + i;
    dstT[base + (size_t)(c0 + c) * SS + r0 + tx] = tile[tx][c];
  }
}

// ---------------------------------------------------------------------------
// Both weight casts in one launch. w_in: 3*D*D elems, then w_out: D*D.
// ---------------------------------------------------------------------------
__global__ __launch_bounds__(256) void cast_w(
    const float* __restrict__ w_in, const float* __restrict__ w_out,
    __hip_bfloat16* __restrict__ o_in, __hip_bfloat16* __restrict__ o_out) {
  const int i = (blockIdx.x * 256 + threadIdx.x) * 4;
  const float* src; __hip_bfloat16* dst; int j;
  if (i < 3 * DD * DD) { src = w_in; dst = o_in; j = i; }
  else { src = w_out; dst = o_out; j = i - 3 * DD * DD; }
  const float4 v = *(const float4*)(src + j);
  dst[j + 0] = __float2bfloat16(v.x);
  dst[j + 1] = __float2bfloat16(v.y);
  dst[j + 2] = __float2bfloat16(v.z);
  dst[j + 3] = __float2bfloat16(v.w);
}

// ---------------------------------------------------------------------------
// wr and wi transposes -> bf16, one launch (z selects). [1025][1024]->[1024][1025]
// ---------------------------------------------------------------------------
__global__ __launch_bounds__(256) void transpose_wrwi_bf(
    const float* __restrict__ wr, const float* __restrict__ wi,
    __hip_bfloat16* __restrict__ wrT, __hip_bfloat16* __restrict__ wiT) {
  __shared__ float tile[64][65];
  const float* src = blockIdx.z ? wi : wr;
  __hip_bfloat16* dst = blockIdx.z ? wiT : wrT;
  const int R = 1025, C = DD;
  const int c0 = blockIdx.x * 64;
  const int r0 = blockIdx.y * 64;
  const int tx = threadIdx.x & 63;
  const int ty = threadIdx.x >> 6;
#pragma unroll
  for (int i = 0; i < 16; ++i) {
    const int r = ty * 16 + i;
    if (r0 + r < R) tile[r][tx] = src[(size_t)(r0 + r) * C + c0 + tx];
  }
  __syncthreads();
#pragma unroll
  for (int i = 0; i < 16; ++i) {
    const int c = ty * 16 + i;
    if (r0 + tx < R) dst[(size_t)(c0 + c) * R + r0 + tx] = __float2bfloat16(tile[tx][c]);
  }
}

// ---------------------------------------------------------------------------
__device__ inline void load16_lds(const __hip_bfloat16* g, __hip_bfloat16* l) {
  __builtin_amdgcn_global_load_lds(
      (const __attribute__((address_space(1))) uint32_t*)g,
      (__attribute__((address_space(3))) uint32_t*)l, 16, 0, 0);
}

// ---------------------------------------------------------------------------
// bf16 MFMA GEMM tile body: C[128,128] tile at (row0,col0) of
// C[M,N] = A[M,K]*B[N,K]^T + bias.  256 threads, BK=32.
// ---------------------------------------------------------------------------
template <bool BF16OUT>
__device__ __forceinline__ void gemm_tile128(
    const __hip_bfloat16* __restrict__ A, const __hip_bfloat16* __restrict__ B,
    const float* __restrict__ bias, void* __restrict__ Cp,
    int N, int K, int row0, int col0,
    __hip_bfloat16* As, __hip_bfloat16* Bs) {
  const int tid  = threadIdx.x;
  const int lane = tid & 63;
  const int wave = tid >> 6;
  const int wrow = (wave >> 1) * 64;
  const int wcol = (wave & 1) * 64;
  const int srow = tid >> 2;
  const int skk  = (tid & 3) * 8;
  const int quad = lane >> 4;
  const int l16  = lane & 15;
  floatx4 acc[4][4] = {};
  for (int k0 = 0; k0 < K; k0 += 32) {
    __syncthreads();
    load16_lds(A + (size_t)(row0 + srow) * K + k0 + skk,      &As[tid * 8]);
    load16_lds(A + (size_t)(row0 + 64 + srow) * K + k0 + skk, &As[2048 + tid * 8]);
    load16_lds(B + (size_t)(col0 + srow) * K + k0 + skk,      &Bs[tid * 8]);
    load16_lds(B + (size_t)(col0 + 64 + srow) * K + k0 + skk, &Bs[2048 + tid * 8]);
    __syncthreads();
    short8 af[4], bf[4];
#pragma unroll
    for (int i = 0; i < 4; ++i)
      af[i] = *(const short8*)&As[(wrow + i * 16 + l16) * 32 + quad * 8];
#pragma unroll
    for (int j = 0; j < 4; ++j)
      bf[j] = *(const short8*)&Bs[(wcol + j * 16 + l16) * 32 + quad * 8];
#pragma unroll
    for (int i = 0; i < 4; ++i)
#pragma unroll
      for (int j = 0; j < 4; ++j)
        acc[i][j] = __builtin_amdgcn_mfma_f32_16x16x32_bf16(af[i], bf[j], acc[i][j], 0, 0, 0);
  }
#pragma unroll
  for (int i = 0; i < 4; ++i) {
#pragma unroll
    for (int j = 0; j < 4; ++j) {
      const int col = col0 + wcol + j * 16 + l16;
      const float bs = bias[col];
#pragma unroll
      for (int r = 0; r < 4; ++r) {
        const int row = row0 + wrow + i * 16 + quad * 4 + r;
        if (BF16OUT)
          ((__hip_bfloat16*)Cp)[(size_t)row * N + col] = __float2bfloat16(acc[i][j][r] + bs);
        else
          ((float*)Cp)[(size_t)row * N + col] = acc[i][j][r] + bs;
      }
    }
  }
}

// ---------------------------------------------------------------------------
// Spectral FFT body (one block = one d-pair of one batch). LDS padded
// a -> a+(a>>5); twiddles on the fly; 1/S scale folded into filter.
// sm must hold 2*2112 floats (16896 B).
// ---------------------------------------------------------------------------
#define PADI(a) ((a) + ((a) >> 5))

__device__ __forceinline__ void spec_body(
    int sid, float* __restrict__ xT,
    const __hip_bfloat16* __restrict__ wrT, const __hip_bfloat16* __restrict__ wiT,
    float* sm) {
  float* re = sm;
  float* im = sm + 2112;
  const int tid = threadIdx.x;
  const int dpair = sid & 511;
  const int b = sid >> 9;
  const int d0 = dpair * 2, d1 = d0 + 1;
  float* col0 = xT + ((size_t)b * DD + d0) * SS;
  float* col1 = xT + ((size_t)b * DD + d1) * SS;

  for (int s4 = tid * 4; s4 < SS; s4 += 1024) {
    const float4 a = *(const float4*)(col0 + s4);
    const float4 c = *(const float4*)(col1 + s4);
    const int p = PADI(s4);
    re[p] = a.x; re[p + 1] = a.y; re[p + 2] = a.z; re[p + 3] = a.w;
    im[p] = c.x; im[p + 1] = c.y; im[p + 2] = c.z; im[p + 3] = c.w;
  }

  // forward DIF (natural -> bit-reversed)
  for (int stage = 11; stage >= 1; --stage) {
    __syncthreads();
    const int half = 1 << (stage - 1);
    const float ang0 = -6.283185307179586f / (float)(1 << stage);
#pragma unroll 4
    for (int t = tid; t < SS / 2; t += 256) {
      const int gI = t >> (stage - 1);
      const int p = t & (half - 1);
      const int i = (gI << stage) + p;
      const int j = i + half;
      float sn, cs;
      __sincosf(ang0 * (float)p, &sn, &cs);
      const int ii = PADI(i), jj = PADI(j);
      const float ar = re[ii], ai = im[ii], br = re[jj], bi = im[jj];
      re[ii] = ar + br; im[ii] = ai + bi;
      const float dr = ar - br, di = ai - bi;
      re[jj] = dr * cs - di * sn;
      im[jj] = dr * sn + di * cs;
    }
  }
  __syncthreads();

  // packed Hermitian filter
  const __hip_bfloat16* w0r = wrT + (size_t)d0 * 1025;
  const __hip_bfloat16* w0i = wiT + (size_t)d0 * 1025;
  const __hip_bfloat16* w1r = wrT + (size_t)d1 * 1025;
  const __hip_bfloat16* w1i = wiT + (size_t)d1 * 1025;
  const float sc = 1.0f / (float)SS;
  for (int k = tid; k < 1024; k += 256) {
    if (k == 0) {
      re[0] *= __bfloat162float(w0r[0]) * sc;
      im[0] *= __bfloat162float(w1r[0]) * sc;
      re[1] *= __bfloat162float(w0r[1024]) * sc;
      im[1] *= __bfloat162float(w1r[1024]) * sc;
    } else {
      const int p1 = PADI(__brev((unsigned)k) >> 21);
      const int p2 = PADI(__brev((unsigned)(SS - k)) >> 21);
      const float ra = re[p1], ia = im[p1];
      const float rb = re[p2], ib = im[p2];
      const float z0r = 0.5f * (ra + rb), z0i = 0.5f * (ia - ib);
      const float z1r = 0.5f * (ia + ib), z1i = -0.5f * (ra - rb);
      const float a0 = __bfloat162float(w0r[k]) * sc, b0 = __bfloat162float(w0i[k]) * sc;
      const float a1 = __bfloat162float(w1r[k]) * sc, b1 = __bfloat162float(w1i[k]) * sc;
      const float y0r = z0r * a0 - z0i * b0, y0i = z0r * b0 + z0i * a0;
      const float y1r = z1r * a1 - z1i * b1, y1i = z1r * b1 + z1i * a1;
      re[p1] = y0r - y1i; im[p1] = y0i + y1r;
      re[p2] = y0r + y1i; im[p2] = y1r - y0i;
    }
  }

  // inverse DIT (bit-reversed -> natural, conjugate twiddles)
  for (int stage = 1; stage <= 11; ++stage) {
    __syncthreads();
    const int half = 1 << (stage - 1);
    const float ang0 = 6.283185307179586f / (float)(1 << stage);
#pragma unroll 4
    for (int t = tid; t < SS / 2; t += 256) {
      const int gI = t >> (stage - 1);
      const int p = t & (half - 1);
      const int i = (gI << stage) + p;
      const int j = i + half;
      float sn, cs;
      __sincosf(ang0 * (float)p, &sn, &cs);
      const int ii = PADI(i), jj = PADI(j);
      const float br = re[jj], bi = im[jj];
      const float tr = br * cs - bi * sn;
      const float ti = br * sn + bi * cs;
      const float ar = re[ii], ai = im[ii];
      re[ii] = ar + tr; im[ii] = ai + ti;
      re[jj] = ar - tr; im[jj] = ai - ti;
    }
  }
  __syncthreads();

  for (int s4 = tid * 4; s4 < SS; s4 += 1024) {
    const int p = PADI(s4);
    float4 a, c;
    a.x = re[p]; a.y = re[p + 1]; a.z = re[p + 2]; a.w = re[p + 3];
    c.x = im[p]; c.y = im[p + 1]; c.z = im[p + 2]; c.w = im[p + 3];
    *(float4*)(col0 + s4) = a;
    *(float4*)(col1 + s4) = c;
  }
}

// ---------------------------------------------------------------------------
// Fused launch 1: blocks [0,768) = QKV GEMM (4096x3072x1024, bf16 out);
// blocks [768,1792) = spectral FFT (independent inputs). Dynamic LDS 16896 B.
// ---------------------------------------------------------------------------
__global__ __launch_bounds__(256) void gemm1_spec(
    const __hip_bfloat16* __restrict__ x_bf, const __hip_bfloat16* __restrict__ w_in_bf,
    const float* __restrict__ in_b, __hip_bfloat16* __restrict__ qkv_bf,
    float* __restrict__ xT, const __hip_bfloat16* __restrict__ wrT,
    const __hip_bfloat16* __restrict__ wiT) {
  extern __shared__ __align__(16) char smem[];
  if (blockIdx.x < 768) {
    const int id = blockIdx.x;
    const int col0 = (id % 24) * 128;
    const int row0 = (id / 24) * 128;
    gemm_tile128<true>(x_bf, w_in_bf, in_b, qkv_bf, 3 * DD, DD, row0, col0,
                       (__hip_bfloat16*)smem, (__hip_bfloat16*)smem + 4096);
  } else {
    spec_body(blockIdx.x - 768, xT, wrT, wiT, (float*)smem);
  }
}

// ---------------------------------------------------------------------------
// Fused launch 2: blocks [0,256) = out-proj GEMM (4096x1024x1024, bf16 out);
// blocks [256,1280) = transpose-back xT[b][d][s] -> x_wave_bf[b][s][d] bf16.
// Dynamic LDS 16640 B.
// ---------------------------------------------------------------------------
__global__ __launch_bounds__(256) void gemm2_tback(
    const __hip_bfloat16* __restrict__ attn_bf, const __hip_bfloat16* __restrict__ w_out_bf,
    const float* __restrict__ out_b, __hip_bfloat16* __restrict__ attn_out_bf,
    const float* __restrict__ xT, __hip_bfloat16* __restrict__ x_wave_bf) {
  extern __shared__ __align__(16) char smem[];
  if (blockIdx.x < 256) {
    const int id = blockIdx.x;
    const int col0 = (id % 8) * 128;
    const int row0 = (id / 8) * 128;
    gemm_tile128<true>(attn_bf, w_out_bf, out_b, attn_out_bf, DD, DD, row0, col0,
                       (__hip_bfloat16*)smem, (__hip_bfloat16*)smem + 4096);
  } else {
    float (*tile)[65] = (float(*)[65])smem;
    const int id = blockIdx.x - 256;          // 0..1023
    const int bz = id >> 9;
    const int rem = id & 511;
    const int s0 = (rem >> 4) * 64;
    const int d0 = (rem & 15) * 64;
    const int tx = threadIdx.x & 63;
    const int ty = threadIdx.x >> 6;
    const float* src = xT + (size_t)bz * DD * SS;
    __hip_bfloat16* dst = x_wave_bf + (size_t)bz * SS * DD;
#pragma unroll
    for (int i = 0; i < 16; ++i) {
      const int r = ty * 16 + i;
      tile[r][tx] = src[(size_t)(d0 + r) * SS + s0 + tx];
    }
    __syncthreads();
#pragma unroll
    for (int i = 0; i < 16; ++i) {
      const int c = ty * 16 + i;
      dst[(size_t)(s0 + c) * DD + d0 + tx] = __float2bfloat16(tile[tx][c]);
    }
  }
}

// ---------------------------------------------------------------------------
// Flash-style MFMA sliding-window attention (unchanged from R6).
// ---------------------------------------------------------------------------
__global__ __launch_bounds__(256, 2) void attn_mfma(
    const __hip_bfloat16* __restrict__ qkv, __hip_bfloat16* __restrict__ attn) {
  __shared__ __attribute__((aligned(16))) __hip_bfloat16 QsA[64 * 32];
  __shared__ __attribute__((aligned(16))) __hip_bfloat16 QsB[64 * 32];
  __shared__ __attribute__((aligned(16))) __hip_bfloat16 KsA[160 * 32];
  __shared__ __attribute__((aligned(16))) __hip_bfloat16 KsB[160 * 32];
  __shared__ __attribute__((aligned(16))) __hip_bfloat16 Vt[64 * 168];
  __shared__ __attribute__((aligned(16))) __hip_bfloat16 Ps[64 * 168];

  const int tid  = threadIdx.x;
  const int lane = tid & 63;
  const int w    = tid >> 6;
  const int quad = lane >> 4;
  const int l16  = lane & 15;
  const int q0   = blockIdx.x * 64;
  const int h    = blockIdx.y;
  const int b    = blockIdx.z;
  const int kbase = q0 - WINW;

  const int r_ = tid >> 2;
  const int c8 = (tid & 3) * 8;

  {
    const __hip_bfloat16* src = qkv + ((size_t)(b * SS + q0 + r_)) * (3 * DD) + h * DHH;
    load16_lds(src + c8,      &QsA[r_ * 32 + c8]);
    load16_lds(src + 32 + c8, &QsB[r_ * 32 + c8]);
  }

  short8 qf0, qf1;
  float m_run[4] = {-1e30f, -1e30f, -1e30f, -1e30f};
  float l_run[4] = {0.f, 0.f, 0.f, 0.f};
  floatx4 ob[4] = {};

  for (int c = 0; c < 2; ++c) {
    const int ck0 = kbase + c * 160;
    __syncthreads();
#pragma unroll
    for (int it = 0; it < 3; ++it) {
      const int r = it * 64 + r_;
      if (r < 160) {
        int key = ck0 + r; key = key < 0 ? 0 : (key > SS - 1 ? SS - 1 : key);
        const __hip_bfloat16* src = qkv + ((size_t)(b * SS + key)) * (3 * DD) + DD + h * DHH;
        load16_lds(src + c8,      &KsA[r * 32 + c8]);
        load16_lds(src + 32 + c8, &KsB[r * 32 + c8]);
      }
    }
    {
      const int k4 = (tid >> 3) * 4;
      const int d8 = (tid & 7) * 8;
#pragma unroll
      for (int it = 0; it < 2; ++it) {
        const int rr = it * 128 + k4;
        if (rr < 160) {
          short8 v[4];
#pragma unroll
          for (int u = 0; u < 4; ++u) {
            int key = ck0 + rr + u; key = key < 0 ? 0 : (key > SS - 1 ? SS - 1 : key);
            v[u] = *(const short8*)(qkv + ((size_t)(b * SS + key)) * (3 * DD) + 2 * DD + h * DHH + d8);
          }
#pragma unroll
          for (int j = 0; j < 8; ++j) {
            short4v pk; pk[0] = v[0][j]; pk[1] = v[1][j]; pk[2] = v[2][j]; pk[3] = v[3][j];
            *(short4v*)&Vt[(d8 + j) * 168 + rr] = pk;
          }
        }
      }
    }
    __syncthreads();

    if (c == 0) {
      qf0 = *(const short8*)&QsA[(w * 16 + l16) * 32 + quad * 8];
      qf1 = *(const short8*)&QsB[(w * 16 + l16) * 32 + quad * 8];
    }

    floatx4 sc[10];
#pragma unroll
    for (int kt = 0; kt < 10; ++kt) {
      const short8 bk0 = *(const short8*)&KsA[(kt * 16 + l16) * 32 + quad * 8];
      const short8 bk1 = *(const short8*)&KsB[(kt * 16 + l16) * 32 + quad * 8];
      floatx4 a = {};
      a = __builtin_amdgcn_mfma_f32_16x16x32_bf16(qf0, bk0, a, 0, 0, 0);
      a = __builtin_amdgcn_mfma_f32_16x16x32_bf16(qf1, bk1, a, 0, 0, 0);
      sc[kt] = a;
    }

    float cm[4] = {-1e30f, -1e30f, -1e30f, -1e30f};
#pragma unroll
    for (int kt = 0; kt < 10; ++kt) {
      const int key = ck0 + kt * 16 + l16;
#pragma unroll
      for (int r = 0; r < 4; ++r) {
        const int qq = q0 + w * 16 + quad * 4 + r;
        const int dqk = qq - key;
        const bool ok = (key >= 0) & (key < SS) & (dqk <= WINW) & (dqk >= -WINW);
        const float s = ok ? sc[kt][r] * 0.125f : -1e30f;
        sc[kt][r] = s;
        cm[r] = fmaxf(cm[r], s);
      }
    }
#pragma unroll
    for (int off = 1; off < 16; off <<= 1)
#pragma unroll
      for (int r = 0; r < 4; ++r) cm[r] = fmaxf(cm[r], __shfl_xor(cm[r], off, 64));

    float alpha[4], csum[4] = {0.f, 0.f, 0.f, 0.f};
#pragma unroll
    for (int r = 0; r < 4; ++r) {
      const float mn = fmaxf(m_run[r], cm[r]);
      alpha[r] = __expf(m_run[r] - mn);
      m_run[r] = mn;
    }

    __hip_bfloat16* Pw = &Ps[w * 16 * 168];
#pragma unroll
    for (int kt = 0; kt < 10; ++kt) {
#pragma unroll
      for (int r = 0; r < 4; ++r) {
        const float p = __expf(sc[kt][r] - m_run[r]);
        csum[r] += p;
        Pw[(quad * 4 + r) * 168 + kt * 16 + l16] = __float2bfloat16(p);
      }
    }
#pragma unroll
    for (int off = 1; off < 16; off <<= 1)
#pragma unroll
      for (int r = 0; r < 4; ++r) csum[r] += __shfl_xor(csum[r], off, 64);
#pragma unroll
    for (int r = 0; r < 4; ++r) l_run[r] = l_run[r] * alpha[r] + csum[r];
#pragma unroll
    for (int t = 0; t < 4; ++t)
#pragma unroll
      for (int r = 0; r < 4; ++r) ob[t][r] *= alpha[r];

#pragma unroll
    for (int kt = 0; kt < 5; ++kt) {
      const short8 pf = *(const short8*)&Pw[l16 * 168 + kt * 32 + quad * 8];
#pragma unroll
      for (int t = 0; t < 4; ++t) {
        const short8 vf = *(const short8*)&Vt[(t * 16 + l16) * 168 + kt * 32 + quad * 8];
        ob[t] = __builtin_amdgcn_mfma_f32_16x16x32_bf16(pf, vf, ob[t], 0, 0, 0);
      }
    }
  }

  float inv[4];
#pragma unroll
  for (int r = 0; r < 4; ++r) inv[r] = 1.f / l_run[r];
  const int qq0 = q0 + w * 16 + quad * 4;
#pragma unroll
  for (int t = 0; t < 4; ++t)
#pragma unroll
    for (int r = 0; r < 4; ++r)
      attn[((size_t)(b * SS + qq0 + r)) * DD + h * DHH + t * 16 + l16] =
          __float2bfloat16(ob[t][r] * inv[r]);
}

// ---------------------------------------------------------------------------
// Fused double LayerNorm: out = LN2( LN1(x + attn_out) + x_wave ), one block
// per row; x_attn never materialized.
// ---------------------------------------------------------------------------
__global__ __launch_bounds__(256) void ln_fused(
    const float* __restrict__ x, const __hip_bfloat16* __restrict__ attn_out,
    const float* __restrict__ g1, const float* __restrict__ b1,
    const __hip_bfloat16* __restrict__ xwave,
    const float* __restrict__ g2, const float* __restrict__ b2,
    float* __restrict__ out) {
  const int row = blockIdx.x;
  const int tid = threadIdx.x;
  const int lane = tid & 63;
  const int wave = tid >> 6;
  __shared__ float red[8];

  const float4 xv = *(const float4*)(x + (size_t)row * DD + tid * 4);
  const short4v av = *(const short4v*)(attn_out + (size_t)row * DD + tid * 4);
  float v[4] = {xv.x + bf2f(av[0]), xv.y + bf2f(av[1]),
                xv.z + bf2f(av[2]), xv.w + bf2f(av[3])};

  float s = v[0] + v[1] + v[2] + v[3];
  float s2 = v[0] * v[0] + v[1] * v[1] + v[2] * v[2] + v[3] * v[3];
#pragma unroll
  for (int off = 32; off; off >>= 1) {
    s += __shfl_xor(s, off, 64);
    s2 += __shfl_xor(s2, off, 64);
  }
  if (lane == 0) { red[wave] = s; red[4 + wave] = s2; }
  __syncthreads();
  s = red[0] + red[1] + red[2] + red[3];
  s2 = red[4] + red[5] + red[6] + red[7];
  float mu = s * (1.f / DD);
  float var = s2 * (1.f / DD) - mu * mu;
  float r = rsqrtf(var + 1e-5f);

  const float4 g1v = *(const float4*)(g1 + tid * 4);
  const float4 b1v = *(const float4*)(b1 + tid * 4);
  const short4v wv = *(const short4v*)(xwave + (size_t)row * DD + tid * 4);
  float a[4];
  a[0] = (v[0] - mu) * r * g1v.x + b1v.x + bf2f(wv[0]);
  a[1] = (v[1] - mu) * r * g1v.y + b1v.y + bf2f(wv[1]);
  a[2] = (v[2] - mu) * r * g1v.z + b1v.z + bf2f(wv[2]);
  a[3] = (v[3] - mu) * r * g1v.w + b1v.w + bf2f(wv[3]);

  s = a[0] + a[1] + a[2] + a[3];
  s2 = a[0] * a[0] + a[1] * a[1] + a[2] * a[2] + a[3] * a[3];
#pragma unroll
  for (int off = 32; off; off >>= 1) {
    s += __shfl_xor(s, off, 64);
    s2 += __shfl_xor(s2, off, 64);
  }
  __syncthreads();    // red[] reuse
  if (lane == 0) { red[wave] = s; red[4 + wave] = s2; }
  __syncthreads();
  s = red[0] + red[1] + red[2] + red[3];
  s2 = red[4] + red[5] + red[6] + red[7];
  mu = s * (1.f / DD);
  var = s2 * (1.f / DD) - mu * mu;
  r = rsqrtf(var + 1e-5f);

  const float4 g2v = *(const float4*)(g2 + tid * 4);
  const float4 b2v = *(const float4*)(b2 + tid * 4);
  float4 o;
  o.x = (a[0] - mu) * r * g2v.x + b2v.x;
  o.y = (a[1] - mu) * r * g2v.y + b2v.y;
  o.z = (a[2] - mu) * r * g2v.z + b2v.z;
  o.w = (a[3] - mu) * r * g2v.w + b2v.w;
  *(float4*)(out + (size_t)row * DD + tid * 4) = o;
}

// ---------------------------------------------------------------------------
extern "C" void kernel_launch(void* const* d_in, const int* in_sizes, int n_in,
                              void* d_out, int out_size, void* d_ws, size_t ws_size,
                              hipStream_t stream) {
  const float* x     = (const float*)d_in[0];
  const float* in_w  = (const float*)d_in[1];
  const float* in_b  = (const float*)d_in[2];
  const float* out_w = (const float*)d_in[3];
  const float* out_b = (const float*)d_in[4];
  const float* ln1_g = (const float*)d_in[5];
  const float* ln1_b = (const float*)d_in[6];
  const float* wr    = (const float*)d_in[7];
  const float* wi    = (const float*)d_in[8];
  const float* ln2_g = (const float*)d_in[9];
  const float* ln2_b = (const float*)d_in[10];
  float* out = (float*)d_out;

  char* ws = (char*)d_ws;
  // Workspace (<= 64 MB), phase-reused:
  //  [0,16)       xT fp32 (live through gemm2_tback; spec FFT in place)
  //  [16,24)      x_bf16 (dead after gemm1) -> attn_bf16 (attn output)
  //  [24,30)      w_in_bf (dead after gemm1)
  //  [30,32)      w_out_bf (dead after gemm2)
  //  [32,56)      qkv_bf16 (dead after attn) -> attn_out_bf [32,40.4) +
  //               x_wave_bf [42,50.4)
  //  [56,60.2)    wrT bf16 ; [60.2,64.4)... bf16 -> fits: 2.1 MB each
  float* xT                = (float*)(ws);
  __hip_bfloat16* x_bf     = (__hip_bfloat16*)(ws + 16777216);
  __hip_bfloat16* attn_bf  = (__hip_bfloat16*)(ws + 16777216);
  __hip_bfloat16* w_in_bf  = (__hip_bfloat16*)(ws + 25165824);
  __hip_bfloat16* w_out_bf = (__hip_bfloat16*)(ws + 31457280);
  __hip_bfloat16* qkv_bf   = (__hip_bfloat16*)(ws + 33554432);
  __hip_bfloat16* attn_out_bf = (__hip_bfloat16*)(ws + 33554432);
  __hip_bfloat16* x_wave_bf   = (__hip_bfloat16*)(ws + 44040192);
  __hip_bfloat16* wrT      = (__hip_bfloat16*)(ws + 58720256);
  __hip_bfloat16* wiT      = (__hip_bfloat16*)(ws + 60819456);

  // 1. x -> xT fp32 + x_bf bf16 (one read of x)
  transpose_x_cast<<<dim3(16, 32, 2), 256, 0, stream>>>(x, xT, x_bf);

  // 2. weight casts
  cast_w<<<4096, 256, 0, stream>>>(in_w, out_w, w_in_bf, w_out_bf);

  // 3. wr/wi -> bf16 transposed
  transpose_wrwi_bf<<<dim3(16, 17, 2), 256, 0, stream>>>(wr, wi, wrT, wiT);

  // 4. fused: QKV GEMM (768 blocks) + spectral FFT (1024 blocks)
  gemm1_spec<<<1792, 256, 16896, stream>>>(x_bf, w_in_bf, in_b, qkv_bf,
                                           xT, wrT, wiT);

  // 5. flash MFMA sliding-window attention -> attn_bf
  attn_mfma<<<dim3(SS / 64, HH, BB), 256, 0, stream>>>(qkv_bf, attn_bf);

  // 6. fused: out-proj GEMM (256 blocks) + transpose-back (1024 blocks)
  gemm2_tback<<<1280, 256, 16640, stream>>>(attn_bf, w_out_bf, out_b,
                                            attn_out_bf, xT, x_wave_bf);

  // 7. fused LN1+LN2 -> out
  ln_fused<<<MROWS, 256, 0, stream>>>(x, attn_out_bf, ln1_g, ln1_b,
                                      x_wave_bf, ln2_g, ln2_b, out);
}

// Round 8
// 230.507 us; speedup vs baseline: 6.8065x; 1.0093x over previous
//
#include <hip/hip_runtime.h>
#include <hip/hip_bf16.h>
#include <math.h>

// Problem constants (B,S,D,H,WIN) = (2,2048,1024,16,128), DH=64
#define BB    2
#define SS    2048
#define DD    1024
#define HH    16
#define DHH   64
#define WINW  128
#define MROWS (BB * SS)          // 4096

typedef __attribute__((ext_vector_type(8))) short short8;
typedef __attribute__((ext_vector_type(4))) short short4v;
typedef __attribute__((ext_vector_type(4))) float floatx4;

__device__ __forceinline__ float bf2f(short s) {
  union { unsigned u; float f; } t;
  t.u = ((unsigned)(unsigned short)s) << 16;
  return t.f;
}

// ---------------------------------------------------------------------------
__device__ inline void load16_lds(const __hip_bfloat16* g, __hip_bfloat16* l) {
  __builtin_amdgcn_global_load_lds(
      (const __attribute__((address_space(1))) uint32_t*)g,
      (__attribute__((address_space(3))) uint32_t*)l, 16, 0, 0);
}

// ---------------------------------------------------------------------------
// Fused preprocessing (one launch, 2592 blocks):
//  [0,1024)    x [B][S][D] fp32 -> xT [B][D][S] fp32 + x_bf bf16 row-major
//  [1024,2048) weight casts fp32->bf16 (w_in then w_out)
//  [2048,2592) wr/wi [1025][1024] -> bf16 transposed [1024][1025]
// ---------------------------------------------------------------------------
__global__ __launch_bounds__(256) void prep_fused(
    const float* __restrict__ x, float* __restrict__ xT,
    __hip_bfloat16* __restrict__ x_bf,
    const float* __restrict__ w_in, const float* __restrict__ w_out,
    __hip_bfloat16* __restrict__ w_in_bf, __hip_bfloat16* __restrict__ w_out_bf,
    const float* __restrict__ wr, const float* __restrict__ wi,
    __hip_bfloat16* __restrict__ wrT, __hip_bfloat16* __restrict__ wiT) {
  __shared__ float tile[64][65];
  const int id = blockIdx.x;
  const int tx = threadIdx.x & 63;
  const int ty = threadIdx.x >> 6;

  if (id < 1024) {
    // x transpose + cast
    const int bz = id >> 9;
    const int rem = id & 511;
    const int c0 = (rem & 15) * 64;   // D
    const int r0 = (rem >> 4) * 64;   // S
    const size_t base = (size_t)bz * SS * DD;
#pragma unroll
    for (int i = 0; i < 16; ++i) {
      const int r = ty * 16 + i;
      const float v = x[base + (size_t)(r0 + r) * DD + c0 + tx];
      tile[r][tx] = v;
      x_bf[base + (size_t)(r0 + r) * DD + c0 + tx] = __float2bfloat16(v);
    }
    __syncthreads();
#pragma unroll
    for (int i = 0; i < 16; ++i) {
      const int c = ty * 16 + i;
      xT[base + (size_t)(c0 + c) * SS + r0 + tx] = tile[tx][c];
    }
  } else if (id < 2048) {
    // weight casts: 4096 elems per block
    const int blk = id - 1024;
    const float* src; __hip_bfloat16* dst; size_t off;
    if (blk < 768) { src = w_in; dst = w_in_bf; off = (size_t)blk * 4096; }
    else { src = w_out; dst = w_out_bf; off = (size_t)(blk - 768) * 4096; }
#pragma unroll
    for (int c = 0; c < 4; ++c) {
      const size_t j = off + c * 1024 + threadIdx.x * 4;
      const float4 v = *(const float4*)(src + j);
      dst[j + 0] = __float2bfloat16(v.x);
      dst[j + 1] = __float2bfloat16(v.y);
      dst[j + 2] = __float2bfloat16(v.z);
      dst[j + 3] = __float2bfloat16(v.w);
    }
  } else {
    // wr/wi transpose -> bf16
    const int id2 = id - 2048;               // 0..543
    const int half = id2 >= 272;
    const int rem = id2 - (half ? 272 : 0);
    const float* src = half ? wi : wr;
    __hip_bfloat16* dst = half ? wiT : wrT;
    const int R = 1025, C = DD;
    const int c0 = (rem & 15) * 64;
    const int r0 = (rem >> 4) * 64;
#pragma unroll
    for (int i = 0; i < 16; ++i) {
      const int r = ty * 16 + i;
      if (r0 + r < R) tile[r][tx] = src[(size_t)(r0 + r) * C + c0 + tx];
    }
    __syncthreads();
#pragma unroll
    for (int i = 0; i < 16; ++i) {
      const int c = ty * 16 + i;
      if (r0 + tx < R) dst[(size_t)(c0 + c) * R + r0 + tx] = __float2bfloat16(tile[tx][c]);
    }
  }
}

// ---------------------------------------------------------------------------
// bf16 MFMA GEMM tile body: C[128,128] tile at (row0,col0) of
// C[M,N] = A[M,K]*B[N,K]^T + bias.  256 threads, BK=64 via two 32-wide
// buffer pairs (keeps conflict-free stride-32 layout + wave-uniform
// global_load_lds dest). Half the barriers of BK=32. sm: 16384 bf16 (32 KB).
// ---------------------------------------------------------------------------
template <bool BF16OUT>
__device__ __forceinline__ void gemm_tile128(
    const __hip_bfloat16* __restrict__ A, const __hip_bfloat16* __restrict__ B,
    const float* __restrict__ bias, void* __restrict__ Cp,
    int N, int K, int row0, int col0, __hip_bfloat16* sm) {
  __hip_bfloat16* As0 = sm;
  __hip_bfloat16* As1 = sm + 4096;
  __hip_bfloat16* Bs0 = sm + 8192;
  __hip_bfloat16* Bs1 = sm + 12288;
  const int tid  = threadIdx.x;
  const int lane = tid & 63;
  const int wave = tid >> 6;
  const int wrow = (wave >> 1) * 64;
  const int wcol = (wave & 1) * 64;
  const int srow = tid >> 2;
  const int skk  = (tid & 3) * 8;
  const int quad = lane >> 4;
  const int l16  = lane & 15;
  floatx4 acc[4][4] = {};
  for (int k0 = 0; k0 < K; k0 += 64) {
    __syncthreads();
    load16_lds(A + (size_t)(row0 + srow) * K + k0 + skk,           &As0[tid * 8]);
    load16_lds(A + (size_t)(row0 + 64 + srow) * K + k0 + skk,      &As0[2048 + tid * 8]);
    load16_lds(A + (size_t)(row0 + srow) * K + k0 + 32 + skk,      &As1[tid * 8]);
    load16_lds(A + (size_t)(row0 + 64 + srow) * K + k0 + 32 + skk, &As1[2048 + tid * 8]);
    load16_lds(B + (size_t)(col0 + srow) * K + k0 + skk,           &Bs0[tid * 8]);
    load16_lds(B + (size_t)(col0 + 64 + srow) * K + k0 + skk,      &Bs0[2048 + tid * 8]);
    load16_lds(B + (size_t)(col0 + srow) * K + k0 + 32 + skk,      &Bs1[tid * 8]);
    load16_lds(B + (size_t)(col0 + 64 + srow) * K + k0 + 32 + skk, &Bs1[2048 + tid * 8]);
    __syncthreads();
    {
      short8 af[4], bf[4];
#pragma unroll
      for (int i = 0; i < 4; ++i)
        af[i] = *(const short8*)&As0[(wrow + i * 16 + l16) * 32 + quad * 8];
#pragma unroll
      for (int j = 0; j < 4; ++j)
        bf[j] = *(const short8*)&Bs0[(wcol + j * 16 + l16) * 32 + quad * 8];
#pragma unroll
      for (int i = 0; i < 4; ++i)
#pragma unroll
        for (int j = 0; j < 4; ++j)
          acc[i][j] = __builtin_amdgcn_mfma_f32_16x16x32_bf16(af[i], bf[j], acc[i][j], 0, 0, 0);
    }
    {
      short8 af[4], bf[4];
#pragma unroll
      for (int i = 0; i < 4; ++i)
        af[i] = *(const short8*)&As1[(wrow + i * 16 + l16) * 32 + quad * 8];
#pragma unroll
      for (int j = 0; j < 4; ++j)
        bf[j] = *(const short8*)&Bs1[(wcol + j * 16 + l16) * 32 + quad * 8];
#pragma unroll
      for (int i = 0; i < 4; ++i)
#pragma unroll
        for (int j = 0; j < 4; ++j)
          acc[i][j] = __builtin_amdgcn_mfma_f32_16x16x32_bf16(af[i], bf[j], acc[i][j], 0, 0, 0);
    }
  }
#pragma unroll
  for (int i = 0; i < 4; ++i) {
#pragma unroll
    for (int j = 0; j < 4; ++j) {
      const int col = col0 + wcol + j * 16 + l16;
      const float bs = bias[col];
#pragma unroll
      for (int r = 0; r < 4; ++r) {
        const int row = row0 + wrow + i * 16 + quad * 4 + r;
        if (BF16OUT)
          ((__hip_bfloat16*)Cp)[(size_t)row * N + col] = __float2bfloat16(acc[i][j][r] + bs);
        else
          ((float*)Cp)[(size_t)row * N + col] = acc[i][j][r] + bs;
      }
    }
  }
}

// ---------------------------------------------------------------------------
// Spectral FFT body (one block = one d-pair of one batch). LDS padded
// a -> a+(a>>5); twiddles on the fly; 1/S scale folded into filter.
// sm must hold 2*2112 floats (16896 B).
// ---------------------------------------------------------------------------
#define PADI(a) ((a) + ((a) >> 5))

__device__ __forceinline__ void spec_body(
    int sid, float* __restrict__ xT,
    const __hip_bfloat16* __restrict__ wrT, const __hip_bfloat16* __restrict__ wiT,
    float* sm) {
  float* re = sm;
  float* im = sm + 2112;
  const int tid = threadIdx.x;
  const int dpair = sid & 511;
  const int b = sid >> 9;
  const int d0 = dpair * 2, d1 = d0 + 1;
  float* col0 = xT + ((size_t)b * DD + d0) * SS;
  float* col1 = xT + ((size_t)b * DD + d1) * SS;

  for (int s4 = tid * 4; s4 < SS; s4 += 1024) {
    const float4 a = *(const float4*)(col0 + s4);
    const float4 c = *(const float4*)(col1 + s4);
    const int p = PADI(s4);
    re[p] = a.x; re[p + 1] = a.y; re[p + 2] = a.z; re[p + 3] = a.w;
    im[p] = c.x; im[p + 1] = c.y; im[p + 2] = c.z; im[p + 3] = c.w;
  }

  // forward DIF (natural -> bit-reversed)
  for (int stage = 11; stage >= 1; --stage) {
    __syncthreads();
    const int half = 1 << (stage - 1);
    const float ang0 = -6.283185307179586f / (float)(1 << stage);
#pragma unroll 4
    for (int t = tid; t < SS / 2; t += 256) {
      const int gI = t >> (stage - 1);
      const int p = t & (half - 1);
      const int i = (gI << stage) + p;
      const int j = i + half;
      float sn, cs;
      __sincosf(ang0 * (float)p, &sn, &cs);
      const int ii = PADI(i), jj = PADI(j);
      const float ar = re[ii], ai = im[ii], br = re[jj], bi = im[jj];
      re[ii] = ar + br; im[ii] = ai + bi;
      const float dr = ar - br, di = ai - bi;
      re[jj] = dr * cs - di * sn;
      im[jj] = dr * sn + di * cs;
    }
  }
  __syncthreads();

  // packed Hermitian filter
  const __hip_bfloat16* w0r = wrT + (size_t)d0 * 1025;
  const __hip_bfloat16* w0i = wiT + (size_t)d0 * 1025;
  const __hip_bfloat16* w1r = wrT + (size_t)d1 * 1025;
  const __hip_bfloat16* w1i = wiT + (size_t)d1 * 1025;
  const float sc = 1.0f / (float)SS;
  for (int k = tid; k < 1024; k += 256) {
    if (k == 0) {
      re[0] *= __bfloat162float(w0r[0]) * sc;
      im[0] *= __bfloat162float(w1r[0]) * sc;
      re[1] *= __bfloat162float(w0r[1024]) * sc;
      im[1] *= __bfloat162float(w1r[1024]) * sc;
    } else {
      const int p1 = PADI(__brev((unsigned)k) >> 21);
      const int p2 = PADI(__brev((unsigned)(SS - k)) >> 21);
      const float ra = re[p1], ia = im[p1];
      const float rb = re[p2], ib = im[p2];
      const float z0r = 0.5f * (ra + rb), z0i = 0.5f * (ia - ib);
      const float z1r = 0.5f * (ia + ib), z1i = -0.5f * (ra - rb);
      const float a0 = __bfloat162float(w0r[k]) * sc, b0 = __bfloat162float(w0i[k]) * sc;
      const float a1 = __bfloat162float(w1r[k]) * sc, b1 = __bfloat162float(w1i[k]) * sc;
      const float y0r = z0r * a0 - z0i * b0, y0i = z0r * b0 + z0i * a0;
      const float y1r = z1r * a1 - z1i * b1, y1i = z1r * b1 + z1i * a1;
      re[p1] = y0r - y1i; im[p1] = y0i + y1r;
      re[p2] = y0r + y1i; im[p2] = y1r - y0i;
    }
  }

  // inverse DIT (bit-reversed -> natural, conjugate twiddles)
  for (int stage = 1; stage <= 11; ++stage) {
    __syncthreads();
    const int half = 1 << (stage - 1);
    const float ang0 = 6.283185307179586f / (float)(1 << stage);
#pragma unroll 4
    for (int t = tid; t < SS / 2; t += 256) {
      const int gI = t >> (stage - 1);
      const int p = t & (half - 1);
      const int i = (gI << stage) + p;
      const int j = i + half;
      float sn, cs;
      __sincosf(ang0 * (float)p, &sn, &cs);
      const int ii = PADI(i), jj = PADI(j);
      const float br = re[jj], bi = im[jj];
      const float tr = br * cs - bi * sn;
      const float ti = br * sn + bi * cs;
      const float ar = re[ii], ai = im[ii];
      re[ii] = ar + tr; im[ii] = ai + ti;
      re[jj] = ar - tr; im[jj] = ai - ti;
    }
  }
  __syncthreads();

  for (int s4 = tid * 4; s4 < SS; s4 += 1024) {
    const int p = PADI(s4);
    float4 a, c;
    a.x = re[p]; a.y = re[p + 1]; a.z = re[p + 2]; a.w = re[p + 3];
    c.x = im[p]; c.y = im[p + 1]; c.z = im[p + 2]; c.w = im[p + 3];
    *(float4*)(col0 + s4) = a;
    *(float4*)(col1 + s4) = c;
  }
}

// ---------------------------------------------------------------------------
// Fused launch 1: blocks [0,768) = QKV GEMM (4096x3072x1024, bf16 out);
// blocks [768,1792) = spectral FFT. Dynamic LDS 32768 B.
// ---------------------------------------------------------------------------
__global__ __launch_bounds__(256) void gemm1_spec(
    const __hip_bfloat16* __restrict__ x_bf, const __hip_bfloat16* __restrict__ w_in_bf,
    const float* __restrict__ in_b, __hip_bfloat16* __restrict__ qkv_bf,
    float* __restrict__ xT, const __hip_bfloat16* __restrict__ wrT,
    const __hip_bfloat16* __restrict__ wiT) {
  extern __shared__ __align__(16) char smem[];
  if (blockIdx.x < 768) {
    const int id = blockIdx.x;
    const int col0 = (id % 24) * 128;
    const int row0 = (id / 24) * 128;
    gemm_tile128<true>(x_bf, w_in_bf, in_b, qkv_bf, 3 * DD, DD, row0, col0,
                       (__hip_bfloat16*)smem);
  } else {
    spec_body(blockIdx.x - 768, xT, wrT, wiT, (float*)smem);
  }
}

// ---------------------------------------------------------------------------
// Fused launch 2: blocks [0,256) = out-proj GEMM (4096x1024x1024, bf16 out);
// blocks [256,1280) = transpose-back xT[b][d][s] -> x_wave_bf[b][s][d] bf16.
// Dynamic LDS 32768 B.
// ---------------------------------------------------------------------------
__global__ __launch_bounds__(256) void gemm2_tback(
    const __hip_bfloat16* __restrict__ attn_bf, const __hip_bfloat16* __restrict__ w_out_bf,
    const float* __restrict__ out_b, __hip_bfloat16* __restrict__ attn_out_bf,
    const float* __restrict__ xT, __hip_bfloat16* __restrict__ x_wave_bf) {
  extern __shared__ __align__(16) char smem[];
  if (blockIdx.x < 256) {
    const int id = blockIdx.x;
    const int col0 = (id % 8) * 128;
    const int row0 = (id / 8) * 128;
    gemm_tile128<true>(attn_bf, w_out_bf, out_b, attn_out_bf, DD, DD, row0, col0,
                       (__hip_bfloat16*)smem);
  } else {
    float (*tile)[65] = (float(*)[65])smem;
    const int id = blockIdx.x - 256;          // 0..1023
    const int bz = id >> 9;
    const int rem = id & 511;
    const int s0 = (rem >> 4) * 64;
    const int d0 = (rem & 15) * 64;
    const int tx = threadIdx.x & 63;
    const int ty = threadIdx.x >> 6;
    const float* src = xT + (size_t)bz * DD * SS;
    __hip_bfloat16* dst = x_wave_bf + (size_t)bz * SS * DD;
#pragma unroll
    for (int i = 0; i < 16; ++i) {
      const int r = ty * 16 + i;
      tile[r][tx] = src[(size_t)(d0 + r) * SS + s0 + tx];
    }
    __syncthreads();
#pragma unroll
    for (int i = 0; i < 16; ++i) {
      const int c = ty * 16 + i;
      dst[(size_t)(s0 + c) * DD + d0 + tx] = __float2bfloat16(tile[tx][c]);
    }
  }
}

// ---------------------------------------------------------------------------
// Flash-style MFMA sliding-window attention (unchanged).
// ---------------------------------------------------------------------------
__global__ __launch_bounds__(256, 2) void attn_mfma(
    const __hip_bfloat16* __restrict__ qkv, __hip_bfloat16* __restrict__ attn) {
  __shared__ __attribute__((aligned(16))) __hip_bfloat16 QsA[64 * 32];
  __shared__ __attribute__((aligned(16))) __hip_bfloat16 QsB[64 * 32];
  __shared__ __attribute__((aligned(16))) __hip_bfloat16 KsA[160 * 32];
  __shared__ __attribute__((aligned(16))) __hip_bfloat16 KsB[160 * 32];
  __shared__ __attribute__((aligned(16))) __hip_bfloat16 Vt[64 * 168];
  __shared__ __attribute__((aligned(16))) __hip_bfloat16 Ps[64 * 168];

  const int tid  = threadIdx.x;
  const int lane = tid & 63;
  const int w    = tid >> 6;
  const int quad = lane >> 4;
  const int l16  = lane & 15;
  const int q0   = blockIdx.x * 64;
  const int h    = blockIdx.y;
  const int b    = blockIdx.z;
  const int kbase = q0 - WINW;

  const int r_ = tid >> 2;
  const int c8 = (tid & 3) * 8;

  {
    const __hip_bfloat16* src = qkv + ((size_t)(b * SS + q0 + r_)) * (3 * DD) + h * DHH;
    load16_lds(src + c8,      &QsA[r_ * 32 + c8]);
    load16_lds(src + 32 + c8, &QsB[r_ * 32 + c8]);
  }

  short8 qf0, qf1;
  float m_run[4] = {-1e30f, -1e30f, -1e30f, -1e30f};
  float l_run[4] = {0.f, 0.f, 0.f, 0.f};
  floatx4 ob[4] = {};

  for (int c = 0; c < 2; ++c) {
    const int ck0 = kbase + c * 160;
    __syncthreads();
#pragma unroll
    for (int it = 0; it < 3; ++it) {
      const int r = it * 64 + r_;
      if (r < 160) {
        int key = ck0 + r; key = key < 0 ? 0 : (key > SS - 1 ? SS - 1 : key);
        const __hip_bfloat16* src = qkv + ((size_t)(b * SS + key)) * (3 * DD) + DD + h * DHH;
        load16_lds(src + c8,      &KsA[r * 32 + c8]);
        load16_lds(src + 32 + c8, &KsB[r * 32 + c8]);
      }
    }
    {
      const int k4 = (tid >> 3) * 4;
      const int d8 = (tid & 7) * 8;
#pragma unroll
      for (int it = 0; it < 2; ++it) {
        const int rr = it * 128 + k4;
        if (rr < 160) {
          short8 v[4];
#pragma unroll
          for (int u = 0; u < 4; ++u) {
            int key = ck0 + rr + u; key = key < 0 ? 0 : (key > SS - 1 ? SS - 1 : key);
            v[u] = *(const short8*)(qkv + ((size_t)(b * SS + key)) * (3 * DD) + 2 * DD + h * DHH + d8);
          }
#pragma unroll
          for (int j = 0; j < 8; ++j) {
            short4v pk; pk[0] = v[0][j]; pk[1] = v[1][j]; pk[2] = v[2][j]; pk[3] = v[3][j];
            *(short4v*)&Vt[(d8 + j) * 168 + rr] = pk;
          }
        }
      }
    }
    __syncthreads();

    if (c == 0) {
      qf0 = *(const short8*)&QsA[(w * 16 + l16) * 32 + quad * 8];
      qf1 = *(const short8*)&QsB[(w * 16 + l16) * 32 + quad * 8];
    }

    floatx4 sc[10];
#pragma unroll
    for (int kt = 0; kt < 10; ++kt) {
      const short8 bk0 = *(const short8*)&KsA[(kt * 16 + l16) * 32 + quad * 8];
      const short8 bk1 = *(const short8*)&KsB[(kt * 16 + l16) * 32 + quad * 8];
      floatx4 a = {};
      a = __builtin_amdgcn_mfma_f32_16x16x32_bf16(qf0, bk0, a, 0, 0, 0);
      a = __builtin_amdgcn_mfma_f32_16x16x32_bf16(qf1, bk1, a, 0, 0, 0);
      sc[kt] = a;
    }

    float cm[4] = {-1e30f, -1e30f, -1e30f, -1e30f};
#pragma unroll
    for (int kt = 0; kt < 10; ++kt) {
      const int key = ck0 + kt * 16 + l16;
#pragma unroll
      for (int r = 0; r < 4; ++r) {
        const int qq = q0 + w * 16 + quad * 4 + r;
        const int dqk = qq - key;
        const bool ok = (key >= 0) & (key < SS) & (dqk <= WINW) & (dqk >= -WINW);
        const float s = ok ? sc[kt][r] * 0.125f : -1e30f;
        sc[kt][r] = s;
        cm[r] = fmaxf(cm[r], s);
      }
    }
#pragma unroll
    for (int off = 1; off < 16; off <<= 1)
#pragma unroll
      for (int r = 0; r < 4; ++r) cm[r] = fmaxf(cm[r], __shfl_xor(cm[r], off, 64));

    float alpha[4], csum[4] = {0.f, 0.f, 0.f, 0.f};
#pragma unroll
    for (int r = 0; r < 4; ++r) {
      const float mn = fmaxf(m_run[r], cm[r]);
      alpha[r] = __expf(m_run[r] - mn);
      m_run[r] = mn;
    }

    __hip_bfloat16* Pw = &Ps[w * 16 * 168];
#pragma unroll
    for (int kt = 0; kt < 10; ++kt) {
#pragma unroll
      for (int r = 0; r < 4; ++r) {
        const float p = __expf(sc[kt][r] - m_run[r]);
        csum[r] += p;
        Pw[(quad * 4 + r) * 168 + kt * 16 + l16] = __float2bfloat16(p);
      }
    }
#pragma unroll
    for (int off = 1; off < 16; off <<= 1)
#pragma unroll
      for (int r = 0; r < 4; ++r) csum[r] += __shfl_xor(csum[r], off, 64);
#pragma unroll
    for (int r = 0; r < 4; ++r) l_run[r] = l_run[r] * alpha[r] + csum[r];
#pragma unroll
    for (int t = 0; t < 4; ++t)
#pragma unroll
      for (int r = 0; r < 4; ++r) ob[t][r] *= alpha[r];

#pragma unroll
    for (int kt = 0; kt < 5; ++kt) {
      const short8 pf = *(const short8*)&Pw[l16 * 168 + kt * 32 + quad * 8];
#pragma unroll
      for (int t = 0; t < 4; ++t) {
        const short8 vf = *(const short8*)&Vt[(t * 16 + l16) * 168 + kt * 32 + quad * 8];
        ob[t] = __builtin_amdgcn_mfma_f32_16x16x32_bf16(pf, vf, ob[t], 0, 0, 0);
      }
    }
  }

  float inv[4];
#pragma unroll
  for (int r = 0; r < 4; ++r) inv[r] = 1.f / l_run[r];
  const int qq0 = q0 + w * 16 + quad * 4;
#pragma unroll
  for (int t = 0; t < 4; ++t)
#pragma unroll
    for (int r = 0; r < 4; ++r)
      attn[((size_t)(b * SS + qq0 + r)) * DD + h * DHH + t * 16 + l16] =
          __float2bfloat16(ob[t][r] * inv[r]);
}

// ---------------------------------------------------------------------------
// Fused double LayerNorm: out = LN2( LN1(x + attn_out) + x_wave ).
// ---------------------------------------------------------------------------
__global__ __launch_bounds__(256) void ln_fused(
    const float* __restrict__ x, const __hip_bfloat16* __restrict__ attn_out,
    const float* __restrict__ g1, const float* __restrict__ b1,
    const __hip_bfloat16* __restrict__ xwave,
    const float* __restrict__ g2, const float* __restrict__ b2,
    float* __restrict__ out) {
  const int row = blockIdx.x;
  const int tid = threadIdx.x;
  const int lane = tid & 63;
  const int wave = tid >> 6;
  __shared__ float red[8];

  const float4 xv = *(const float4*)(x + (size_t)row * DD + tid * 4);
  const short4v av = *(const short4v*)(attn_out + (size_t)row * DD + tid * 4);
  float v[4] = {xv.x + bf2f(av[0]), xv.y + bf2f(av[1]),
                xv.z + bf2f(av[2]), xv.w + bf2f(av[3])};

  float s = v[0] + v[1] + v[2] + v[3];
  float s2 = v[0] * v[0] + v[1] * v[1] + v[2] * v[2] + v[3] * v[3];
#pragma unroll
  for (int off = 32; off; off >>= 1) {
    s += __shfl_xor(s, off, 64);
    s2 += __shfl_xor(s2, off, 64);
  }
  if (lane == 0) { red[wave] = s; red[4 + wave] = s2; }
  __syncthreads();
  s = red[0] + red[1] + red[2] + red[3];
  s2 = red[4] + red[5] + red[6] + red[7];
  float mu = s * (1.f / DD);
  float var = s2 * (1.f / DD) - mu * mu;
  float r = rsqrtf(var + 1e-5f);

  const float4 g1v = *(const float4*)(g1 + tid * 4);
  const float4 b1v = *(const float4*)(b1 + tid * 4);
  const short4v wv = *(const short4v*)(xwave + (size_t)row * DD + tid * 4);
  float a[4];
  a[0] = (v[0] - mu) * r * g1v.x + b1v.x + bf2f(wv[0]);
  a[1] = (v[1] - mu) * r * g1v.y + b1v.y + bf2f(wv[1]);
  a[2] = (v[2] - mu) * r * g1v.z + b1v.z + bf2f(wv[2]);
  a[3] = (v[3] - mu) * r * g1v.w + b1v.w + bf2f(wv[3]);

  s = a[0] + a[1] + a[2] + a[3];
  s2 = a[0] * a[0] + a[1] * a[1] + a[2] * a[2] + a[3] * a[3];
#pragma unroll
  for (int off = 32; off; off >>= 1) {
    s += __shfl_xor(s, off, 64);
    s2 += __shfl_xor(s2, off, 64);
  }
  __syncthreads();
  if (lane == 0) { red[wave] = s; red[4 + wave] = s2; }
  __syncthreads();
  s = red[0] + red[1] + red[2] + red[3];
  s2 = red[4] + red[5] + red[6] + red[7];
  mu = s * (1.f / DD);
  var = s2 * (1.f / DD) - mu * mu;
  r = rsqrtf(var + 1e-5f);

  const float4 g2v = *(const float4*)(g2 + tid * 4);
  const float4 b2v = *(const float4*)(b2 + tid * 4);
  float4 o;
  o.x = (a[0] - mu) * r * g2v.x + b2v.x;
  o.y = (a[1] - mu) * r * g2v.y + b2v.y;
  o.z = (a[2] - mu) * r * g2v.z + b2v.z;
  o.w = (a[3] - mu) * r * g2v.w + b2v.w;
  *(float4*)(out + (size_t)row * DD + tid * 4) = o;
}

// ---------------------------------------------------------------------------
extern "C" void kernel_launch(void* const* d_in, const int* in_sizes, int n_in,
                              void* d_out, int out_size, void* d_ws, size_t ws_size,
                              hipStream_t stream) {
  const float* x     = (const float*)d_in[0];
  const float* in_w  = (const float*)d_in[1];
  const float* in_b  = (const float*)d_in[2];
  const float* out_w = (const float*)d_in[3];
  const float* out_b = (const float*)d_in[4];
  const float* ln1_g = (const float*)d_in[5];
  const float* ln1_b = (const float*)d_in[6];
  const float* wr    = (const float*)d_in[7];
  const float* wi    = (const float*)d_in[8];
  const float* ln2_g = (const float*)d_in[9];
  const float* ln2_b = (const float*)d_in[10];
  float* out = (float*)d_out;

  char* ws = (char*)d_ws;
  // Workspace (<= 64 MB), phase-reused (same as R7):
  //  [0,16)       xT fp32 (live through gemm2_tback; spec FFT in place)
  //  [16,24)      x_bf16 (dead after gemm1) -> attn_bf16
  //  [24,30)      w_in_bf ; [30,32) w_out_bf
  //  [32,56)      qkv_bf16 (dead after attn) -> attn_out_bf + x_wave_bf
  //  [56,60.2)    wrT bf16 ; [58,62.2) wiT bf16
  float* xT                = (float*)(ws);
  __hip_bfloat16* x_bf     = (__hip_bfloat16*)(ws + 16777216);
  __hip_bfloat16* attn_bf  = (__hip_bfloat16*)(ws + 16777216);
  __hip_bfloat16* w_in_bf  = (__hip_bfloat16*)(ws + 25165824);
  __hip_bfloat16* w_out_bf = (__hip_bfloat16*)(ws + 31457280);
  __hip_bfloat16* qkv_bf   = (__hip_bfloat16*)(ws + 33554432);
  __hip_bfloat16* attn_out_bf = (__hip_bfloat16*)(ws + 33554432);
  __hip_bfloat16* x_wave_bf   = (__hip_bfloat16*)(ws + 44040192);
  __hip_bfloat16* wrT      = (__hip_bfloat16*)(ws + 58720256);
  __hip_bfloat16* wiT      = (__hip_bfloat16*)(ws + 60819456);

  // 1. fused preprocessing: x transpose+cast | weight casts | wr/wi transposes
  prep_fused<<<2592, 256, 0, stream>>>(x, xT, x_bf, in_w, out_w,
                                       w_in_bf, w_out_bf, wr, wi, wrT, wiT);

  // 2. fused: QKV GEMM (768 blocks) + spectral FFT (1024 blocks)
  gemm1_spec<<<1792, 256, 32768, stream>>>(x_bf, w_in_bf, in_b, qkv_bf,
                                           xT, wrT, wiT);

  // 3. flash MFMA sliding-window attention -> attn_bf
  attn_mfma<<<dim3(SS / 64, HH, BB), 256, 0, stream>>>(qkv_bf, attn_bf);

  // 4. fused: out-proj GEMM (256 blocks) + transpose-back (1024 blocks)
  gemm2_tback<<<1280, 256, 32768, stream>>>(attn_bf, w_out_bf, out_b,
                                            attn_out_bf, xT, x_wave_bf);

  // 5. fused LN1+LN2 -> out
  ln_fused<<<MROWS, 256, 0, stream>>>(x, attn_out_bf, ln1_g, ln1_b,
                                      x_wave_bf, ln2_g, ln2_b, out);
}

// Round 9
// 228.689 us; speedup vs baseline: 6.8606x; 1.0080x over previous
//
#include <hip/hip_runtime.h>
#include <hip/hip_bf16.h>
#include <math.h>

// Problem constants (B,S,D,H,WIN) = (2,2048,1024,16,128), DH=64
#define BB    2
#define SS    2048
#define DD    1024
#define HH    16
#define DHH   64
#define WINW  128
#define MROWS (BB * SS)          // 4096

typedef __attribute__((ext_vector_type(8))) short short8;
typedef __attribute__((ext_vector_type(4))) short short4v;
typedef __attribute__((ext_vector_type(4))) float floatx4;

__device__ __forceinline__ float bf2f(short s) {
  union { unsigned u; float f; } t;
  t.u = ((unsigned)(unsigned short)s) << 16;
  return t.f;
}

// ---------------------------------------------------------------------------
__device__ inline void load16_lds(const __hip_bfloat16* g, __hip_bfloat16* l) {
  __builtin_amdgcn_global_load_lds(
      (const __attribute__((address_space(1))) uint32_t*)g,
      (__attribute__((address_space(3))) uint32_t*)l, 16, 0, 0);
}

// ---------------------------------------------------------------------------
// Fused preprocessing (one launch, 2592 blocks) — unchanged from R8.
// ---------------------------------------------------------------------------
__global__ __launch_bounds__(256) void prep_fused(
    const float* __restrict__ x, float* __restrict__ xT,
    __hip_bfloat16* __restrict__ x_bf,
    const float* __restrict__ w_in, const float* __restrict__ w_out,
    __hip_bfloat16* __restrict__ w_in_bf, __hip_bfloat16* __restrict__ w_out_bf,
    const float* __restrict__ wr, const float* __restrict__ wi,
    __hip_bfloat16* __restrict__ wrT, __hip_bfloat16* __restrict__ wiT) {
  __shared__ float tile[64][65];
  const int id = blockIdx.x;
  const int tx = threadIdx.x & 63;
  const int ty = threadIdx.x >> 6;

  if (id < 1024) {
    const int bz = id >> 9;
    const int rem = id & 511;
    const int c0 = (rem & 15) * 64;   // D
    const int r0 = (rem >> 4) * 64;   // S
    const size_t base = (size_t)bz * SS * DD;
#pragma unroll
    for (int i = 0; i < 16; ++i) {
      const int r = ty * 16 + i;
      const float v = x[base + (size_t)(r0 + r) * DD + c0 + tx];
      tile[r][tx] = v;
      x_bf[base + (size_t)(r0 + r) * DD + c0 + tx] = __float2bfloat16(v);
    }
    __syncthreads();
#pragma unroll
    for (int i = 0; i < 16; ++i) {
      const int c = ty * 16 + i;
      xT[base + (size_t)(c0 + c) * SS + r0 + tx] = tile[tx][c];
    }
  } else if (id < 2048) {
    const int blk = id - 1024;
    const float* src; __hip_bfloat16* dst; size_t off;
    if (blk < 768) { src = w_in; dst = w_in_bf; off = (size_t)blk * 4096; }
    else { src = w_out; dst = w_out_bf; off = (size_t)(blk - 768) * 4096; }
#pragma unroll
    for (int c = 0; c < 4; ++c) {
      const size_t j = off + c * 1024 + threadIdx.x * 4;
      const float4 v = *(const float4*)(src + j);
      dst[j + 0] = __float2bfloat16(v.x);
      dst[j + 1] = __float2bfloat16(v.y);
      dst[j + 2] = __float2bfloat16(v.z);
      dst[j + 3] = __float2bfloat16(v.w);
    }
  } else {
    const int id2 = id - 2048;               // 0..543
    const int half = id2 >= 272;
    const int rem = id2 - (half ? 272 : 0);
    const float* src = half ? wi : wr;
    __hip_bfloat16* dst = half ? wiT : wrT;
    const int R = 1025, C = DD;
    const int c0 = (rem & 15) * 64;
    const int r0 = (rem >> 4) * 64;
#pragma unroll
    for (int i = 0; i < 16; ++i) {
      const int r = ty * 16 + i;
      if (r0 + r < R) tile[r][tx] = src[(size_t)(r0 + r) * C + c0 + tx];
    }
    __syncthreads();
#pragma unroll
    for (int i = 0; i < 16; ++i) {
      const int c = ty * 16 + i;
      if (r0 + tx < R) dst[(size_t)(c0 + c) * R + r0 + tx] = __float2bfloat16(tile[tx][c]);
    }
  }
}

// ---------------------------------------------------------------------------
// bf16 MFMA GEMM tile body (BK=64, unchanged from R8). sm: 32 KB.
// ---------------------------------------------------------------------------
template <bool BF16OUT>
__device__ __forceinline__ void gemm_tile128(
    const __hip_bfloat16* __restrict__ A, const __hip_bfloat16* __restrict__ B,
    const float* __restrict__ bias, void* __restrict__ Cp,
    int N, int K, int row0, int col0, __hip_bfloat16* sm) {
  __hip_bfloat16* As0 = sm;
  __hip_bfloat16* As1 = sm + 4096;
  __hip_bfloat16* Bs0 = sm + 8192;
  __hip_bfloat16* Bs1 = sm + 12288;
  const int tid  = threadIdx.x;
  const int lane = tid & 63;
  const int wave = tid >> 6;
  const int wrow = (wave >> 1) * 64;
  const int wcol = (wave & 1) * 64;
  const int srow = tid >> 2;
  const int skk  = (tid & 3) * 8;
  const int quad = lane >> 4;
  const int l16  = lane & 15;
  floatx4 acc[4][4] = {};
  for (int k0 = 0; k0 < K; k0 += 64) {
    __syncthreads();
    load16_lds(A + (size_t)(row0 + srow) * K + k0 + skk,           &As0[tid * 8]);
    load16_lds(A + (size_t)(row0 + 64 + srow) * K + k0 + skk,      &As0[2048 + tid * 8]);
    load16_lds(A + (size_t)(row0 + srow) * K + k0 + 32 + skk,      &As1[tid * 8]);
    load16_lds(A + (size_t)(row0 + 64 + srow) * K + k0 + 32 + skk, &As1[2048 + tid * 8]);
    load16_lds(B + (size_t)(col0 + srow) * K + k0 + skk,           &Bs0[tid * 8]);
    load16_lds(B + (size_t)(col0 + 64 + srow) * K + k0 + skk,      &Bs0[2048 + tid * 8]);
    load16_lds(B + (size_t)(col0 + srow) * K + k0 + 32 + skk,      &Bs1[tid * 8]);
    load16_lds(B + (size_t)(col0 + 64 + srow) * K + k0 + 32 + skk, &Bs1[2048 + tid * 8]);
    __syncthreads();
    {
      short8 af[4], bf[4];
#pragma unroll
      for (int i = 0; i < 4; ++i)
        af[i] = *(const short8*)&As0[(wrow + i * 16 + l16) * 32 + quad * 8];
#pragma unroll
      for (int j = 0; j < 4; ++j)
        bf[j] = *(const short8*)&Bs0[(wcol + j * 16 + l16) * 32 + quad * 8];
#pragma unroll
      for (int i = 0; i < 4; ++i)
#pragma unroll
        for (int j = 0; j < 4; ++j)
          acc[i][j] = __builtin_amdgcn_mfma_f32_16x16x32_bf16(af[i], bf[j], acc[i][j], 0, 0, 0);
    }
    {
      short8 af[4], bf[4];
#pragma unroll
      for (int i = 0; i < 4; ++i)
        af[i] = *(const short8*)&As1[(wrow + i * 16 + l16) * 32 + quad * 8];
#pragma unroll
      for (int j = 0; j < 4; ++j)
        bf[j] = *(const short8*)&Bs1[(wcol + j * 16 + l16) * 32 + quad * 8];
#pragma unroll
      for (int i = 0; i < 4; ++i)
#pragma unroll
        for (int j = 0; j < 4; ++j)
          acc[i][j] = __builtin_amdgcn_mfma_f32_16x16x32_bf16(af[i], bf[j], acc[i][j], 0, 0, 0);
    }
  }
#pragma unroll
  for (int i = 0; i < 4; ++i) {
#pragma unroll
    for (int j = 0; j < 4; ++j) {
      const int col = col0 + wcol + j * 16 + l16;
      const float bs = bias[col];
#pragma unroll
      for (int r = 0; r < 4; ++r) {
        const int row = row0 + wrow + i * 16 + quad * 4 + r;
        if (BF16OUT)
          ((__hip_bfloat16*)Cp)[(size_t)row * N + col] = __float2bfloat16(acc[i][j][r] + bs);
        else
          ((float*)Cp)[(size_t)row * N + col] = acc[i][j][r] + bs;
      }
    }
  }
}

// ---------------------------------------------------------------------------
// Spectral FFT body v2: interleaved complex (float2, b64 LDS ops, pad/32)
// + conflict-free LDS twiddle tables (dense base for stages 11/10,
// consecutive-p level tables twl[half-1+p] for stages 1..9).
// Radix-2 index math identical to the verified R5-R8 version.
// LDS layout in sm (float2*): cx[2112] | twb[1024] | twl[511] = 29176 B.
// ---------------------------------------------------------------------------
#define PAD2(a) ((a) + ((a) >> 5))

__device__ __forceinline__ void spec_body(
    int sid, float* __restrict__ xT,
    const __hip_bfloat16* __restrict__ wrT, const __hip_bfloat16* __restrict__ wiT,
    float* smf) {
  float2* cx  = (float2*)smf;
  float2* twb = cx + 2112;
  float2* twl = twb + 1024;
  const int tid = threadIdx.x;
  const int dpair = sid & 511;
  const int b = sid >> 9;
  const int d0 = dpair * 2, d1 = d0 + 1;
  float* col0 = xT + ((size_t)b * DD + d0) * SS;
  float* col1 = xT + ((size_t)b * DD + d1) * SS;

  // load two real columns -> packed complex (s4%32 <= 28: no pad straddle)
  for (int s4 = tid * 4; s4 < SS; s4 += 1024) {
    const float4 a = *(const float4*)(col0 + s4);
    const float4 c = *(const float4*)(col1 + s4);
    const int p = PAD2(s4);
    cx[p + 0] = float2{a.x, c.x};
    cx[p + 1] = float2{a.y, c.y};
    cx[p + 2] = float2{a.z, c.z};
    cx[p + 3] = float2{a.w, c.w};
  }
  // twiddle tables: base (dense, stages 11/10) + levels (stages 1..9)
  for (int j = tid; j < 1024; j += 256) {
    float sn, cs;
    __sincosf(-6.283185307179586f * (float)j * (1.0f / 2048.0f), &sn, &cs);
    twb[j] = float2{cs, sn};
  }
#pragma unroll
  for (int s = 1; s <= 9; ++s) {
    const int sz = 1 << (s - 1);
    const float ang = -6.283185307179586f / (float)(1 << s);
    for (int p = tid; p < sz; p += 256) {
      float sn, cs;
      __sincosf(ang * (float)p, &sn, &cs);
      twl[sz - 1 + p] = float2{cs, sn};
    }
  }

  // forward DIF (natural -> bit-reversed)
  for (int stage = 11; stage >= 1; --stage) {
    __syncthreads();
    const int half = 1 << (stage - 1);
    const float2* twp = (stage >= 10) ? twb : (twl + (half - 1));
    const int tmul = (stage == 10) ? 2 : 1;
#pragma unroll 2
    for (int t = tid; t < SS / 2; t += 256) {
      const int gI = t >> (stage - 1);
      const int p = t & (half - 1);
      const int i = (gI << stage) + p;
      const int j = i + half;
      const float2 w = twp[p * tmul];
      const int ii = PAD2(i), jj = PAD2(j);
      const float2 a = cx[ii];
      const float2 bv = cx[jj];
      cx[ii] = float2{a.x + bv.x, a.y + bv.y};
      const float dr = a.x - bv.x, di = a.y - bv.y;
      cx[jj] = float2{dr * w.x - di * w.y, dr * w.y + di * w.x};
    }
  }
  __syncthreads();

  // packed Hermitian filter (bit-reversed positions), 1/S folded in
  const __hip_bfloat16* w0r = wrT + (size_t)d0 * 1025;
  const __hip_bfloat16* w0i = wiT + (size_t)d0 * 1025;
  const __hip_bfloat16* w1r = wrT + (size_t)d1 * 1025;
  const __hip_bfloat16* w1i = wiT + (size_t)d1 * 1025;
  const float sc = 1.0f / (float)SS;
  for (int k = tid; k < 1024; k += 256) {
    if (k == 0) {
      const float2 z0 = cx[0];                // DC, forced real
      cx[0] = float2{z0.x * __bfloat162float(w0r[0]) * sc,
                     z0.y * __bfloat162float(w1r[0]) * sc};
      const float2 zn = cx[1];                // Nyquist (bitrev pos 1), real
      cx[1] = float2{zn.x * __bfloat162float(w0r[1024]) * sc,
                     zn.y * __bfloat162float(w1r[1024]) * sc};
    } else {
      const int p1 = PAD2(__brev((unsigned)k) >> 21);
      const int p2 = PAD2(__brev((unsigned)(SS - k)) >> 21);
      const float2 A = cx[p1];
      const float2 Bv = cx[p2];
      const float z0r = 0.5f * (A.x + Bv.x), z0i = 0.5f * (A.y - Bv.y);
      const float z1r = 0.5f * (A.y + Bv.y), z1i = -0.5f * (A.x - Bv.x);
      const float a0 = __bfloat162float(w0r[k]) * sc, b0 = __bfloat162float(w0i[k]) * sc;
      const float a1 = __bfloat162float(w1r[k]) * sc, b1 = __bfloat162float(w1i[k]) * sc;
      const float y0r = z0r * a0 - z0i * b0, y0i = z0r * b0 + z0i * a0;
      const float y1r = z1r * a1 - z1i * b1, y1i = z1r * b1 + z1i * a1;
      cx[p1] = float2{y0r - y1i, y0i + y1r};
      cx[p2] = float2{y0r + y1i, y1r - y0i};
    }
  }

  // inverse DIT (bit-reversed -> natural, conjugate twiddles)
  for (int stage = 1; stage <= 11; ++stage) {
    __syncthreads();
    const int half = 1 << (stage - 1);
    const float2* twp = (stage >= 10) ? twb : (twl + (half - 1));
    const int tmul = (stage == 10) ? 2 : 1;
#pragma unroll 2
    for (int t = tid; t < SS / 2; t += 256) {
      const int gI = t >> (stage - 1);
      const int p = t & (half - 1);
      const int i = (gI << stage) + p;
      const int j = i + half;
      const float2 w = twp[p * tmul];
      const int ii = PAD2(i), jj = PAD2(j);
      const float2 bv = cx[jj];
      const float tr = bv.x * w.x + bv.y * w.y;   // b * conj(w)
      const float ti = bv.y * w.x - bv.x * w.y;
      const float2 a = cx[ii];
      cx[ii] = float2{a.x + tr, a.y + ti};
      cx[jj] = float2{a.x - tr, a.y - ti};
    }
  }
  __syncthreads();

  for (int s4 = tid * 4; s4 < SS; s4 += 1024) {
    const int p = PAD2(s4);
    float4 a, c;
    const float2 v0 = cx[p + 0], v1 = cx[p + 1], v2 = cx[p + 2], v3 = cx[p + 3];
    a.x = v0.x; a.y = v1.x; a.z = v2.x; a.w = v3.x;
    c.x = v0.y; c.y = v1.y; c.z = v2.y; c.w = v3.y;
    *(float4*)(col0 + s4) = a;
    *(float4*)(col1 + s4) = c;
  }
}

// ---------------------------------------------------------------------------
// Fused launch 1: blocks [0,768) = QKV GEMM; [768,1792) = spectral FFT.
// Dynamic LDS 32768 B.
// ---------------------------------------------------------------------------
__global__ __launch_bounds__(256) void gemm1_spec(
    const __hip_bfloat16* __restrict__ x_bf, const __hip_bfloat16* __restrict__ w_in_bf,
    const float* __restrict__ in_b, __hip_bfloat16* __restrict__ qkv_bf,
    float* __restrict__ xT, const __hip_bfloat16* __restrict__ wrT,
    const __hip_bfloat16* __restrict__ wiT) {
  extern __shared__ __align__(16) char smem[];
  if (blockIdx.x < 768) {
    const int id = blockIdx.x;
    const int col0 = (id % 24) * 128;
    const int row0 = (id / 24) * 128;
    gemm_tile128<true>(x_bf, w_in_bf, in_b, qkv_bf, 3 * DD, DD, row0, col0,
                       (__hip_bfloat16*)smem);
  } else {
    spec_body(blockIdx.x - 768, xT, wrT, wiT, (float*)smem);
  }
}

// ---------------------------------------------------------------------------
// Fused launch 2: blocks [0,256) = out-proj GEMM; [256,1280) = transpose-back.
// Dynamic LDS 32768 B.
// ---------------------------------------------------------------------------
__global__ __launch_bounds__(256) void gemm2_tback(
    const __hip_bfloat16* __restrict__ attn_bf, const __hip_bfloat16* __restrict__ w_out_bf,
    const float* __restrict__ out_b, __hip_bfloat16* __restrict__ attn_out_bf,
    const float* __restrict__ xT, __hip_bfloat16* __restrict__ x_wave_bf) {
  extern __shared__ __align__(16) char smem[];
  if (blockIdx.x < 256) {
    const int id = blockIdx.x;
    const int col0 = (id % 8) * 128;
    const int row0 = (id / 8) * 128;
    gemm_tile128<true>(attn_bf, w_out_bf, out_b, attn_out_bf, DD, DD, row0, col0,
                       (__hip_bfloat16*)smem);
  } else {
    float (*tile)[65] = (float(*)[65])smem;
    const int id = blockIdx.x - 256;          // 0..1023
    const int bz = id >> 9;
    const int rem = id & 511;
    const int s0 = (rem >> 4) * 64;
    const int d0 = (rem & 15) * 64;
    const int tx = threadIdx.x & 63;
    const int ty = threadIdx.x >> 6;
    const float* src = xT + (size_t)bz * DD * SS;
    __hip_bfloat16* dst = x_wave_bf + (size_t)bz * SS * DD;
#pragma unroll
    for (int i = 0; i < 16; ++i) {
      const int r = ty * 16 + i;
      tile[r][tx] = src[(size_t)(d0 + r) * SS + s0 + tx];
    }
    __syncthreads();
#pragma unroll
    for (int i = 0; i < 16; ++i) {
      const int c = ty * 16 + i;
      dst[(size_t)(s0 + c) * DD + d0 + tx] = __float2bfloat16(tile[tx][c]);
    }
  }
}

// ---------------------------------------------------------------------------
// Flash-style MFMA sliding-window attention (unchanged).
// ---------------------------------------------------------------------------
__global__ __launch_bounds__(256, 2) void attn_mfma(
    const __hip_bfloat16* __restrict__ qkv, __hip_bfloat16* __restrict__ attn) {
  __shared__ __attribute__((aligned(16))) __hip_bfloat16 QsA[64 * 32];
  __shared__ __attribute__((aligned(16))) __hip_bfloat16 QsB[64 * 32];
  __shared__ __attribute__((aligned(16))) __hip_bfloat16 KsA[160 * 32];
  __shared__ __attribute__((aligned(16))) __hip_bfloat16 KsB[160 * 32];
  __shared__ __attribute__((aligned(16))) __hip_bfloat16 Vt[64 * 168];
  __shared__ __attribute__((aligned(16))) __hip_bfloat16 Ps[64 * 168];

  const int tid  = threadIdx.x;
  const int lane = tid & 63;
  const int w    = tid >> 6;
  const int quad = lane >> 4;
  const int l16  = lane & 15;
  const int q0   = blockIdx.x * 64;
  const int h    = blockIdx.y;
  const int b    = blockIdx.z;
  const int kbase = q0 - WINW;

  const int r_ = tid >> 2;
  const int c8 = (tid & 3) * 8;

  {
    const __hip_bfloat16* src = qkv + ((size_t)(b * SS + q0 + r_)) * (3 * DD) + h * DHH;
    load16_lds(src + c8,      &QsA[r_ * 32 + c8]);
    load16_lds(src + 32 + c8, &QsB[r_ * 32 + c8]);
  }

  short8 qf0, qf1;
  float m_run[4] = {-1e30f, -1e30f, -1e30f, -1e30f};
  float l_run[4] = {0.f, 0.f, 0.f, 0.f};
  floatx4 ob[4] = {};

  for (int c = 0; c < 2; ++c) {
    const int ck0 = kbase + c * 160;
    __syncthreads();
#pragma unroll
    for (int it = 0; it < 3; ++it) {
      const int r = it * 64 + r_;
      if (r < 160) {
        int key = ck0 + r; key = key < 0 ? 0 : (key > SS - 1 ? SS - 1 : key);
        const __hip_bfloat16* src = qkv + ((size_t)(b * SS + key)) * (3 * DD) + DD + h * DHH;
        load16_lds(src + c8,      &KsA[r * 32 + c8]);
        load16_lds(src + 32 + c8, &KsB[r * 32 + c8]);
      }
    }
    {
      const int k4 = (tid >> 3) * 4;
      const int d8 = (tid & 7) * 8;
#pragma unroll
      for (int it = 0; it < 2; ++it) {
        const int rr = it * 128 + k4;
        if (rr < 160) {
          short8 v[4];
#pragma unroll
          for (int u = 0; u < 4; ++u) {
            int key = ck0 + rr + u; key = key < 0 ? 0 : (key > SS - 1 ? SS - 1 : key);
            v[u] = *(const short8*)(qkv + ((size_t)(b * SS + key)) * (3 * DD) + 2 * DD + h * DHH + d8);
          }
#pragma unroll
          for (int j = 0; j < 8; ++j) {
            short4v pk; pk[0] = v[0][j]; pk[1] = v[1][j]; pk[2] = v[2][j]; pk[3] = v[3][j];
            *(short4v*)&Vt[(d8 + j) * 168 + rr] = pk;
          }
        }
      }
    }
    __syncthreads();

    if (c == 0) {
      qf0 = *(const short8*)&QsA[(w * 16 + l16) * 32 + quad * 8];
      qf1 = *(const short8*)&QsB[(w * 16 + l16) * 32 + quad * 8];
    }

    floatx4 sc[10];
#pragma unroll
    for (int kt = 0; kt < 10; ++kt) {
      const short8 bk0 = *(const short8*)&KsA[(kt * 16 + l16) * 32 + quad * 8];
      const short8 bk1 = *(const short8*)&KsB[(kt * 16 + l16) * 32 + quad * 8];
      floatx4 a = {};
      a = __builtin_amdgcn_mfma_f32_16x16x32_bf16(qf0, bk0, a, 0, 0, 0);
      a = __builtin_amdgcn_mfma_f32_16x16x32_bf16(qf1, bk1, a, 0, 0, 0);
      sc[kt] = a;
    }

    float cm[4] = {-1e30f, -1e30f, -1e30f, -1e30f};
#pragma unroll
    for (int kt = 0; kt < 10; ++kt) {
      const int key = ck0 + kt * 16 + l16;
#pragma unroll
      for (int r = 0; r < 4; ++r) {
        const int qq = q0 + w * 16 + quad * 4 + r;
        const int dqk = qq - key;
        const bool ok = (key >= 0) & (key < SS) & (dqk <= WINW) & (dqk >= -WINW);
        const float s = ok ? sc[kt][r] * 0.125f : -1e30f;
        sc[kt][r] = s;
        cm[r] = fmaxf(cm[r], s);
      }
    }
#pragma unroll
    for (int off = 1; off < 16; off <<= 1)
#pragma unroll
      for (int r = 0; r < 4; ++r) cm[r] = fmaxf(cm[r], __shfl_xor(cm[r], off, 64));

    float alpha[4], csum[4] = {0.f, 0.f, 0.f, 0.f};
#pragma unroll
    for (int r = 0; r < 4; ++r) {
      const float mn = fmaxf(m_run[r], cm[r]);
      alpha[r] = __expf(m_run[r] - mn);
      m_run[r] = mn;
    }

    __hip_bfloat16* Pw = &Ps[w * 16 * 168];
#pragma unroll
    for (int kt = 0; kt < 10; ++kt) {
#pragma unroll
      for (int r = 0; r < 4; ++r) {
        const float p = __expf(sc[kt][r] - m_run[r]);
        csum[r] += p;
        Pw[(quad * 4 + r) * 168 + kt * 16 + l16] = __float2bfloat16(p);
      }
    }
#pragma unroll
    for (int off = 1; off < 16; off <<= 1)
#pragma unroll
      for (int r = 0; r < 4; ++r) csum[r] += __shfl_xor(csum[r], off, 64);
#pragma unroll
    for (int r = 0; r < 4; ++r) l_run[r] = l_run[r] * alpha[r] + csum[r];
#pragma unroll
    for (int t = 0; t < 4; ++t)
#pragma unroll
      for (int r = 0; r < 4; ++r) ob[t][r] *= alpha[r];

#pragma unroll
    for (int kt = 0; kt < 5; ++kt) {
      const short8 pf = *(const short8*)&Pw[l16 * 168 + kt * 32 + quad * 8];
#pragma unroll
      for (int t = 0; t < 4; ++t) {
        const short8 vf = *(const short8*)&Vt[(t * 16 + l16) * 168 + kt * 32 + quad * 8];
        ob[t] = __builtin_amdgcn_mfma_f32_16x16x32_bf16(pf, vf, ob[t], 0, 0, 0);
      }
    }
  }

  float inv[4];
#pragma unroll
  for (int r = 0; r < 4; ++r) inv[r] = 1.f / l_run[r];
  const int qq0 = q0 + w * 16 + quad * 4;
#pragma unroll
  for (int t = 0; t < 4; ++t)
#pragma unroll
    for (int r = 0; r < 4; ++r)
      attn[((size_t)(b * SS + qq0 + r)) * DD + h * DHH + t * 16 + l16] =
          __float2bfloat16(ob[t][r] * inv[r]);
}

// ---------------------------------------------------------------------------
// Fused double LayerNorm: out = LN2( LN1(x + attn_out) + x_wave ).
// ---------------------------------------------------------------------------
__global__ __launch_bounds__(256) void ln_fused(
    const float* __restrict__ x, const __hip_bfloat16* __restrict__ attn_out,
    const float* __restrict__ g1, const float* __restrict__ b1,
    const __hip_bfloat16* __restrict__ xwave,
    const float* __restrict__ g2, const float* __restrict__ b2,
    float* __restrict__ out) {
  const int row = blockIdx.x;
  const int tid = threadIdx.x;
  const int lane = tid & 63;
  const int wave = tid >> 6;
  __shared__ float red[8];

  const float4 xv = *(const float4*)(x + (size_t)row * DD + tid * 4);
  const short4v av = *(const short4v*)(attn_out + (size_t)row * DD + tid * 4);
  float v[4] = {xv.x + bf2f(av[0]), xv.y + bf2f(av[1]),
                xv.z + bf2f(av[2]), xv.w + bf2f(av[3])};

  float s = v[0] + v[1] + v[2] + v[3];
  float s2 = v[0] * v[0] + v[1] * v[1] + v[2] * v[2] + v[3] * v[3];
#pragma unroll
  for (int off = 32; off; off >>= 1) {
    s += __shfl_xor(s, off, 64);
    s2 += __shfl_xor(s2, off, 64);
  }
  if (lane == 0) { red[wave] = s; red[4 + wave] = s2; }
  __syncthreads();
  s = red[0] + red[1] + red[2] + red[3];
  s2 = red[4] + red[5] + red[6] + red[7];
  float mu = s * (1.f / DD);
  float var = s2 * (1.f / DD) - mu * mu;
  float r = rsqrtf(var + 1e-5f);

  const float4 g1v = *(const float4*)(g1 + tid * 4);
  const float4 b1v = *(const float4*)(b1 + tid * 4);
  const short4v wv = *(const short4v*)(xwave + (size_t)row * DD + tid * 4);
  float a[4];
  a[0] = (v[0] - mu) * r * g1v.x + b1v.x + bf2f(wv[0]);
  a[1] = (v[1] - mu) * r * g1v.y + b1v.y + bf2f(wv[1]);
  a[2] = (v[2] - mu) * r * g1v.z + b1v.z + bf2f(wv[2]);
  a[3] = (v[3] - mu) * r * g1v.w + b1v.w + bf2f(wv[3]);

  s = a[0] + a[1] + a[2] + a[3];
  s2 = a[0] * a[0] + a[1] * a[1] + a[2] * a[2] + a[3] * a[3];
#pragma unroll
  for (int off = 32; off; off >>= 1) {
    s += __shfl_xor(s, off, 64);
    s2 += __shfl_xor(s2, off, 64);
  }
  __syncthreads();
  if (lane == 0) { red[wave] = s; red[4 + wave] = s2; }
  __syncthreads();
  s = red[0] + red[1] + red[2] + red[3];
  s2 = red[4] + red[5] + red[6] + red[7];
  mu = s * (1.f / DD);
  var = s2 * (1.f / DD) - mu * mu;
  r = rsqrtf(var + 1e-5f);

  const float4 g2v = *(const float4*)(g2 + tid * 4);
  const float4 b2v = *(const float4*)(b2 + tid * 4);
  float4 o;
  o.x = (a[0] - mu) * r * g2v.x + b2v.x;
  o.y = (a[1] - mu) * r * g2v.y + b2v.y;
  o.z = (a[2] - mu) * r * g2v.z + b2v.z;
  o.w = (a[3] - mu) * r * g2v.w + b2v.w;
  *(float4*)(out + (size_t)row * DD + tid * 4) = o;
}

// ---------------------------------------------------------------------------
extern "C" void kernel_launch(void* const* d_in, const int* in_sizes, int n_in,
                              void* d_out, int out_size, void* d_ws, size_t ws_size,
                              hipStream_t stream) {
  const float* x     = (const float*)d_in[0];
  const float* in_w  = (const float*)d_in[1];
  const float* in_b  = (const float*)d_in[2];
  const float* out_w = (const float*)d_in[3];
  const float* out_b = (const float*)d_in[4];
  const float* ln1_g = (const float*)d_in[5];
  const float* ln1_b = (const float*)d_in[6];
  const float* wr    = (const float*)d_in[7];
  const float* wi    = (const float*)d_in[8];
  const float* ln2_g = (const float*)d_in[9];
  const float* ln2_b = (const float*)d_in[10];
  float* out = (float*)d_out;

  char* ws = (char*)d_ws;
  float* xT                = (float*)(ws);
  __hip_bfloat16* x_bf     = (__hip_bfloat16*)(ws + 16777216);
  __hip_bfloat16* attn_bf  = (__hip_bfloat16*)(ws + 16777216);
  __hip_bfloat16* w_in_bf  = (__hip_bfloat16*)(ws + 25165824);
  __hip_bfloat16* w_out_bf = (__hip_bfloat16*)(ws + 31457280);
  __hip_bfloat16* qkv_bf   = (__hip_bfloat16*)(ws + 33554432);
  __hip_bfloat16* attn_out_bf = (__hip_bfloat16*)(ws + 33554432);
  __hip_bfloat16* x_wave_bf   = (__hip_bfloat16*)(ws + 44040192);
  __hip_bfloat16* wrT      = (__hip_bfloat16*)(ws + 58720256);
  __hip_bfloat16* wiT      = (__hip_bfloat16*)(ws + 60819456);

  // 1. fused preprocessing
  prep_fused<<<2592, 256, 0, stream>>>(x, xT, x_bf, in_w, out_w,
                                       w_in_bf, w_out_bf, wr, wi, wrT, wiT);

  // 2. fused: QKV GEMM (768 blocks) + spectral FFT (1024 blocks)
  gemm1_spec<<<1792, 256, 32768, stream>>>(x_bf, w_in_bf, in_b, qkv_bf,
                                           xT, wrT, wiT);

  // 3. flash MFMA sliding-window attention
  attn_mfma<<<dim3(SS / 64, HH, BB), 256, 0, stream>>>(qkv_bf, attn_bf);

  // 4. fused: out-proj GEMM (256 blocks) + transpose-back (1024 blocks)
  gemm2_tback<<<1280, 256, 32768, stream>>>(attn_bf, w_out_bf, out_b,
                                            attn_out_bf, xT, x_wave_bf);

  // 5. fused LN1+LN2 -> out
  ln_fused<<<MROWS, 256, 0, stream>>>(x, attn_out_bf, ln1_g, ln1_b,
                                      x_wave_bf, ln2_g, ln2_b, out);
}

// Round 10
// 215.554 us; speedup vs baseline: 7.2787x; 1.0609x over previous
//
#include <hip/hip_runtime.h>
#include <hip/hip_bf16.h>
#include <math.h>

// Problem constants (B,S,D,H,WIN) = (2,2048,1024,16,128), DH=64
#define BB    2
#define SS    2048
#define DD    1024
#define HH    16
#define DHH   64
#define WINW  128
#define MROWS (BB * SS)          // 4096

typedef __attribute__((ext_vector_type(8))) short short8;
typedef __attribute__((ext_vector_type(4))) short short4v;
typedef __attribute__((ext_vector_type(4))) float floatx4;

__device__ __forceinline__ float bf2f(short s) {
  union { unsigned u; float f; } t;
  t.u = ((unsigned)(unsigned short)s) << 16;
  return t.f;
}

// ---------------------------------------------------------------------------
__device__ inline void load16_lds(const __hip_bfloat16* g, __hip_bfloat16* l) {
  __builtin_amdgcn_global_load_lds(
      (const __attribute__((address_space(1))) uint32_t*)g,
      (__attribute__((address_space(3))) uint32_t*)l, 16, 0, 0);
}

// ---------------------------------------------------------------------------
// Fused preprocessing (one launch, 2592 blocks):
//  [0,1024)    x fp32 -> xT_bf [B][D][S] bf16 (transposed) + x_bf bf16 row-major
//  [1024,2048) weight casts fp32->bf16
//  [2048,2592) wr/wi -> bf16 transposed [1024][1025]
// ---------------------------------------------------------------------------
__global__ __launch_bounds__(256) void prep_fused(
    const float* __restrict__ x, __hip_bfloat16* __restrict__ xT_bf,
    __hip_bfloat16* __restrict__ x_bf,
    const float* __restrict__ w_in, const float* __restrict__ w_out,
    __hip_bfloat16* __restrict__ w_in_bf, __hip_bfloat16* __restrict__ w_out_bf,
    const float* __restrict__ wr, const float* __restrict__ wi,
    __hip_bfloat16* __restrict__ wrT, __hip_bfloat16* __restrict__ wiT) {
  __shared__ float tile[64][65];
  const int id = blockIdx.x;
  const int tx = threadIdx.x & 63;
  const int ty = threadIdx.x >> 6;

  if (id < 1024) {
    const int bz = id >> 9;
    const int rem = id & 511;
    const int c0 = (rem & 15) * 64;   // D
    const int r0 = (rem >> 4) * 64;   // S
    const size_t base = (size_t)bz * SS * DD;
#pragma unroll
    for (int i = 0; i < 16; ++i) {
      const int r = ty * 16 + i;
      const float v = x[base + (size_t)(r0 + r) * DD + c0 + tx];
      tile[r][tx] = v;
      x_bf[base + (size_t)(r0 + r) * DD + c0 + tx] = __float2bfloat16(v);
    }
    __syncthreads();
#pragma unroll
    for (int i = 0; i < 16; ++i) {
      const int c = ty * 16 + i;
      xT_bf[base + (size_t)(c0 + c) * SS + r0 + tx] = __float2bfloat16(tile[tx][c]);
    }
  } else if (id < 2048) {
    const int blk = id - 1024;
    const float* src; __hip_bfloat16* dst; size_t off;
    if (blk < 768) { src = w_in; dst = w_in_bf; off = (size_t)blk * 4096; }
    else { src = w_out; dst = w_out_bf; off = (size_t)(blk - 768) * 4096; }
#pragma unroll
    for (int c = 0; c < 4; ++c) {
      const size_t j = off + c * 1024 + threadIdx.x * 4;
      const float4 v = *(const float4*)(src + j);
      dst[j + 0] = __float2bfloat16(v.x);
      dst[j + 1] = __float2bfloat16(v.y);
      dst[j + 2] = __float2bfloat16(v.z);
      dst[j + 3] = __float2bfloat16(v.w);
    }
  } else {
    const int id2 = id - 2048;               // 0..543
    const int half = id2 >= 272;
    const int rem = id2 - (half ? 272 : 0);
    const float* src = half ? wi : wr;
    __hip_bfloat16* dst = half ? wiT : wrT;
    const int R = 1025, C = DD;
    const int c0 = (rem & 15) * 64;
    const int r0 = (rem >> 4) * 64;
#pragma unroll
    for (int i = 0; i < 16; ++i) {
      const int r = ty * 16 + i;
      if (r0 + r < R) tile[r][tx] = src[(size_t)(r0 + r) * C + c0 + tx];
    }
    __syncthreads();
#pragma unroll
    for (int i = 0; i < 16; ++i) {
      const int c = ty * 16 + i;
      if (r0 + tx < R) dst[(size_t)(c0 + c) * R + r0 + tx] = __float2bfloat16(tile[tx][c]);
    }
  }
}

// ---------------------------------------------------------------------------
// bf16 MFMA GEMM tile body (BK=64, unchanged from R8). sm: 32 KB.
// ---------------------------------------------------------------------------
template <bool BF16OUT>
__device__ __forceinline__ void gemm_tile128(
    const __hip_bfloat16* __restrict__ A, const __hip_bfloat16* __restrict__ B,
    const float* __restrict__ bias, void* __restrict__ Cp,
    int N, int K, int row0, int col0, __hip_bfloat16* sm) {
  __hip_bfloat16* As0 = sm;
  __hip_bfloat16* As1 = sm + 4096;
  __hip_bfloat16* Bs0 = sm + 8192;
  __hip_bfloat16* Bs1 = sm + 12288;
  const int tid  = threadIdx.x;
  const int lane = tid & 63;
  const int wave = tid >> 6;
  const int wrow = (wave >> 1) * 64;
  const int wcol = (wave & 1) * 64;
  const int srow = tid >> 2;
  const int skk  = (tid & 3) * 8;
  const int quad = lane >> 4;
  const int l16  = lane & 15;
  floatx4 acc[4][4] = {};
  for (int k0 = 0; k0 < K; k0 += 64) {
    __syncthreads();
    load16_lds(A + (size_t)(row0 + srow) * K + k0 + skk,           &As0[tid * 8]);
    load16_lds(A + (size_t)(row0 + 64 + srow) * K + k0 + skk,      &As0[2048 + tid * 8]);
    load16_lds(A + (size_t)(row0 + srow) * K + k0 + 32 + skk,      &As1[tid * 8]);
    load16_lds(A + (size_t)(row0 + 64 + srow) * K + k0 + 32 + skk, &As1[2048 + tid * 8]);
    load16_lds(B + (size_t)(col0 + srow) * K + k0 + skk,           &Bs0[tid * 8]);
    load16_lds(B + (size_t)(col0 + 64 + srow) * K + k0 + skk,      &Bs0[2048 + tid * 8]);
    load16_lds(B + (size_t)(col0 + srow) * K + k0 + 32 + skk,      &Bs1[tid * 8]);
    load16_lds(B + (size_t)(col0 + 64 + srow) * K + k0 + 32 + skk, &Bs1[2048 + tid * 8]);
    __syncthreads();
    {
      short8 af[4], bf[4];
#pragma unroll
      for (int i = 0; i < 4; ++i)
        af[i] = *(const short8*)&As0[(wrow + i * 16 + l16) * 32 + quad * 8];
#pragma unroll
      for (int j = 0; j < 4; ++j)
        bf[j] = *(const short8*)&Bs0[(wcol + j * 16 + l16) * 32 + quad * 8];
#pragma unroll
      for (int i = 0; i < 4; ++i)
#pragma unroll
        for (int j = 0; j < 4; ++j)
          acc[i][j] = __builtin_amdgcn_mfma_f32_16x16x32_bf16(af[i], bf[j], acc[i][j], 0, 0, 0);
    }
    {
      short8 af[4], bf[4];
#pragma unroll
      for (int i = 0; i < 4; ++i)
        af[i] = *(const short8*)&As1[(wrow + i * 16 + l16) * 32 + quad * 8];
#pragma unroll
      for (int j = 0; j < 4; ++j)
        bf[j] = *(const short8*)&Bs1[(wcol + j * 16 + l16) * 32 + quad * 8];
#pragma unroll
      for (int i = 0; i < 4; ++i)
#pragma unroll
        for (int j = 0; j < 4; ++j)
          acc[i][j] = __builtin_amdgcn_mfma_f32_16x16x32_bf16(af[i], bf[j], acc[i][j], 0, 0, 0);
    }
  }
#pragma unroll
  for (int i = 0; i < 4; ++i) {
#pragma unroll
    for (int j = 0; j < 4; ++j) {
      const int col = col0 + wcol + j * 16 + l16;
      const float bs = bias[col];
#pragma unroll
      for (int r = 0; r < 4; ++r) {
        const int row = row0 + wrow + i * 16 + quad * 4 + r;
        if (BF16OUT)
          ((__hip_bfloat16*)Cp)[(size_t)row * N + col] = __float2bfloat16(acc[i][j][r] + bs);
        else
          ((float*)Cp)[(size_t)row * N + col] = acc[i][j][r] + bs;
      }
    }
  }
}

// ---------------------------------------------------------------------------
// Spectral FFT body v3: fused double radix-2 stages (4 points/group in regs,
// one sincosf per group; w2 = -i*w1, w3 = w1^2). 12 LDS passes total vs 22.
// Final permutation identical to the verified radix-2 chain (bitrev11), so
// the packed-Hermitian filter stage is unchanged. xT is bf16, in-place.
// LDS: cx[2112] float2 = 16896 B.
// ---------------------------------------------------------------------------
#define PAD2(a) ((a) + ((a) >> 5))

__device__ __forceinline__ void spec_body(
    int sid, __hip_bfloat16* __restrict__ xw,
    const __hip_bfloat16* __restrict__ wrT, const __hip_bfloat16* __restrict__ wiT,
    float* smf) {
  float2* cx = (float2*)smf;
  const int tid = threadIdx.x;
  const int dpair = sid & 511;
  const int b = sid >> 9;
  const int d0 = dpair * 2, d1 = d0 + 1;
  __hip_bfloat16* col0 = xw + ((size_t)b * DD + d0) * SS;
  __hip_bfloat16* col1 = xw + ((size_t)b * DD + d1) * SS;

  // load two bf16 columns -> packed complex
  for (int s4 = tid * 4; s4 < SS; s4 += 1024) {
    const short4v a = *(const short4v*)(col0 + s4);
    const short4v c = *(const short4v*)(col1 + s4);
    const int p = PAD2(s4);
    cx[p + 0] = float2{bf2f(a[0]), bf2f(c[0])};
    cx[p + 1] = float2{bf2f(a[1]), bf2f(c[1])};
    cx[p + 2] = float2{bf2f(a[2]), bf2f(c[2])};
    cx[p + 3] = float2{bf2f(a[3]), bf2f(c[3])};
  }

  // ---- forward DIF: double stages s = 11,9,7,5,3 then single stage 1 ----
#pragma unroll
  for (int s = 11; s >= 3; s -= 2) {
    __syncthreads();
    const int h2 = 1 << (s - 2);
    const float ang = -6.283185307179586f / (float)(1 << s);
#pragma unroll 2
    for (int g = tid; g < 512; g += 256) {
      const int q = g & (h2 - 1);
      const int base = ((g >> (s - 2)) << s) + q;
      const int i0 = PAD2(base), i1 = PAD2(base + h2);
      const int i2 = PAD2(base + 2 * h2), i3 = PAD2(base + 3 * h2);
      float sn, cn;
      __sincosf(ang * (float)q, &sn, &cn);          // w1 = (cn, sn)
      const float2 A = cx[i0], B = cx[i1], C = cx[i2], D = cx[i3];
      const float2 Ap = {A.x + C.x, A.y + C.y};
      const float acx = A.x - C.x, acy = A.y - C.y;
      const float2 Cp = {acx * cn - acy * sn, acx * sn + acy * cn};
      const float2 Bp = {B.x + D.x, B.y + D.y};
      const float bdx = B.x - D.x, bdy = B.y - D.y;
      const float2 Dp = {bdx * sn + bdy * cn, bdy * sn - bdx * cn};  // *( -i*w1 )
      const float w3r = cn * cn - sn * sn, w3i = 2.f * cn * sn;     // w1^2
      cx[i0] = float2{Ap.x + Bp.x, Ap.y + Bp.y};
      const float abx = Ap.x - Bp.x, aby = Ap.y - Bp.y;
      cx[i1] = float2{abx * w3r - aby * w3i, abx * w3i + aby * w3r};
      cx[i2] = float2{Cp.x + Dp.x, Cp.y + Dp.y};
      const float cdx = Cp.x - Dp.x, cdy = Cp.y - Dp.y;
      cx[i3] = float2{cdx * w3r - cdy * w3i, cdx * w3i + cdy * w3r};
    }
  }
  __syncthreads();
  for (int t = tid; t < 1024; t += 256) {           // stage 1, twiddle = 1
    const int i = PAD2(2 * t), j = PAD2(2 * t + 1);
    const float2 a = cx[i], b = cx[j];
    cx[i] = float2{a.x + b.x, a.y + b.y};
    cx[j] = float2{a.x - b.x, a.y - b.y};
  }
  __syncthreads();

  // ---- packed Hermitian filter (bitrev positions), 1/S folded in ----
  const __hip_bfloat16* w0r = wrT + (size_t)d0 * 1025;
  const __hip_bfloat16* w0i = wiT + (size_t)d0 * 1025;
  const __hip_bfloat16* w1r = wrT + (size_t)d1 * 1025;
  const __hip_bfloat16* w1i = wiT + (size_t)d1 * 1025;
  const float sc = 1.0f / (float)SS;
  for (int k = tid; k < 1024; k += 256) {
    if (k == 0) {
      const float2 z0 = cx[0];
      cx[0] = float2{z0.x * __bfloat162float(w0r[0]) * sc,
                     z0.y * __bfloat162float(w1r[0]) * sc};
      const float2 zn = cx[1];
      cx[1] = float2{zn.x * __bfloat162float(w0r[1024]) * sc,
                     zn.y * __bfloat162float(w1r[1024]) * sc};
    } else {
      const int p1 = PAD2(__brev((unsigned)k) >> 21);
      const int p2 = PAD2(__brev((unsigned)(SS - k)) >> 21);
      const float2 A = cx[p1];
      const float2 Bv = cx[p2];
      const float z0r = 0.5f * (A.x + Bv.x), z0i = 0.5f * (A.y - Bv.y);
      const float z1r = 0.5f * (A.y + Bv.y), z1i = -0.5f * (A.x - Bv.x);
      const float a0 = __bfloat162float(w0r[k]) * sc, b0 = __bfloat162float(w0i[k]) * sc;
      const float a1 = __bfloat162float(w1r[k]) * sc, b1 = __bfloat162float(w1i[k]) * sc;
      const float y0r = z0r * a0 - z0i * b0, y0i = z0r * b0 + z0i * a0;
      const float y1r = z1r * a1 - z1i * b1, y1i = z1r * b1 + z1i * a1;
      cx[p1] = float2{y0r - y1i, y0i + y1r};
      cx[p2] = float2{y0r + y1i, y1r - y0i};
    }
  }

  // ---- inverse DIT: double stages s = 1,3,5,7,9 then single stage 11 ----
#pragma unroll
  for (int s = 1; s <= 9; s += 2) {
    __syncthreads();
    const int h = 1 << (s - 1);
    const float ang = -6.283185307179586f / (float)(1 << (s + 1));
#pragma unroll 2
    for (int g = tid; g < 512; g += 256) {
      const int q = g & (h - 1);
      const int base = ((g >> (s - 1)) << (s + 1)) + q;
      const int i0 = PAD2(base), i1 = PAD2(base + h);
      const int i2 = PAD2(base + 2 * h), i3 = PAD2(base + 3 * h);
      float sn, cn;
      __sincosf(ang * (float)q, &sn, &cn);   // wp = (cn, sn); conj used below
      const float wpr = cn, wpi = -sn;                       // conj(wp)
      const float wsr = cn * cn - sn * sn, wsi = -2.f * cn * sn;  // conj(wp)^2
      const float2 A = cx[i0], B = cx[i1], C = cx[i2], D = cx[i3];
      const float2 tB = {B.x * wsr - B.y * wsi, B.x * wsi + B.y * wsr};
      const float2 tD = {D.x * wsr - D.y * wsi, D.x * wsi + D.y * wsr};
      const float2 Ap = {A.x + tB.x, A.y + tB.y};
      const float2 Bp = {A.x - tB.x, A.y - tB.y};
      const float2 Cp = {C.x + tD.x, C.y + tD.y};
      const float2 Dp = {C.x - tD.x, C.y - tD.y};
      const float2 u = {Cp.x * wpr - Cp.y * wpi, Cp.x * wpi + Cp.y * wpr};
      const float2 v = {Dp.x * sn - Dp.y * cn, Dp.x * cn + Dp.y * sn}; // *(i*conj(wp)) = (sn,cn)
      cx[i0] = float2{Ap.x + u.x, Ap.y + u.y};
      cx[i2] = float2{Ap.x - u.x, Ap.y - u.y};
      cx[i1] = float2{Bp.x + v.x, Bp.y + v.y};
      cx[i3] = float2{Bp.x - v.x, Bp.y - v.y};
    }
  }
  __syncthreads();
  for (int p = tid; p < 1024; p += 256) {    // stage 11: pairs (p, p+1024)
    float sn, cn;
    __sincosf(-6.283185307179586f * (float)p * (1.0f / 2048.0f), &sn, &cn);
    const int i = PAD2(p), j = PAD2(p + 1024);
    const float2 a = cx[i], b = cx[j];
    const float tr = b.x * cn + b.y * sn;    // b * conj(w)
    const float ti = b.y * cn - b.x * sn;
    cx[i] = float2{a.x + tr, a.y + ti};
    cx[j] = float2{a.x - tr, a.y - ti};
  }
  __syncthreads();

  // store bf16, in place
  for (int s4 = tid * 4; s4 < SS; s4 += 1024) {
    const int p = PAD2(s4);
    const float2 v0 = cx[p + 0], v1 = cx[p + 1], v2 = cx[p + 2], v3 = cx[p + 3];
    short4v a, c;
    a[0] = (short)__bfloat16_as_ushort(__float2bfloat16(v0.x));
    a[1] = (short)__bfloat16_as_ushort(__float2bfloat16(v1.x));
    a[2] = (short)__bfloat16_as_ushort(__float2bfloat16(v2.x));
    a[3] = (short)__bfloat16_as_ushort(__float2bfloat16(v3.x));
    c[0] = (short)__bfloat16_as_ushort(__float2bfloat16(v0.y));
    c[1] = (short)__bfloat16_as_ushort(__float2bfloat16(v1.y));
    c[2] = (short)__bfloat16_as_ushort(__float2bfloat16(v2.y));
    c[3] = (short)__bfloat16_as_ushort(__float2bfloat16(v3.y));
    *(short4v*)(col0 + s4) = a;
    *(short4v*)(col1 + s4) = c;
  }
}

// ---------------------------------------------------------------------------
// Fused launch 1: blocks [0,768) = QKV GEMM; [768,1792) = spectral FFT.
// Dynamic LDS 32768 B.
// ---------------------------------------------------------------------------
__global__ __launch_bounds__(256) void gemm1_spec(
    const __hip_bfloat16* __restrict__ x_bf, const __hip_bfloat16* __restrict__ w_in_bf,
    const float* __restrict__ in_b, __hip_bfloat16* __restrict__ qkv_bf,
    __hip_bfloat16* __restrict__ xT_bf, const __hip_bfloat16* __restrict__ wrT,
    const __hip_bfloat16* __restrict__ wiT) {
  extern __shared__ __align__(16) char smem[];
  if (blockIdx.x < 768) {
    const int id = blockIdx.x;
    const int col0 = (id % 24) * 128;
    const int row0 = (id / 24) * 128;
    gemm_tile128<true>(x_bf, w_in_bf, in_b, qkv_bf, 3 * DD, DD, row0, col0,
                       (__hip_bfloat16*)smem);
  } else {
    spec_body(blockIdx.x - 768, xT_bf, wrT, wiT, (float*)smem);
  }
}

// ---------------------------------------------------------------------------
// Fused launch 2: blocks [0,256) = out-proj GEMM; [256,1280) = transpose-back
// xT_bf [b][d][s] -> x_wave_bf [b][s][d]. Dynamic LDS 32768 B.
// ---------------------------------------------------------------------------
__global__ __launch_bounds__(256) void gemm2_tback(
    const __hip_bfloat16* __restrict__ attn_bf, const __hip_bfloat16* __restrict__ w_out_bf,
    const float* __restrict__ out_b, __hip_bfloat16* __restrict__ attn_out_bf,
    const __hip_bfloat16* __restrict__ xT_bf, __hip_bfloat16* __restrict__ x_wave_bf) {
  extern __shared__ __align__(16) char smem[];
  if (blockIdx.x < 256) {
    const int id = blockIdx.x;
    const int col0 = (id % 8) * 128;
    const int row0 = (id / 8) * 128;
    gemm_tile128<true>(attn_bf, w_out_bf, out_b, attn_out_bf, DD, DD, row0, col0,
                       (__hip_bfloat16*)smem);
  } else {
    float (*tile)[65] = (float(*)[65])smem;
    const int id = blockIdx.x - 256;          // 0..1023
    const int bz = id >> 9;
    const int rem = id & 511;
    const int s0 = (rem >> 4) * 64;
    const int d0 = (rem & 15) * 64;
    const int tx = threadIdx.x & 63;
    const int ty = threadIdx.x >> 6;
    const __hip_bfloat16* src = xT_bf + (size_t)bz * DD * SS;
    __hip_bfloat16* dst = x_wave_bf + (size_t)bz * SS * DD;
#pragma unroll
    for (int i = 0; i < 16; ++i) {
      const int r = ty * 16 + i;
      tile[r][tx] = __bfloat162float(src[(size_t)(d0 + r) * SS + s0 + tx]);
    }
    __syncthreads();
#pragma unroll
    for (int i = 0; i < 16; ++i) {
      const int c = ty * 16 + i;
      dst[(size_t)(s0 + c) * DD + d0 + tx] = __float2bfloat16(tile[tx][c]);
    }
  }
}

// ---------------------------------------------------------------------------
// Flash-style MFMA sliding-window attention (unchanged).
// ---------------------------------------------------------------------------
__global__ __launch_bounds__(256, 2) void attn_mfma(
    const __hip_bfloat16* __restrict__ qkv, __hip_bfloat16* __restrict__ attn) {
  __shared__ __attribute__((aligned(16))) __hip_bfloat16 QsA[64 * 32];
  __shared__ __attribute__((aligned(16))) __hip_bfloat16 QsB[64 * 32];
  __shared__ __attribute__((aligned(16))) __hip_bfloat16 KsA[160 * 32];
  __shared__ __attribute__((aligned(16))) __hip_bfloat16 KsB[160 * 32];
  __shared__ __attribute__((aligned(16))) __hip_bfloat16 Vt[64 * 168];
  __shared__ __attribute__((aligned(16))) __hip_bfloat16 Ps[64 * 168];

  const int tid  = threadIdx.x;
  const int lane = tid & 63;
  const int w    = tid >> 6;
  const int quad = lane >> 4;
  const int l16  = lane & 15;
  const int q0   = blockIdx.x * 64;
  const int h    = blockIdx.y;
  const int b    = blockIdx.z;
  const int kbase = q0 - WINW;

  const int r_ = tid >> 2;
  const int c8 = (tid & 3) * 8;

  {
    const __hip_bfloat16* src = qkv + ((size_t)(b * SS + q0 + r_)) * (3 * DD) + h * DHH;
    load16_lds(src + c8,      &QsA[r_ * 32 + c8]);
    load16_lds(src + 32 + c8, &QsB[r_ * 32 + c8]);
  }

  short8 qf0, qf1;
  float m_run[4] = {-1e30f, -1e30f, -1e30f, -1e30f};
  float l_run[4] = {0.f, 0.f, 0.f, 0.f};
  floatx4 ob[4] = {};

  for (int c = 0; c < 2; ++c) {
    const int ck0 = kbase + c * 160;
    __syncthreads();
#pragma unroll
    for (int it = 0; it < 3; ++it) {
      const int r = it * 64 + r_;
      if (r < 160) {
        int key = ck0 + r; key = key < 0 ? 0 : (key > SS - 1 ? SS - 1 : key);
        const __hip_bfloat16* src = qkv + ((size_t)(b * SS + key)) * (3 * DD) + DD + h * DHH;
        load16_lds(src + c8,      &KsA[r * 32 + c8]);
        load16_lds(src + 32 + c8, &KsB[r * 32 + c8]);
      }
    }
    {
      const int k4 = (tid >> 3) * 4;
      const int d8 = (tid & 7) * 8;
#pragma unroll
      for (int it = 0; it < 2; ++it) {
        const int rr = it * 128 + k4;
        if (rr < 160) {
          short8 v[4];
#pragma unroll
          for (int u = 0; u < 4; ++u) {
            int key = ck0 + rr + u; key = key < 0 ? 0 : (key > SS - 1 ? SS - 1 : key);
            v[u] = *(const short8*)(qkv + ((size_t)(b * SS + key)) * (3 * DD) + 2 * DD + h * DHH + d8);
          }
#pragma unroll
          for (int j = 0; j < 8; ++j) {
            short4v pk; pk[0] = v[0][j]; pk[1] = v[1][j]; pk[2] = v[2][j]; pk[3] = v[3][j];
            *(short4v*)&Vt[(d8 + j) * 168 + rr] = pk;
          }
        }
      }
    }
    __syncthreads();

    if (c == 0) {
      qf0 = *(const short8*)&QsA[(w * 16 + l16) * 32 + quad * 8];
      qf1 = *(const short8*)&QsB[(w * 16 + l16) * 32 + quad * 8];
    }

    floatx4 sc[10];
#pragma unroll
    for (int kt = 0; kt < 10; ++kt) {
      const short8 bk0 = *(const short8*)&KsA[(kt * 16 + l16) * 32 + quad * 8];
      const short8 bk1 = *(const short8*)&KsB[(kt * 16 + l16) * 32 + quad * 8];
      floatx4 a = {};
      a = __builtin_amdgcn_mfma_f32_16x16x32_bf16(qf0, bk0, a, 0, 0, 0);
      a = __builtin_amdgcn_mfma_f32_16x16x32_bf16(qf1, bk1, a, 0, 0, 0);
      sc[kt] = a;
    }

    float cm[4] = {-1e30f, -1e30f, -1e30f, -1e30f};
#pragma unroll
    for (int kt = 0; kt < 10; ++kt) {
      const int key = ck0 + kt * 16 + l16;
#pragma unroll
      for (int r = 0; r < 4; ++r) {
        const int qq = q0 + w * 16 + quad * 4 + r;
        const int dqk = qq - key;
        const bool ok = (key >= 0) & (key < SS) & (dqk <= WINW) & (dqk >= -WINW);
        const float s = ok ? sc[kt][r] * 0.125f : -1e30f;
        sc[kt][r] = s;
        cm[r] = fmaxf(cm[r], s);
      }
    }
#pragma unroll
    for (int off = 1; off < 16; off <<= 1)
#pragma unroll
      for (int r = 0; r < 4; ++r) cm[r] = fmaxf(cm[r], __shfl_xor(cm[r], off, 64));

    float alpha[4], csum[4] = {0.f, 0.f, 0.f, 0.f};
#pragma unroll
    for (int r = 0; r < 4; ++r) {
      const float mn = fmaxf(m_run[r], cm[r]);
      alpha[r] = __expf(m_run[r] - mn);
      m_run[r] = mn;
    }

    __hip_bfloat16* Pw = &Ps[w * 16 * 168];
#pragma unroll
    for (int kt = 0; kt < 10; ++kt) {
#pragma unroll
      for (int r = 0; r < 4; ++r) {
        const float p = __expf(sc[kt][r] - m_run[r]);
        csum[r] += p;
        Pw[(quad * 4 + r) * 168 + kt * 16 + l16] = __float2bfloat16(p);
      }
    }
#pragma unroll
    for (int off = 1; off < 16; off <<= 1)
#pragma unroll
      for (int r = 0; r < 4; ++r) csum[r] += __shfl_xor(csum[r], off, 64);
#pragma unroll
    for (int r = 0; r < 4; ++r) l_run[r] = l_run[r] * alpha[r] + csum[r];
#pragma unroll
    for (int t = 0; t < 4; ++t)
#pragma unroll
      for (int r = 0; r < 4; ++r) ob[t][r] *= alpha[r];

#pragma unroll
    for (int kt = 0; kt < 5; ++kt) {
      const short8 pf = *(const short8*)&Pw[l16 * 168 + kt * 32 + quad * 8];
#pragma unroll
      for (int t = 0; t < 4; ++t) {
        const short8 vf = *(const short8*)&Vt[(t * 16 + l16) * 168 + kt * 32 + quad * 8];
        ob[t] = __builtin_amdgcn_mfma_f32_16x16x32_bf16(pf, vf, ob[t], 0, 0, 0);
      }
    }
  }

  float inv[4];
#pragma unroll
  for (int r = 0; r < 4; ++r) inv[r] = 1.f / l_run[r];
  const int qq0 = q0 + w * 16 + quad * 4;
#pragma unroll
  for (int t = 0; t < 4; ++t)
#pragma unroll
    for (int r = 0; r < 4; ++r)
      attn[((size_t)(b * SS + qq0 + r)) * DD + h * DHH + t * 16 + l16] =
          __float2bfloat16(ob[t][r] * inv[r]);
}

// ---------------------------------------------------------------------------
// Fused double LayerNorm: out = LN2( LN1(x + attn_out) + x_wave ).
// ---------------------------------------------------------------------------
__global__ __launch_bounds__(256) void ln_fused(
    const float* __restrict__ x, const __hip_bfloat16* __restrict__ attn_out,
    const float* __restrict__ g1, const float* __restrict__ b1,
    const __hip_bfloat16* __restrict__ xwave,
    const float* __restrict__ g2, const float* __restrict__ b2,
    float* __restrict__ out) {
  const int row = blockIdx.x;
  const int tid = threadIdx.x;
  const int lane = tid & 63;
  const int wave = tid >> 6;
  __shared__ float red[8];

  const float4 xv = *(const float4*)(x + (size_t)row * DD + tid * 4);
  const short4v av = *(const short4v*)(attn_out + (size_t)row * DD + tid * 4);
  float v[4] = {xv.x + bf2f(av[0]), xv.y + bf2f(av[1]),
                xv.z + bf2f(av[2]), xv.w + bf2f(av[3])};

  float s = v[0] + v[1] + v[2] + v[3];
  float s2 = v[0] * v[0] + v[1] * v[1] + v[2] * v[2] + v[3] * v[3];
#pragma unroll
  for (int off = 32; off; off >>= 1) {
    s += __shfl_xor(s, off, 64);
    s2 += __shfl_xor(s2, off, 64);
  }
  if (lane == 0) { red[wave] = s; red[4 + wave] = s2; }
  __syncthreads();
  s = red[0] + red[1] + red[2] + red[3];
  s2 = red[4] + red[5] + red[6] + red[7];
  float mu = s * (1.f / DD);
  float var = s2 * (1.f / DD) - mu * mu;
  float r = rsqrtf(var + 1e-5f);

  const float4 g1v = *(const float4*)(g1 + tid * 4);
  const float4 b1v = *(const float4*)(b1 + tid * 4);
  const short4v wv = *(const short4v*)(xwave + (size_t)row * DD + tid * 4);
  float a[4];
  a[0] = (v[0] - mu) * r * g1v.x + b1v.x + bf2f(wv[0]);
  a[1] = (v[1] - mu) * r * g1v.y + b1v.y + bf2f(wv[1]);
  a[2] = (v[2] - mu) * r * g1v.z + b1v.z + bf2f(wv[2]);
  a[3] = (v[3] - mu) * r * g1v.w + b1v.w + bf2f(wv[3]);

  s = a[0] + a[1] + a[2] + a[3];
  s2 = a[0] * a[0] + a[1] * a[1] + a[2] * a[2] + a[3] * a[3];
#pragma unroll
  for (int off = 32; off; off >>= 1) {
    s += __shfl_xor(s, off, 64);
    s2 += __shfl_xor(s2, off, 64);
  }
  __syncthreads();
  if (lane == 0) { red[wave] = s; red[4 + wave] = s2; }
  __syncthreads();
  s = red[0] + red[1] + red[2] + red[3];
  s2 = red[4] + red[5] + red[6] + red[7];
  mu = s * (1.f / DD);
  var = s2 * (1.f / DD) - mu * mu;
  r = rsqrtf(var + 1e-5f);

  const float4 g2v = *(const float4*)(g2 + tid * 4);
  const float4 b2v = *(const float4*)(b2 + tid * 4);
  float4 o;
  o.x = (a[0] - mu) * r * g2v.x + b2v.x;
  o.y = (a[1] - mu) * r * g2v.y + b2v.y;
  o.z = (a[2] - mu) * r * g2v.z + b2v.z;
  o.w = (a[3] - mu) * r * g2v.w + b2v.w;
  *(float4*)(out + (size_t)row * DD + tid * 4) = o;
}

// ---------------------------------------------------------------------------
extern "C" void kernel_launch(void* const* d_in, const int* in_sizes, int n_in,
                              void* d_out, int out_size, void* d_ws, size_t ws_size,
                              hipStream_t stream) {
  const float* x     = (const float*)d_in[0];
  const float* in_w  = (const float*)d_in[1];
  const float* in_b  = (const float*)d_in[2];
  const float* out_w = (const float*)d_in[3];
  const float* out_b = (const float*)d_in[4];
  const float* ln1_g = (const float*)d_in[5];
  const float* ln1_b = (const float*)d_in[6];
  const float* wr    = (const float*)d_in[7];
  const float* wi    = (const float*)d_in[8];
  const float* ln2_g = (const float*)d_in[9];
  const float* ln2_b = (const float*)d_in[10];
  float* out = (float*)d_out;

  char* ws = (char*)d_ws;
  // Workspace (<= 64 MB), phase-reused:
  //  [0,8)     xT_bf bf16 [B][D][S] (FFT in place; read by tback)
  //  [16,24)   x_bf16 (dead after gemm1) -> attn_bf16
  //  [24,30)   w_in_bf ; [30,32) w_out_bf
  //  [32,56)   qkv_bf16 (dead after attn) -> attn_out_bf + x_wave_bf
  //  [56,61)   wrT bf16 ; wiT bf16
  __hip_bfloat16* xT_bf    = (__hip_bfloat16*)(ws);
  __hip_bfloat16* x_bf     = (__hip_bfloat16*)(ws + 16777216);
  __hip_bfloat16* attn_bf  = (__hip_bfloat16*)(ws + 16777216);
  __hip_bfloat16* w_in_bf  = (__hip_bfloat16*)(ws + 25165824);
  __hip_bfloat16* w_out_bf = (__hip_bfloat16*)(ws + 31457280);
  __hip_bfloat16* qkv_bf   = (__hip_bfloat16*)(ws + 33554432);
  __hip_bfloat16* attn_out_bf = (__hip_bfloat16*)(ws + 33554432);
  __hip_bfloat16* x_wave_bf   = (__hip_bfloat16*)(ws + 44040192);
  __hip_bfloat16* wrT      = (__hip_bfloat16*)(ws + 58720256);
  __hip_bfloat16* wiT      = (__hip_bfloat16*)(ws + 60819456);

  // 1. fused preprocessing
  prep_fused<<<2592, 256, 0, stream>>>(x, xT_bf, x_bf, in_w, out_w,
                                       w_in_bf, w_out_bf, wr, wi, wrT, wiT);

  // 2. fused: QKV GEMM (768 blocks) + spectral FFT (1024 blocks)
  gemm1_spec<<<1792, 256, 32768, stream>>>(x_bf, w_in_bf, in_b, qkv_bf,
                                           xT_bf, wrT, wiT);

  // 3. flash MFMA sliding-window attention
  attn_mfma<<<dim3(SS / 64, HH, BB), 256, 0, stream>>>(qkv_bf, attn_bf);

  // 4. fused: out-proj GEMM (256 blocks) + transpose-back (1024 blocks)
  gemm2_tback<<<1280, 256, 32768, stream>>>(attn_bf, w_out_bf, out_b,
                                            attn_out_bf, xT_bf, x_wave_bf);

  // 5. fused LN1+LN2 -> out
  ln_fused<<<MROWS, 256, 0, stream>>>(x, attn_out_bf, ln1_g, ln1_b,
                                      x_wave_bf, ln2_g, ln2_b, out);
}